// Round 1
// baseline (4290.708 us; speedup 1.0000x reference)
//
#include <hip/hip_runtime.h>
#include <cstddef>

constexpr int V = 50000, E = 400000, R = 400, D = 100, OUT = 200, B = 1024;
constexpr int HALF = E / 2;
constexpr float EPS = 1e-5f;

// ---------------- precompute: Mloop[j][o] = sum_k loop_rel[(j+k)%D] * loop_w[k][o]
__global__ __launch_bounds__(256) void k_mloop(const float* __restrict__ loop_rel,
                                               const float* __restrict__ loop_w,
                                               float* __restrict__ Mloop) {
    int i = blockIdx.x * 256 + threadIdx.x;
    if (i >= D * OUT) return;
    int j = i / OUT, o = i % OUT;
    float s = 0.f;
    for (int k = 0; k < D; ++k) {
        int idx = j + k; if (idx >= D) idx -= D;
        s += loop_rel[idx] * loop_w[k * OUT + o];
    }
    Mloop[i] = s;
}

// ---------------- precompute: r_out = rel_emb @ w_rel  [R,OUT]
__global__ __launch_bounds__(256) void k_rout(const float* __restrict__ rel_emb,
                                              const float* __restrict__ w_rel,
                                              float* __restrict__ r_out) {
    int i = blockIdx.x * 256 + threadIdx.x;
    if (i >= R * OUT) return;
    int r = i / OUT, o = i % OUT;
    float s = 0.f;
    for (int k = 0; k < D; ++k) s += rel_emb[r * D + k] * w_rel[k * OUT + o];
    r_out[i] = s;
}

// ---------------- per-edge: ccorr(h_src, r_e) @ W * norm -> atomic agg[dst]
__global__ __launch_bounds__(128) void k_edge(const int* __restrict__ esrc,
                                              const int* __restrict__ edst,
                                              const int* __restrict__ etyp,
                                              const float* __restrict__ enorm,
                                              const float* __restrict__ ent_emb,
                                              const float* __restrict__ rel_emb,
                                              const float* __restrict__ in_w,
                                              const float* __restrict__ out_w,
                                              float* __restrict__ agg) {
    __shared__ float a[D];
    __shared__ float b2[2 * D];  // duplicated to avoid mod in inner loop
    __shared__ float c[D];
    int e = blockIdx.x;
    int t = threadIdx.x;
    int s = esrc[e];
    int ty = etyp[e];
    if (t < D) {
        float av = ent_emb[s * D + t];
        float bv = rel_emb[ty * D + t];
        a[t] = av;
        b2[t] = bv;
        b2[t + D] = bv;
    }
    __syncthreads();
    if (t < D) {
        float sum = 0.f;
#pragma unroll 4
        for (int j = 0; j < D; ++j) sum += a[j] * b2[j + t];
        c[t] = sum;
    }
    __syncthreads();
    const float* W = (e < HALF) ? in_w : out_w;
    float nrm = enorm[e];
    int dd = edst[e];
#pragma unroll
    for (int rep = 0; rep < 2; ++rep) {
        int o = t + rep * 128;
        if (o < OUT) {
            float sum = 0.f;
#pragma unroll 4
            for (int k = 0; k < D; ++k) sum += c[k] * W[k * OUT + o];
            atomicAdd(&agg[dd * OUT + o], sum * nrm);
        }
    }
}

// ---------------- x[v][o] = (agg + ent_emb@Mloop)/3 + conv_bias  (in place over agg)
__global__ __launch_bounds__(128) void k_x(const float* __restrict__ ent_emb,
                                           const float* __restrict__ Mloop,
                                           const float* __restrict__ conv_bias,
                                           float* __restrict__ x) {
    __shared__ float a[D];
    int v = blockIdx.x, t = threadIdx.x;
    if (t < D) a[t] = ent_emb[v * D + t];
    __syncthreads();
#pragma unroll
    for (int rep = 0; rep < 2; ++rep) {
        int o = t + rep * 128;
        if (o < OUT) {
            float s = 0.f;
#pragma unroll 4
            for (int k = 0; k < D; ++k) s += a[k] * Mloop[k * OUT + o];
            x[v * OUT + o] = (x[v * OUT + o] + s) * (1.f / 3.f) + conv_bias[o];
        }
    }
}

// ---------------- per-column sums for BN (200 cols x 512 row-stripes)
__global__ __launch_bounds__(256) void k_stats(const float* __restrict__ x,
                                               float* __restrict__ colsum,
                                               float* __restrict__ colsq) {
    int g = blockIdx.x * 256 + threadIdx.x;  // 400 blocks -> 102400 = 200*512
    int col = g % OUT;
    int r0 = g / OUT;
    float s = 0.f, sq = 0.f;
    for (int r = r0; r < V; r += 512) {
        float v = x[(size_t)r * OUT + col];
        s += v;
        sq += v * v;
    }
    atomicAdd(&colsum[col], s);
    atomicAdd(&colsq[col], sq);
}

__global__ void k_finstats(const float* __restrict__ colsum, const float* __restrict__ colsq,
                           float* __restrict__ mean, float* __restrict__ rstd) {
    int o = threadIdx.x;
    if (o >= OUT) return;
    float m = colsum[o] / (float)V;
    float var = colsq[o] / (float)V - m * m;
    mean[o] = m;
    rstd[o] = rsqrtf(var + EPS);
}

// ---------------- obj[b][o] = tanh(BN(x[head[b]][o])) * r_out[rela[b]][o]
__global__ __launch_bounds__(256) void k_obj(const int* __restrict__ head,
                                             const int* __restrict__ rela,
                                             const float* __restrict__ x,
                                             const float* __restrict__ mean,
                                             const float* __restrict__ rstd,
                                             const float* __restrict__ gamma,
                                             const float* __restrict__ beta,
                                             const float* __restrict__ r_out,
                                             float* __restrict__ obj) {
    int b = blockIdx.x, t = threadIdx.x;
    if (t >= OUT) return;
    int h = head[b], r = rela[b];
    float val = (x[h * OUT + t] - mean[t]) * rstd[t] * gamma[t] + beta[t];
    val = tanhf(val);
    obj[b * OUT + t] = val * r_out[r * OUT + t];
}

// ---------------- decoder: score[b][v] = sigmoid(obj[b] . emb_ent[v] + ent_bias[v])
constexpr int BM = 32;   // b tile
constexpr int BN = 128;  // v tile
constexpr int OPAD = OUT + 1;  // LDS pad to break stride-200 bank conflicts

__global__ __launch_bounds__(256) void k_dec(const float* __restrict__ obj,
                                             const float* __restrict__ emb_ent,
                                             const float* __restrict__ ent_bias,
                                             float* __restrict__ score) {
    __shared__ float so[BM][OPAD];   // 32*201*4  = 25.7 KB
    __shared__ float se[BN][OPAD];   // 128*201*4 = 102.9 KB
    int t = threadIdx.x;
    int v0 = blockIdx.x * BN;
    int b0 = blockIdx.y * BM;
    for (int i = t; i < BM * OUT; i += 256) {
        so[i / OUT][i % OUT] = obj[(b0 + i / OUT) * OUT + i % OUT];
    }
    for (int i = t; i < BN * OUT; i += 256) {
        int v = v0 + i / OUT;
        se[i / OUT][i % OUT] = (v < V) ? emb_ent[(size_t)v * OUT + i % OUT] : 0.f;
    }
    __syncthreads();
    int tx = t % 32;  // v: 32 groups x 4
    int ty = t / 32;  // b: 8 groups x 4
    float acc[4][4] = {};
    for (int k = 0; k < OUT; ++k) {
        float av[4], bv[4];
#pragma unroll
        for (int i = 0; i < 4; ++i) av[i] = so[ty * 4 + i][k];
#pragma unroll
        for (int j = 0; j < 4; ++j) bv[j] = se[tx * 4 + j][k];
#pragma unroll
        for (int i = 0; i < 4; ++i)
#pragma unroll
            for (int j = 0; j < 4; ++j) acc[i][j] += av[i] * bv[j];
    }
#pragma unroll
    for (int i = 0; i < 4; ++i) {
        int b = b0 + ty * 4 + i;
#pragma unroll
        for (int j = 0; j < 4; ++j) {
            int v = v0 + tx * 4 + j;
            if (v < V) {
                float val = acc[i][j] + ent_bias[v];
                score[(size_t)b * V + v] = 1.f / (1.f + __expf(-val));
            }
        }
    }
}

extern "C" void kernel_launch(void* const* d_in, const int* in_sizes, int n_in,
                              void* d_out, int out_size, void* d_ws, size_t ws_size,
                              hipStream_t stream) {
    const int*   edge_src  = (const int*)d_in[0];
    const int*   edge_dst  = (const int*)d_in[1];
    const int*   edge_type = (const int*)d_in[2];
    const int*   head      = (const int*)d_in[3];
    const int*   rela      = (const int*)d_in[4];
    const float* edge_norm = (const float*)d_in[5];
    const float* ent_emb   = (const float*)d_in[6];
    const float* rel_emb   = (const float*)d_in[7];
    const float* in_w      = (const float*)d_in[8];
    const float* out_w     = (const float*)d_in[9];
    const float* loop_w    = (const float*)d_in[10];
    const float* w_rel     = (const float*)d_in[11];
    const float* loop_rel  = (const float*)d_in[12];
    const float* conv_bias = (const float*)d_in[13];
    const float* bn_gamma  = (const float*)d_in[14];
    const float* bn_beta   = (const float*)d_in[15];
    const float* emb_ent   = (const float*)d_in[16];
    const float* ent_bias  = (const float*)d_in[17];
    float* score = (float*)d_out;

    // workspace layout (floats)
    float* ws = (float*)d_ws;
    float* agg    = ws;                              // V*OUT = 10,000,000
    float* colsum = ws + (size_t)V * OUT;            // 200
    float* colsq  = colsum + OUT;                    // 200
    float* meanp  = colsq + OUT;                     // 200
    float* rstdp  = meanp + OUT;                     // 200
    float* Mloop  = rstdp + OUT;                     // D*OUT = 20,000
    float* r_out  = Mloop + (size_t)D * OUT;         // R*OUT = 80,000
    float* obj    = r_out + (size_t)R * OUT;         // B*OUT = 204,800

    // zero agg + colsum + colsq
    hipMemsetAsync(agg, 0, ((size_t)V * OUT + 2 * OUT) * sizeof(float), stream);

    k_mloop<<<(D * OUT + 255) / 256, 256, 0, stream>>>(loop_rel, loop_w, Mloop);
    k_rout<<<(R * OUT + 255) / 256, 256, 0, stream>>>(rel_emb, w_rel, r_out);
    k_edge<<<E, 128, 0, stream>>>(edge_src, edge_dst, edge_type, edge_norm,
                                  ent_emb, rel_emb, in_w, out_w, agg);
    k_x<<<V, 128, 0, stream>>>(ent_emb, Mloop, conv_bias, agg);
    k_stats<<<400, 256, 0, stream>>>(agg, colsum, colsq);
    k_finstats<<<1, 256, 0, stream>>>(colsum, colsq, meanp, rstdp);
    k_obj<<<B, 256, 0, stream>>>(head, rela, agg, meanp, rstdp, bn_gamma, bn_beta,
                                 r_out, obj);
    dim3 dgrid((V + BN - 1) / BN, B / BM);
    k_dec<<<dgrid, 256, 0, stream>>>(obj, emb_ent, ent_bias, score);
}

// Round 2
// 1419.582 us; speedup vs baseline: 3.0225x; 3.0225x over previous
//
#include <hip/hip_runtime.h>
#include <cstddef>

constexpr int V = 50000, E = 400000, R = 400, D = 100, OUT = 200, B = 1024;
constexpr int HALF = E / 2;
constexpr float EPS = 1e-5f;
constexpr int K2 = 232;      // padded K stride (bf16) for decoder GEMM; 464B rows -> conflict-free frag reads
constexpr int VPAD = 50176;  // 196 * 256
constexpr int EPB = 32;      // edges per block

typedef short bf16x8 __attribute__((ext_vector_type(8)));
typedef float f32x4  __attribute__((ext_vector_type(4)));

typedef __attribute__((address_space(1))) const unsigned int guint_t;
typedef __attribute__((address_space(3))) unsigned int luint_t;

__device__ inline unsigned short f2bf(float x) {
    unsigned u = __float_as_uint(x);
    u = (u + 0x7fffu + ((u >> 16) & 1u)) >> 16;
    return (unsigned short)u;
}

// ---------------- Mloop[j][o] = sum_k loop_rel[(j+k)%D] * loop_w[k][o]
__global__ __launch_bounds__(256) void k_mloop(const float* __restrict__ loop_rel,
                                               const float* __restrict__ loop_w,
                                               float* __restrict__ Mloop) {
    int i = blockIdx.x * 256 + threadIdx.x;
    if (i >= D * OUT) return;
    int j = i / OUT, o = i % OUT;
    float s = 0.f;
    for (int k = 0; k < D; ++k) {
        int idx = j + k; if (idx >= D) idx -= D;
        s += loop_rel[idx] * loop_w[k * OUT + o];
    }
    Mloop[i] = s;
}

// ---------------- r_out = rel_emb @ w_rel  [R,OUT]
__global__ __launch_bounds__(256) void k_rout(const float* __restrict__ rel_emb,
                                              const float* __restrict__ w_rel,
                                              float* __restrict__ r_out) {
    int i = blockIdx.x * 256 + threadIdx.x;
    if (i >= R * OUT) return;
    int r = i / OUT, o = i % OUT;
    float s = 0.f;
    for (int k = 0; k < D; ++k) s += rel_emb[r * D + k] * w_rel[k * OUT + o];
    r_out[i] = s;
}

// ---------------- 32 edges/block: ccorr + @W + norm + atomic scatter
__global__ __launch_bounds__(256) void k_edge2(const int* __restrict__ esrc,
                                               const int* __restrict__ edst,
                                               const int* __restrict__ etyp,
                                               const float* __restrict__ enorm,
                                               const float* __restrict__ ent_emb,
                                               const float* __restrict__ rel_emb,
                                               const float* __restrict__ in_w,
                                               const float* __restrict__ out_w,
                                               float* __restrict__ agg) {
    __shared__ float sh[EPB][100];   // h_src rows
    __shared__ float sr[EPB][204];   // r duplicated (r[k], r[k+100]); stride 204 -> bank-friendly
    __shared__ float sct[100][36];   // c transposed [k][edge]; stride 36 -> bank-friendly
    __shared__ int   sdst[EPB];
    __shared__ float snrm[EPB];
    __shared__ int   ssrc[EPB], styp[EPB];
    int t = threadIdx.x;
    int e0 = blockIdx.x * EPB;
    if (t < EPB) {
        ssrc[t] = esrc[e0 + t];
        styp[t] = etyp[e0 + t];
        sdst[t] = edst[e0 + t];
        snrm[t] = enorm[e0 + t];
    }
    __syncthreads();
    for (int i = t; i < EPB * 25; i += 256) {
        int ee = i / 25, q = i - ee * 25;
        float4 hv = *(const float4*)&ent_emb[(size_t)ssrc[ee] * D + q * 4];
        float4 rv = *(const float4*)&rel_emb[(size_t)styp[ee] * D + q * 4];
        *(float4*)&sh[ee][q * 4] = hv;
        *(float4*)&sr[ee][q * 4] = rv;
        *(float4*)&sr[ee][q * 4 + 100] = rv;
    }
    __syncthreads();
    // ccorr: c[k] = sum_j h[j] * r[j+k]
    for (int i = t; i < EPB * 25; i += 256) {
        int kg = i >> 5, ee = i & 31;
        int k0 = kg * 4;
        float c0 = 0.f, c1 = 0.f, c2 = 0.f, c3 = 0.f;
#pragma unroll 5
        for (int jb = 0; jb < 25; ++jb) {
            float4 a4 = *(const float4*)&sh[ee][jb * 4];
            float4 bb0 = *(const float4*)&sr[ee][jb * 4 + k0];
            float4 bb1 = *(const float4*)&sr[ee][jb * 4 + k0 + 4];
            float a0 = a4.x, a1 = a4.y, a2 = a4.z, a3 = a4.w;
            c0 += a0 * bb0.x + a1 * bb0.y + a2 * bb0.z + a3 * bb0.w;
            c1 += a0 * bb0.y + a1 * bb0.z + a2 * bb0.w + a3 * bb1.x;
            c2 += a0 * bb0.z + a1 * bb0.w + a2 * bb1.x + a3 * bb1.y;
            c3 += a0 * bb0.w + a1 * bb1.x + a2 * bb1.y + a3 * bb1.z;
        }
        sct[k0 + 0][ee] = c0;
        sct[k0 + 1][ee] = c1;
        sct[k0 + 2][ee] = c2;
        sct[k0 + 3][ee] = c3;
    }
    __syncthreads();
    // msg = c @ W * norm -> atomic scatter; 8x4 register microtile
    if (t < 200) {
        int og = t % 50, eg = t / 50;
        int o0 = og * 4, ee0 = eg * 8;
        const float* __restrict__ W = (e0 < HALF) ? in_w : out_w;
        float acc[8][4] = {};
        for (int k = 0; k < D; ++k) {
            float4 w4 = *(const float4*)&W[k * OUT + o0];
            float4 ca = *(const float4*)&sct[k][ee0];
            float4 cb = *(const float4*)&sct[k][ee0 + 4];
            float cc[8] = {ca.x, ca.y, ca.z, ca.w, cb.x, cb.y, cb.z, cb.w};
            float wv[4] = {w4.x, w4.y, w4.z, w4.w};
#pragma unroll
            for (int ee = 0; ee < 8; ++ee)
#pragma unroll
                for (int j = 0; j < 4; ++j) acc[ee][j] += cc[ee] * wv[j];
        }
#pragma unroll
        for (int ee = 0; ee < 8; ++ee) {
            int e = ee0 + ee;
            float nr = snrm[e];
            size_t base = (size_t)sdst[e] * OUT + o0;
#pragma unroll
            for (int j = 0; j < 4; ++j) atomicAdd(&agg[base + j], acc[ee][j] * nr);
        }
    }
}

// ---------------- x = (agg + ent_emb@Mloop)/3 + conv_bias (in place over agg)
__global__ __launch_bounds__(256) void k_x2(const float* __restrict__ ent_emb,
                                            const float* __restrict__ Mloop,
                                            const float* __restrict__ conv_bias,
                                            float* __restrict__ x) {
    __shared__ float sat[100][36];
    int t = threadIdx.x;
    int v0 = blockIdx.x * 32;
    for (int i = t; i < 800; i += 256) {
        int kg = i >> 5, vv = i & 31;
        int vsafe = min(v0 + vv, V - 1);
        float4 a4 = *(const float4*)&ent_emb[(size_t)vsafe * D + kg * 4];
        sat[kg * 4 + 0][vv] = a4.x;
        sat[kg * 4 + 1][vv] = a4.y;
        sat[kg * 4 + 2][vv] = a4.z;
        sat[kg * 4 + 3][vv] = a4.w;
    }
    __syncthreads();
    if (t < 200) {
        int og = t % 50, eg = t / 50;
        int o0 = og * 4, vv0 = eg * 8;
        float acc[8][4] = {};
        for (int k = 0; k < D; ++k) {
            float4 w4 = *(const float4*)&Mloop[k * OUT + o0];
            float4 ca = *(const float4*)&sat[k][vv0];
            float4 cb = *(const float4*)&sat[k][vv0 + 4];
            float cc[8] = {ca.x, ca.y, ca.z, ca.w, cb.x, cb.y, cb.z, cb.w};
            float wv[4] = {w4.x, w4.y, w4.z, w4.w};
#pragma unroll
            for (int ee = 0; ee < 8; ++ee)
#pragma unroll
                for (int j = 0; j < 4; ++j) acc[ee][j] += cc[ee] * wv[j];
        }
        float4 bi = *(const float4*)&conv_bias[o0];
        float bv[4] = {bi.x, bi.y, bi.z, bi.w};
#pragma unroll
        for (int ee = 0; ee < 8; ++ee) {
            int v = v0 + vv0 + ee;
            if (v < V) {
                size_t base = (size_t)v * OUT + o0;
                float4 ag = *(const float4*)&x[base];
                float4 ov;
                ov.x = (ag.x + acc[ee][0]) * (1.f / 3.f) + bv[0];
                ov.y = (ag.y + acc[ee][1]) * (1.f / 3.f) + bv[1];
                ov.z = (ag.z + acc[ee][2]) * (1.f / 3.f) + bv[2];
                ov.w = (ag.w + acc[ee][3]) * (1.f / 3.f) + bv[3];
                *(float4*)&x[base] = ov;
            }
        }
    }
}

// ---------------- per-column sums for BN
__global__ __launch_bounds__(256) void k_stats(const float* __restrict__ x,
                                               float* __restrict__ colsum,
                                               float* __restrict__ colsq) {
    int g = blockIdx.x * 256 + threadIdx.x;  // 400 blocks -> 102400 = 200*512
    int col = g % OUT;
    int r0 = g / OUT;
    float s = 0.f, sq = 0.f;
    for (int r = r0; r < V; r += 512) {
        float v = x[(size_t)r * OUT + col];
        s += v;
        sq += v * v;
    }
    atomicAdd(&colsum[col], s);
    atomicAdd(&colsq[col], sq);
}

__global__ void k_finstats(const float* __restrict__ colsum, const float* __restrict__ colsq,
                           float* __restrict__ mean, float* __restrict__ rstd) {
    int o = threadIdx.x;
    if (o >= OUT) return;
    float m = colsum[o] / (float)V;
    float var = colsq[o] / (float)V - m * m;
    mean[o] = m;
    rstd[o] = rsqrtf(var + EPS);
}

// ---------------- obj_bf[b][k] = bf16(tanh(BN(x[head]))*r_out[rela]), zero-padded to K2
__global__ __launch_bounds__(256) void k_obj(const int* __restrict__ head,
                                             const int* __restrict__ rela,
                                             const float* __restrict__ x,
                                             const float* __restrict__ mean,
                                             const float* __restrict__ rstd,
                                             const float* __restrict__ gamma,
                                             const float* __restrict__ beta,
                                             const float* __restrict__ r_out,
                                             unsigned short* __restrict__ obj_bf) {
    int b = blockIdx.x, t = threadIdx.x;
    if (t >= K2) return;
    float v = 0.f;
    if (t < OUT) {
        int h = head[b], r = rela[b];
        float val = (x[(size_t)h * OUT + t] - mean[t]) * rstd[t] * gamma[t] + beta[t];
        val = tanhf(val);
        v = val * r_out[r * OUT + t];
    }
    obj_bf[(size_t)b * K2 + t] = f2bf(v);
}

// ---------------- emb_bf[v][k] = bf16(emb_ent[v][k]) padded (rows to VPAD, cols to K2)
__global__ __launch_bounds__(256) void k_cvt_emb(const float* __restrict__ emb_ent,
                                                 unsigned short* __restrict__ emb_bf) {
    int v = blockIdx.x, t = threadIdx.x;
    if (t >= K2) return;
    float val = (v < V && t < OUT) ? emb_ent[(size_t)v * OUT + t] : 0.f;
    emb_bf[(size_t)v * K2 + t] = f2bf(val);
}

// ---------------- decoder: score = sigmoid(obj @ emb^T + bias), bf16 MFMA
constexpr int DEC_BM = 64, DEC_BN = 256;

__global__ __launch_bounds__(512) void k_dec2(const unsigned short* __restrict__ obj_bf,
                                              const unsigned short* __restrict__ emb_bf,
                                              const float* __restrict__ ent_bias,
                                              float* __restrict__ score) {
    __shared__ __align__(16) unsigned short As[DEC_BM * K2];  // 29696 B
    __shared__ __align__(16) unsigned short Bs[DEC_BN * K2];  // 118784 B
    int t = threadIdx.x;
    int lane = t & 63, wid = t >> 6;
    int b0 = blockIdx.x * DEC_BM;
    int v0 = blockIdx.y * DEC_BN;
    const unsigned short* gA = obj_bf + (size_t)b0 * K2;
    const unsigned short* gB = emb_bf + (size_t)v0 * K2;
    // stage A (29 x 1KB chunks) and B (116 x 1KB chunks) via global_load_lds width 16
    for (int c = wid; c < 29; c += 8) {
        __builtin_amdgcn_global_load_lds((guint_t*)(gA + c * 512 + lane * 8),
                                         (luint_t*)(As + c * 512), 16, 0, 0);
    }
    for (int c = wid; c < 116; c += 8) {
        __builtin_amdgcn_global_load_lds((guint_t*)(gB + c * 512 + lane * 8),
                                         (luint_t*)(Bs + c * 512), 16, 0, 0);
    }
    __syncthreads();
    int wm = wid & 1, wn = wid >> 1;  // 2 (m) x 4 (n) waves
    int rA = wm * 32 + (lane & 15);
    int rB = wn * 64 + (lane & 15);
    int kc = (lane >> 4) * 8;
    f32x4 acc[2][4] = {};
    for (int ks = 0; ks < 7; ++ks) {
        int kof = ks * 32 + kc;
        bf16x8 a0 = *(const bf16x8*)&As[(rA + 0) * K2 + kof];
        bf16x8 a1 = *(const bf16x8*)&As[(rA + 16) * K2 + kof];
        bf16x8 bb0 = *(const bf16x8*)&Bs[(rB + 0) * K2 + kof];
        bf16x8 bb1 = *(const bf16x8*)&Bs[(rB + 16) * K2 + kof];
        bf16x8 bb2 = *(const bf16x8*)&Bs[(rB + 32) * K2 + kof];
        bf16x8 bb3 = *(const bf16x8*)&Bs[(rB + 48) * K2 + kof];
        acc[0][0] = __builtin_amdgcn_mfma_f32_16x16x32_bf16(a0, bb0, acc[0][0], 0, 0, 0);
        acc[0][1] = __builtin_amdgcn_mfma_f32_16x16x32_bf16(a0, bb1, acc[0][1], 0, 0, 0);
        acc[0][2] = __builtin_amdgcn_mfma_f32_16x16x32_bf16(a0, bb2, acc[0][2], 0, 0, 0);
        acc[0][3] = __builtin_amdgcn_mfma_f32_16x16x32_bf16(a0, bb3, acc[0][3], 0, 0, 0);
        acc[1][0] = __builtin_amdgcn_mfma_f32_16x16x32_bf16(a1, bb0, acc[1][0], 0, 0, 0);
        acc[1][1] = __builtin_amdgcn_mfma_f32_16x16x32_bf16(a1, bb1, acc[1][1], 0, 0, 0);
        acc[1][2] = __builtin_amdgcn_mfma_f32_16x16x32_bf16(a1, bb2, acc[1][2], 0, 0, 0);
        acc[1][3] = __builtin_amdgcn_mfma_f32_16x16x32_bf16(a1, bb3, acc[1][3], 0, 0, 0);
    }
#pragma unroll
    for (int nf = 0; nf < 4; ++nf) {
        int v = v0 + wn * 64 + nf * 16 + (lane & 15);
        if (v >= V) continue;
        float bias = ent_bias[v];
#pragma unroll
        for (int mf = 0; mf < 2; ++mf) {
            int brow = b0 + wm * 32 + mf * 16 + (lane >> 4) * 4;
            f32x4 a = acc[mf][nf];
#pragma unroll
            for (int i = 0; i < 4; ++i) {
                float val = a[i] + bias;
                score[(size_t)(brow + i) * V + v] = 1.f / (1.f + __expf(-val));
            }
        }
    }
}

extern "C" void kernel_launch(void* const* d_in, const int* in_sizes, int n_in,
                              void* d_out, int out_size, void* d_ws, size_t ws_size,
                              hipStream_t stream) {
    const int*   edge_src  = (const int*)d_in[0];
    const int*   edge_dst  = (const int*)d_in[1];
    const int*   edge_type = (const int*)d_in[2];
    const int*   head      = (const int*)d_in[3];
    const int*   rela      = (const int*)d_in[4];
    const float* edge_norm = (const float*)d_in[5];
    const float* ent_emb   = (const float*)d_in[6];
    const float* rel_emb   = (const float*)d_in[7];
    const float* in_w      = (const float*)d_in[8];
    const float* out_w     = (const float*)d_in[9];
    const float* loop_w    = (const float*)d_in[10];
    const float* w_rel     = (const float*)d_in[11];
    const float* loop_rel  = (const float*)d_in[12];
    const float* conv_bias = (const float*)d_in[13];
    const float* bn_gamma  = (const float*)d_in[14];
    const float* bn_beta   = (const float*)d_in[15];
    const float* emb_ent   = (const float*)d_in[16];
    const float* ent_bias  = (const float*)d_in[17];
    float* score = (float*)d_out;

    float* ws = (float*)d_ws;
    float* agg    = ws;                      // 10,000,000 floats
    float* colsum = ws + 10000000;           // 200
    float* colsq  = colsum + OUT;            // 200
    float* meanp  = colsq + OUT;             // 200
    float* rstdp  = meanp + OUT;             // 200
    float* Mloop  = rstdp + OUT;             // 20,000
    float* r_out  = Mloop + D * OUT;         // 80,000
    unsigned short* obj_bf = (unsigned short*)(r_out + R * OUT);  // 1024*232 ushorts
    unsigned short* emb_bf = (unsigned short*)ws;  // reuses agg region AFTER k_obj

    hipMemsetAsync(agg, 0, (size_t)(10000000 + 2 * OUT) * sizeof(float), stream);

    k_mloop<<<(D * OUT + 255) / 256, 256, 0, stream>>>(loop_rel, loop_w, Mloop);
    k_rout<<<(R * OUT + 255) / 256, 256, 0, stream>>>(rel_emb, w_rel, r_out);
    k_edge2<<<E / EPB, 256, 0, stream>>>(edge_src, edge_dst, edge_type, edge_norm,
                                         ent_emb, rel_emb, in_w, out_w, agg);
    k_x2<<<(V + 31) / 32, 256, 0, stream>>>(ent_emb, Mloop, conv_bias, agg);
    k_stats<<<400, 256, 0, stream>>>(agg, colsum, colsq);
    k_finstats<<<1, 256, 0, stream>>>(colsum, colsq, meanp, rstdp);
    k_obj<<<B, 256, 0, stream>>>(head, rela, agg, meanp, rstdp, bn_gamma, bn_beta,
                                 r_out, obj_bf);
    k_cvt_emb<<<VPAD, 256, 0, stream>>>(emb_ent, emb_bf);
    dim3 dgrid(B / DEC_BM, VPAD / DEC_BN);
    k_dec2<<<dgrid, 512, 0, stream>>>(obj_bf, emb_bf, ent_bias, score);
}

// Round 3
// 885.932 us; speedup vs baseline: 4.8432x; 1.6024x over previous
//
#include <hip/hip_runtime.h>
#include <cstddef>

constexpr int V = 50000, E = 400000, R = 400, D = 100, OUT = 200, B = 1024;
constexpr int HALF = E / 2;
constexpr float EPS = 1e-5f;
constexpr int K2 = 232;        // decoder K pad (bf16)
constexpr int VPAD = 50176;    // 196*256
constexpr int NKEY = 800;      // (rel, side)
constexpr int E1MAX = 450560;  // E + NKEY*63 rounded up to 64
constexpr int MT_O = 208, MT_K = 128;              // Mt tile dims (padded)
constexpr int MT_SZ = MT_O * MT_K;                 // ushorts per key

typedef short bf16x8 __attribute__((ext_vector_type(8)));
typedef float f32x4  __attribute__((ext_vector_type(4)));
typedef __attribute__((address_space(1))) const unsigned int guint_t;
typedef __attribute__((address_space(3))) unsigned int luint_t;

__device__ inline unsigned short f2bf(float x) {
    unsigned u = __float_as_uint(x);
    u = (u + 0x7fffu + ((u >> 16) & 1u)) >> 16;
    return (unsigned short)u;
}
__device__ inline float bf2f(unsigned short u) {
    return __uint_as_float(((unsigned)u) << 16);
}

// ---------------- Mloop[j][o] = sum_k loop_rel[(j+k)%D] * loop_w[k][o]
__global__ __launch_bounds__(256) void k_mloop(const float* __restrict__ loop_rel,
                                               const float* __restrict__ loop_w,
                                               float* __restrict__ Mloop) {
    int i = blockIdx.x * 256 + threadIdx.x;
    if (i >= D * OUT) return;
    int j = i / OUT, o = i % OUT;
    float s = 0.f;
    for (int k = 0; k < D; ++k) {
        int idx = j + k; if (idx >= D) idx -= D;
        s += loop_rel[idx] * loop_w[k * OUT + o];
    }
    Mloop[i] = s;
}

// ---------------- r_out = rel_emb @ w_rel  [R,OUT]
__global__ __launch_bounds__(256) void k_rout(const float* __restrict__ rel_emb,
                                              const float* __restrict__ w_rel,
                                              float* __restrict__ r_out) {
    int i = blockIdx.x * 256 + threadIdx.x;
    if (i >= R * OUT) return;
    int r = i / OUT, o = i % OUT;
    float s = 0.f;
    for (int k = 0; k < D; ++k) s += rel_emb[r * D + k] * w_rel[k * OUT + o];
    r_out[i] = s;
}

// ---------------- histograms
__global__ __launch_bounds__(256) void k_hist(const int* __restrict__ etyp,
                                              const int* __restrict__ edst,
                                              int* __restrict__ hist1,
                                              int* __restrict__ hist2) {
    int e = blockIdx.x * 256 + threadIdx.x;
    if (e >= E) return;
    int key = etyp[e] + (e < HALF ? 0 : R);
    atomicAdd(&hist1[key], 1);
    atomicAdd(&hist2[edst[e]], 1);
}

// ---------------- scans: start1 (64-aligned pad), start2 (exact)
__global__ __launch_bounds__(1024) void k_scan(const int* __restrict__ hist1,
                                               const int* __restrict__ hist2,
                                               int* __restrict__ start1,
                                               int* __restrict__ start2,
                                               int* __restrict__ Edev) {
    __shared__ int buf[1024];
    int t = threadIdx.x;
    // scan1 over 800, padded to 64-multiples
    int c = (t < NKEY) ? ((hist1[t] + 63) & ~63) : 0;
    buf[t] = c; __syncthreads();
    for (int off = 1; off < 1024; off <<= 1) {
        int x = (t >= off) ? buf[t - off] : 0; __syncthreads();
        buf[t] += x; __syncthreads();
    }
    if (t < NKEY) start1[t] = buf[t] - c;
    if (t == NKEY - 1) { start1[NKEY] = buf[t]; *Edev = buf[t]; }
    __syncthreads();
    // scan2 over 50000 via 1024 stripes of 49
    const int STR = 49;
    int base = t * STR;
    int s = 0;
    for (int i = 0; i < STR; ++i) { int idx = base + i; s += (idx < V) ? hist2[idx] : 0; }
    buf[t] = s; __syncthreads();
    for (int off = 1; off < 1024; off <<= 1) {
        int x = (t >= off) ? buf[t - off] : 0; __syncthreads();
        buf[t] += x; __syncthreads();
    }
    int run = buf[t] - s;
    for (int i = 0; i < STR; ++i) {
        int idx = base + i;
        if (idx < V) { int h = hist2[idx]; start2[idx] = run; run += h; }
    }
    if (t == 0) start2[V] = E;
}

// ---------------- scatter both permutations
__global__ __launch_bounds__(256) void k_scatter(const int* __restrict__ etyp,
                                                 const int* __restrict__ edst,
                                                 const int* __restrict__ start1,
                                                 const int* __restrict__ start2,
                                                 int* __restrict__ cursor1,
                                                 int* __restrict__ cursor2,
                                                 int* __restrict__ perm1,
                                                 int* __restrict__ inv1,
                                                 int* __restrict__ keys_sorted,
                                                 int* __restrict__ perm2) {
    int e = blockIdx.x * 256 + threadIdx.x;
    if (e >= E) return;
    int key = etyp[e] + (e < HALF ? 0 : R);
    int p = start1[key] + atomicAdd(&cursor1[key], 1);
    perm1[p] = e;
    inv1[e] = p;
    keys_sorted[p] = key;
    int d = edst[e];
    int q = start2[d] + atomicAdd(&cursor2[d], 1);
    perm2[q] = e;
}

// ---------------- Mt[key][o][j] = sum_k r_rho[(j+k)%D] * W[k][o]  (bf16, padded)
__global__ __launch_bounds__(256) void k_mtab(const float* __restrict__ rel_emb,
                                              const float* __restrict__ in_w,
                                              const float* __restrict__ out_w,
                                              unsigned short* __restrict__ Mtab) {
    __shared__ float rsh[228];
    int key = blockIdx.x;
    int rho = (key < R) ? key : key - R;
    const float* __restrict__ W = (key < R) ? in_w : out_w;
    int t = threadIdx.x;
    for (int s = t; s < 228; s += 256) {
        int sm = s; if (sm >= 200) sm -= 200; if (sm >= 100) sm -= 100;
        rsh[s] = rel_emb[rho * D + sm];
    }
    __syncthreads();
    unsigned short* MtK = Mtab + (size_t)key * MT_SZ;
    int jg = t >> 3;           // 0..31 -> j0 = jg*4
    int og = t & 7;            // o-group lane
    int j0 = jg * 4;
    for (int go = og; go < 50; go += 8) {
        int o0 = go * 4;
        float acc[4][4] = {};  // [oi][ji]
        for (int k = 0; k < D; ++k) {
            float4 w = *(const float4*)&W[k * OUT + o0];
            float rv0 = rsh[j0 + k], rv1 = rsh[j0 + k + 1];
            float rv2 = rsh[j0 + k + 2], rv3 = rsh[j0 + k + 3];
            float wv[4] = {w.x, w.y, w.z, w.w};
#pragma unroll
            for (int oi = 0; oi < 4; ++oi) {
                acc[oi][0] += rv0 * wv[oi];
                acc[oi][1] += rv1 * wv[oi];
                acc[oi][2] += rv2 * wv[oi];
                acc[oi][3] += rv3 * wv[oi];
            }
        }
#pragma unroll
        for (int ji = 0; ji < 4; ++ji)
            if (j0 + ji >= D) { acc[0][ji] = acc[1][ji] = acc[2][ji] = acc[3][ji] = 0.f; }
#pragma unroll
        for (int oi = 0; oi < 4; ++oi) {
            ushort4 pk;
            pk.x = f2bf(acc[oi][0]); pk.y = f2bf(acc[oi][1]);
            pk.z = f2bf(acc[oi][2]); pk.w = f2bf(acc[oi][3]);
            *(ushort4*)&MtK[(o0 + oi) * MT_K + j0] = pk;
        }
    }
    // zero pad rows o in [200,208)
    for (int i = t; i < 8 * 32; i += 256) {
        int row = 200 + (i >> 5), j4 = (i & 31) * 4;
        *(ushort4*)&MtK[row * MT_K + j4] = make_ushort4(0, 0, 0, 0);
    }
}

// ---------------- per-chunk MFMA: msg[p][o] = (h_src[p] @ Mt_key) * norm
__global__ __launch_bounds__(256, 2) void k_edgemm(const int* __restrict__ perm1,
                                                   const int* __restrict__ keys_sorted,
                                                   const int* __restrict__ Edev,
                                                   const int* __restrict__ esrc,
                                                   const float* __restrict__ enorm,
                                                   const float* __restrict__ ent_emb,
                                                   const unsigned short* __restrict__ Mtab,
                                                   unsigned short* __restrict__ msg) {
    __shared__ __align__(16) unsigned short MtL[MT_SZ];   // 53,248 B (swizzled 16B granules)
    __shared__ __align__(16) unsigned short AtL[64 * MT_K];  // 16,384 B (swizzled)
    __shared__ float snrm[64];
    __shared__ int ssrc[64];
    int t = threadIdx.x, lane = t & 63, wid = t >> 6;
    int chunk = blockIdx.x;
    if (chunk * 64 >= *Edev) return;
    int key = keys_sorted[chunk * 64];
    const unsigned short* MtK = Mtab + (size_t)key * MT_SZ;
    // issue Mt staging (swizzled global source, linear LDS dest)
    for (int i = 0; i < 13; ++i) {
        int G0 = (wid * 13 + i) * 64;
        int G = G0 + lane;
        int o = G >> 4, g = G & 15;
        int gs = g ^ (o & 7);
        __builtin_amdgcn_global_load_lds((guint_t*)(MtK + o * MT_K + gs * 8),
                                         (luint_t*)(MtL + (size_t)G0 * 8), 16, 0, 0);
    }
    if (t < 64) {
        int p = chunk * 64 + t;
        int e = perm1[p];
        ssrc[t] = (e >= 0) ? esrc[e] : 0;
        snrm[t] = (e >= 0) ? enorm[e] : 0.f;
    }
    __syncthreads();
    // gather + cvt A rows (swizzled ds writes)
    for (int i = t; i < 64 * 25; i += 256) {
        int row = i / 25, q = i - row * 25;
        float4 hv = *(const float4*)&ent_emb[(size_t)ssrc[row] * D + q * 4];
        ushort4 hb;
        hb.x = f2bf(hv.x); hb.y = f2bf(hv.y); hb.z = f2bf(hv.z); hb.w = f2bf(hv.w);
        int byte = q * 8;
        int g = byte >> 4, off8 = byte & 15;
        int gs = g ^ (row & 7);
        *(ushort4*)((char*)AtL + row * 256 + gs * 16 + off8) = hb;
    }
    // zero k in [100,128): bytes 200..255 per row
    for (int i = t; i < 64 * 7; i += 256) {
        int row = i / 7, c = i - row * 7;
        int byte = 200 + c * 8;
        int g = byte >> 4, off8 = byte & 15;
        int gs = g ^ (row & 7);
        *(ushort4*)((char*)AtL + row * 256 + gs * 16 + off8) = make_ushort4(0, 0, 0, 0);
    }
    __syncthreads();
    int erow = wid * 16 + (lane & 15);
    int kq = lane >> 4;
    f32x4 acc[13] = {};
    for (int ks = 0; ks < 4; ++ks) {
        int g = ks * 4 + kq;
        bf16x8 bfr = *(const bf16x8*)((const char*)AtL + erow * 256 + ((g ^ (erow & 7)) * 16));
#pragma unroll
        for (int of = 0; of < 13; ++of) {
            int orow = of * 16 + (lane & 15);
            bf16x8 afr = *(const bf16x8*)((const char*)MtL + orow * 256 + ((g ^ (orow & 7)) * 16));
            acc[of] = __builtin_amdgcn_mfma_f32_16x16x32_bf16(afr, bfr, acc[of], 0, 0, 0);
        }
    }
    float nr = snrm[erow];
    size_t rowbase = (size_t)(chunk * 64 + erow) * OUT;
#pragma unroll
    for (int of = 0; of < 13; ++of) {
        int o0 = of * 16 + kq * 4;
        if (o0 < OUT) {
            ushort4 pk;
            pk.x = f2bf(acc[of][0] * nr); pk.y = f2bf(acc[of][1] * nr);
            pk.z = f2bf(acc[of][2] * nr); pk.w = f2bf(acc[of][3] * nr);
            *(ushort4*)&msg[rowbase + o0] = pk;
        }
    }
}

// ---------------- gather-sum per dst (no atomics)
__global__ __launch_bounds__(256) void k_agg(const int* __restrict__ start2,
                                             const int* __restrict__ perm2,
                                             const int* __restrict__ inv1,
                                             const unsigned short* __restrict__ msg,
                                             float* __restrict__ agg) {
    int wid = threadIdx.x >> 6, lane = threadIdx.x & 63;
    int v = blockIdx.x * 4 + wid;
    if (v >= V) return;
    int s = start2[v], epos = start2[v + 1];
    f32x4 acc = {0.f, 0.f, 0.f, 0.f};
    for (int q = s; q < epos; ++q) {
        int e = perm2[q];
        int p = inv1[e];
        if (lane < 50) {
            ushort4 m = *(const ushort4*)&msg[(size_t)p * OUT + lane * 4];
            acc[0] += bf2f(m.x); acc[1] += bf2f(m.y);
            acc[2] += bf2f(m.z); acc[3] += bf2f(m.w);
        }
    }
    if (lane < 50) {
        float4 o; o.x = acc[0]; o.y = acc[1]; o.z = acc[2]; o.w = acc[3];
        *(float4*)&agg[(size_t)v * OUT + lane * 4] = o;
    }
}

// ---------------- x = (agg + ent_emb@Mloop)/3 + conv_bias (in place)
__global__ __launch_bounds__(256) void k_x2(const float* __restrict__ ent_emb,
                                            const float* __restrict__ Mloop,
                                            const float* __restrict__ conv_bias,
                                            float* __restrict__ x) {
    __shared__ float sat[100][36];
    int t = threadIdx.x;
    int v0 = blockIdx.x * 32;
    for (int i = t; i < 800; i += 256) {
        int kg = i >> 5, vv = i & 31;
        int vsafe = min(v0 + vv, V - 1);
        float4 a4 = *(const float4*)&ent_emb[(size_t)vsafe * D + kg * 4];
        sat[kg * 4 + 0][vv] = a4.x;
        sat[kg * 4 + 1][vv] = a4.y;
        sat[kg * 4 + 2][vv] = a4.z;
        sat[kg * 4 + 3][vv] = a4.w;
    }
    __syncthreads();
    if (t < 200) {
        int og = t % 50, eg = t / 50;
        int o0 = og * 4, vv0 = eg * 8;
        float acc[8][4] = {};
        for (int k = 0; k < D; ++k) {
            float4 w4 = *(const float4*)&Mloop[k * OUT + o0];
            float4 ca = *(const float4*)&sat[k][vv0];
            float4 cb = *(const float4*)&sat[k][vv0 + 4];
            float cc[8] = {ca.x, ca.y, ca.z, ca.w, cb.x, cb.y, cb.z, cb.w};
            float wv[4] = {w4.x, w4.y, w4.z, w4.w};
#pragma unroll
            for (int ee = 0; ee < 8; ++ee)
#pragma unroll
                for (int j = 0; j < 4; ++j) acc[ee][j] += cc[ee] * wv[j];
        }
        float4 bi = *(const float4*)&conv_bias[o0];
        float bv[4] = {bi.x, bi.y, bi.z, bi.w};
#pragma unroll
        for (int ee = 0; ee < 8; ++ee) {
            int v = v0 + vv0 + ee;
            if (v < V) {
                size_t base = (size_t)v * OUT + o0;
                float4 ag = *(const float4*)&x[base];
                float4 ov;
                ov.x = (ag.x + acc[ee][0]) * (1.f / 3.f) + bv[0];
                ov.y = (ag.y + acc[ee][1]) * (1.f / 3.f) + bv[1];
                ov.z = (ag.z + acc[ee][2]) * (1.f / 3.f) + bv[2];
                ov.w = (ag.w + acc[ee][3]) * (1.f / 3.f) + bv[3];
                *(float4*)&x[base] = ov;
            }
        }
    }
}

// ---------------- BN stats
__global__ __launch_bounds__(256) void k_stats(const float* __restrict__ x,
                                               float* __restrict__ colsum,
                                               float* __restrict__ colsq) {
    int g = blockIdx.x * 256 + threadIdx.x;
    int col = g % OUT;
    int r0 = g / OUT;
    float s = 0.f, sq = 0.f;
    for (int r = r0; r < V; r += 512) {
        float v = x[(size_t)r * OUT + col];
        s += v;
        sq += v * v;
    }
    atomicAdd(&colsum[col], s);
    atomicAdd(&colsq[col], sq);
}

__global__ void k_finstats(const float* __restrict__ colsum, const float* __restrict__ colsq,
                           float* __restrict__ mean, float* __restrict__ rstd) {
    int o = threadIdx.x;
    if (o >= OUT) return;
    float m = colsum[o] / (float)V;
    float var = colsq[o] / (float)V - m * m;
    mean[o] = m;
    rstd[o] = rsqrtf(var + EPS);
}

// ---------------- obj_bf = bf16(tanh(BN(x[head]))*r_out[rela]) zero-padded to K2
__global__ __launch_bounds__(256) void k_obj(const int* __restrict__ head,
                                             const int* __restrict__ rela,
                                             const float* __restrict__ x,
                                             const float* __restrict__ mean,
                                             const float* __restrict__ rstd,
                                             const float* __restrict__ gamma,
                                             const float* __restrict__ beta,
                                             const float* __restrict__ r_out,
                                             unsigned short* __restrict__ obj_bf) {
    int b = blockIdx.x, t = threadIdx.x;
    if (t >= K2) return;
    float v = 0.f;
    if (t < OUT) {
        int h = head[b], r = rela[b];
        float val = (x[(size_t)h * OUT + t] - mean[t]) * rstd[t] * gamma[t] + beta[t];
        val = tanhf(val);
        v = val * r_out[r * OUT + t];
    }
    obj_bf[(size_t)b * K2 + t] = f2bf(v);
}

// ---------------- emb_bf padded
__global__ __launch_bounds__(256) void k_cvt_emb(const float* __restrict__ emb_ent,
                                                 unsigned short* __restrict__ emb_bf) {
    int v = blockIdx.x, t = threadIdx.x;
    if (t >= K2) return;
    float val = (v < V && t < OUT) ? emb_ent[(size_t)v * OUT + t] : 0.f;
    emb_bf[(size_t)v * K2 + t] = f2bf(val);
}

// ---------------- decoder (bf16 MFMA)
constexpr int DEC_BM = 64, DEC_BN = 256;

__global__ __launch_bounds__(512) void k_dec2(const unsigned short* __restrict__ obj_bf,
                                              const unsigned short* __restrict__ emb_bf,
                                              const float* __restrict__ ent_bias,
                                              float* __restrict__ score) {
    __shared__ __align__(16) unsigned short As[DEC_BM * K2];
    __shared__ __align__(16) unsigned short Bs[DEC_BN * K2];
    int t = threadIdx.x;
    int lane = t & 63, wid = t >> 6;
    int b0 = blockIdx.x * DEC_BM;
    int v0 = blockIdx.y * DEC_BN;
    const unsigned short* gA = obj_bf + (size_t)b0 * K2;
    const unsigned short* gB = emb_bf + (size_t)v0 * K2;
    for (int c = wid; c < 29; c += 8) {
        __builtin_amdgcn_global_load_lds((guint_t*)(gA + c * 512 + lane * 8),
                                         (luint_t*)(As + c * 512), 16, 0, 0);
    }
    for (int c = wid; c < 116; c += 8) {
        __builtin_amdgcn_global_load_lds((guint_t*)(gB + c * 512 + lane * 8),
                                         (luint_t*)(Bs + c * 512), 16, 0, 0);
    }
    __syncthreads();
    int wm = wid & 1, wn = wid >> 1;
    int rA = wm * 32 + (lane & 15);
    int rB = wn * 64 + (lane & 15);
    int kc = (lane >> 4) * 8;
    f32x4 acc[2][4] = {};
    for (int ks = 0; ks < 7; ++ks) {
        int kof = ks * 32 + kc;
        bf16x8 a0 = *(const bf16x8*)&As[(rA + 0) * K2 + kof];
        bf16x8 a1 = *(const bf16x8*)&As[(rA + 16) * K2 + kof];
        bf16x8 bb0 = *(const bf16x8*)&Bs[(rB + 0) * K2 + kof];
        bf16x8 bb1 = *(const bf16x8*)&Bs[(rB + 16) * K2 + kof];
        bf16x8 bb2 = *(const bf16x8*)&Bs[(rB + 32) * K2 + kof];
        bf16x8 bb3 = *(const bf16x8*)&Bs[(rB + 48) * K2 + kof];
        acc[0][0] = __builtin_amdgcn_mfma_f32_16x16x32_bf16(a0, bb0, acc[0][0], 0, 0, 0);
        acc[0][1] = __builtin_amdgcn_mfma_f32_16x16x32_bf16(a0, bb1, acc[0][1], 0, 0, 0);
        acc[0][2] = __builtin_amdgcn_mfma_f32_16x16x32_bf16(a0, bb2, acc[0][2], 0, 0, 0);
        acc[0][3] = __builtin_amdgcn_mfma_f32_16x16x32_bf16(a0, bb3, acc[0][3], 0, 0, 0);
        acc[1][0] = __builtin_amdgcn_mfma_f32_16x16x32_bf16(a1, bb0, acc[1][0], 0, 0, 0);
        acc[1][1] = __builtin_amdgcn_mfma_f32_16x16x32_bf16(a1, bb1, acc[1][1], 0, 0, 0);
        acc[1][2] = __builtin_amdgcn_mfma_f32_16x16x32_bf16(a1, bb2, acc[1][2], 0, 0, 0);
        acc[1][3] = __builtin_amdgcn_mfma_f32_16x16x32_bf16(a1, bb3, acc[1][3], 0, 0, 0);
    }
#pragma unroll
    for (int nf = 0; nf < 4; ++nf) {
        int v = v0 + wn * 64 + nf * 16 + (lane & 15);
        if (v >= V) continue;
        float bias = ent_bias[v];
#pragma unroll
        for (int mf = 0; mf < 2; ++mf) {
            int brow = b0 + wm * 32 + mf * 16 + (lane >> 4) * 4;
            f32x4 a = acc[mf][nf];
#pragma unroll
            for (int i = 0; i < 4; ++i) {
                float val = a[i] + bias;
                score[(size_t)(brow + i) * V + v] = 1.f / (1.f + __expf(-val));
            }
        }
    }
}

extern "C" void kernel_launch(void* const* d_in, const int* in_sizes, int n_in,
                              void* d_out, int out_size, void* d_ws, size_t ws_size,
                              hipStream_t stream) {
    const int*   edge_src  = (const int*)d_in[0];
    const int*   edge_dst  = (const int*)d_in[1];
    const int*   edge_type = (const int*)d_in[2];
    const int*   head      = (const int*)d_in[3];
    const int*   rela      = (const int*)d_in[4];
    const float* edge_norm = (const float*)d_in[5];
    const float* ent_emb   = (const float*)d_in[6];
    const float* rel_emb   = (const float*)d_in[7];
    const float* in_w      = (const float*)d_in[8];
    const float* out_w     = (const float*)d_in[9];
    const float* loop_w    = (const float*)d_in[10];
    const float* w_rel     = (const float*)d_in[11];
    const float* loop_rel  = (const float*)d_in[12];
    const float* conv_bias = (const float*)d_in[13];
    const float* bn_gamma  = (const float*)d_in[14];
    const float* bn_beta   = (const float*)d_in[15];
    const float* emb_ent   = (const float*)d_in[16];
    const float* ent_bias  = (const float*)d_in[17];
    float* score = (float*)d_out;

    // ---- workspace layout (bytes)
    char* w = (char*)d_ws;
    float*          agg    = (float*)w;                      w += (size_t)V * OUT * 4;       // 40,000,000
    unsigned short* Mtab   = (unsigned short*)w;             w += (size_t)NKEY * MT_SZ * 2;  // 42,598,400
    int*            perm1  = (int*)w;                        w += (size_t)E1MAX * 4;
    int*            keyss  = (int*)w;                        w += (size_t)E1MAX * 4;
    int*            perm2  = (int*)w;                        w += (size_t)E * 4;
    int*            inv1   = (int*)w;                        w += (size_t)E * 4;
    // zeroed region: hist1, cursor1, hist2, cursor2, colsum, colsq
    char* zbase = w;
    int*   hist1   = (int*)w;                                w += NKEY * 4;
    int*   cursor1 = (int*)w;                                w += NKEY * 4;
    int*   hist2   = (int*)w;                                w += V * 4;
    int*   cursor2 = (int*)w;                                w += V * 4;
    float* colsum  = (float*)w;                              w += OUT * 4;
    float* colsq   = (float*)w;                              w += OUT * 4;
    size_t zbytes = (size_t)(w - zbase);
    int*   start1  = (int*)w;                                w += (NKEY + 1) * 4;
    int*   start2  = (int*)w;                                w += (V + 4) * 4;
    int*   Edev    = (int*)w;                                w += 16;
    float* meanp   = (float*)w;                              w += OUT * 4;
    float* rstdp   = (float*)w;                              w += OUT * 4;
    float* Mloop   = (float*)w;                              w += (size_t)D * OUT * 4;
    float* r_out   = (float*)w;                              w += (size_t)R * OUT * 4;
    unsigned short* obj_bf = (unsigned short*)w;             w += (size_t)B * K2 * 2;
    unsigned short* emb_bf = (unsigned short*)d_ws;          // reuses agg region AFTER k_obj
    unsigned short* msg    = (unsigned short*)d_out;         // lives in d_out until k_dec2

    hipMemsetAsync(zbase, 0, zbytes, stream);
    hipMemsetAsync(perm1, 0xFF, (size_t)E1MAX * 4, stream);

    k_hist<<<(E + 255) / 256, 256, 0, stream>>>(edge_type, edge_dst, hist1, hist2);
    k_scan<<<1, 1024, 0, stream>>>(hist1, hist2, start1, start2, Edev);
    k_scatter<<<(E + 255) / 256, 256, 0, stream>>>(edge_type, edge_dst, start1, start2,
                                                   cursor1, cursor2, perm1, inv1, keyss, perm2);
    k_mtab<<<NKEY, 256, 0, stream>>>(rel_emb, in_w, out_w, Mtab);
    k_mloop<<<(D * OUT + 255) / 256, 256, 0, stream>>>(loop_rel, loop_w, Mloop);
    k_rout<<<(R * OUT + 255) / 256, 256, 0, stream>>>(rel_emb, w_rel, r_out);
    k_edgemm<<<E1MAX / 64, 256, 0, stream>>>(perm1, keyss, Edev, edge_src, edge_norm,
                                             ent_emb, Mtab, msg);
    k_agg<<<V / 4, 256, 0, stream>>>(start2, perm2, inv1, msg, agg);
    k_x2<<<(V + 31) / 32, 256, 0, stream>>>(ent_emb, Mloop, conv_bias, agg);
    k_stats<<<400, 256, 0, stream>>>(agg, colsum, colsq);
    k_finstats<<<1, 256, 0, stream>>>(colsum, colsq, meanp, rstdp);
    k_obj<<<B, 256, 0, stream>>>(head, rela, agg, meanp, rstdp, bn_gamma, bn_beta,
                                 r_out, obj_bf);
    k_cvt_emb<<<VPAD, 256, 0, stream>>>(emb_ent, emb_bf);
    dim3 dgrid(B / DEC_BM, VPAD / DEC_BN);
    k_dec2<<<dgrid, 512, 0, stream>>>(obj_bf, emb_bf, ent_bias, score);
}

// Round 4
// 772.678 us; speedup vs baseline: 5.5530x; 1.1466x over previous
//
#include <hip/hip_runtime.h>
#include <cstddef>

constexpr int V = 50000, E = 400000, R = 400, D = 100, OUT = 200, B = 1024;
constexpr int HALF = E / 2;
constexpr float EPS = 1e-5f;
constexpr int K2 = 232;        // decoder K pad (bf16)
constexpr int VPAD = 50176;    // 196*256
constexpr int NKEY = 800;      // (rel, side)
constexpr int E1MAX = 450560;  // E + NKEY*63 rounded up; /64 = 7040 (div by 8)
constexpr int MT_O = 208, MT_K = 128;
constexpr int MT_SZ = MT_O * MT_K;

typedef short bf16x8 __attribute__((ext_vector_type(8)));
typedef float f32x4  __attribute__((ext_vector_type(4)));
typedef unsigned short ushort8 __attribute__((ext_vector_type(8)));
typedef __attribute__((address_space(1))) const unsigned int guint_t;
typedef __attribute__((address_space(3))) unsigned int luint_t;

__device__ inline unsigned short f2bf(float x) {
    unsigned u = __float_as_uint(x);
    u = (u + 0x7fffu + ((u >> 16) & 1u)) >> 16;
    return (unsigned short)u;
}
__device__ inline float bf2f(unsigned short u) {
    return __uint_as_float(((unsigned)u) << 16);
}

// ---------------- Mloop[j][o] = sum_k loop_rel[(j+k)%D] * loop_w[k][o]
__global__ __launch_bounds__(256) void k_mloop(const float* __restrict__ loop_rel,
                                               const float* __restrict__ loop_w,
                                               float* __restrict__ Mloop) {
    int i = blockIdx.x * 256 + threadIdx.x;
    if (i >= D * OUT) return;
    int j = i / OUT, o = i % OUT;
    float s = 0.f;
    for (int k = 0; k < D; ++k) {
        int idx = j + k; if (idx >= D) idx -= D;
        s += loop_rel[idx] * loop_w[k * OUT + o];
    }
    Mloop[i] = s;
}

// ---------------- r_out = rel_emb @ w_rel  [R,OUT]
__global__ __launch_bounds__(256) void k_rout(const float* __restrict__ rel_emb,
                                              const float* __restrict__ w_rel,
                                              float* __restrict__ r_out) {
    int i = blockIdx.x * 256 + threadIdx.x;
    if (i >= R * OUT) return;
    int r = i / OUT, o = i % OUT;
    float s = 0.f;
    for (int k = 0; k < D; ++k) s += rel_emb[r * D + k] * w_rel[k * OUT + o];
    r_out[i] = s;
}

// ---------------- histograms
__global__ __launch_bounds__(256) void k_hist(const int* __restrict__ etyp,
                                              const int* __restrict__ edst,
                                              int* __restrict__ hist1,
                                              int* __restrict__ hist2) {
    int e = blockIdx.x * 256 + threadIdx.x;
    if (e >= E) return;
    int key = etyp[e] + (e < HALF ? 0 : R);
    atomicAdd(&hist1[key], 1);
    atomicAdd(&hist2[edst[e]], 1);
}

// ---------------- scans
__global__ __launch_bounds__(1024) void k_scan(const int* __restrict__ hist1,
                                               const int* __restrict__ hist2,
                                               int* __restrict__ start1,
                                               int* __restrict__ start2,
                                               int* __restrict__ Edev) {
    __shared__ int buf[1024];
    int t = threadIdx.x;
    int c = (t < NKEY) ? ((hist1[t] + 63) & ~63) : 0;
    buf[t] = c; __syncthreads();
    for (int off = 1; off < 1024; off <<= 1) {
        int x = (t >= off) ? buf[t - off] : 0; __syncthreads();
        buf[t] += x; __syncthreads();
    }
    if (t < NKEY) start1[t] = buf[t] - c;
    if (t == NKEY - 1) { start1[NKEY] = buf[t]; *Edev = buf[t]; }
    __syncthreads();
    const int STR = 49;
    int base = t * STR;
    int s = 0;
    for (int i = 0; i < STR; ++i) { int idx = base + i; s += (idx < V) ? hist2[idx] : 0; }
    buf[t] = s; __syncthreads();
    for (int off = 1; off < 1024; off <<= 1) {
        int x = (t >= off) ? buf[t - off] : 0; __syncthreads();
        buf[t] += x; __syncthreads();
    }
    int run = buf[t] - s;
    for (int i = 0; i < STR; ++i) {
        int idx = base + i;
        if (idx < V) { int h = hist2[idx]; start2[idx] = run; run += h; }
    }
    if (t == 0) start2[V] = E;
}

// ---------------- scatter: key-order perm1 + dst-order poslist (poslist[q] = key-order pos)
__global__ __launch_bounds__(256) void k_scatter(const int* __restrict__ etyp,
                                                 const int* __restrict__ edst,
                                                 const int* __restrict__ start1,
                                                 const int* __restrict__ start2,
                                                 int* __restrict__ cursor1,
                                                 int* __restrict__ cursor2,
                                                 int* __restrict__ perm1,
                                                 int* __restrict__ keys_sorted,
                                                 int* __restrict__ poslist) {
    int e = blockIdx.x * 256 + threadIdx.x;
    if (e >= E) return;
    int key = etyp[e] + (e < HALF ? 0 : R);
    int p = start1[key] + atomicAdd(&cursor1[key], 1);
    perm1[p] = e;
    keys_sorted[p] = key;
    int d = edst[e];
    int q = start2[d] + atomicAdd(&cursor2[d], 1);
    poslist[q] = p;
}

// ---------------- ent_bf[v][0..127] = bf16(ent_emb[v][k]), zero for k>=100
__global__ __launch_bounds__(256) void k_cvt_ent(const float* __restrict__ ent_emb,
                                                 unsigned short* __restrict__ ent_bf) {
    int i = blockIdx.x * 256 + threadIdx.x;  // V*16
    if (i >= V * 16) return;
    int v = i >> 4, c8 = i & 15;
    int c0 = c8 * 8;
    ushort8 o = (ushort8)0;
    if (c0 < 96) {
        float4 f0 = *(const float4*)&ent_emb[(size_t)v * D + c0];
        float4 f1 = *(const float4*)&ent_emb[(size_t)v * D + c0 + 4];
        o[0] = f2bf(f0.x); o[1] = f2bf(f0.y); o[2] = f2bf(f0.z); o[3] = f2bf(f0.w);
        o[4] = f2bf(f1.x); o[5] = f2bf(f1.y); o[6] = f2bf(f1.z); o[7] = f2bf(f1.w);
    } else if (c0 == 96) {
        float4 f0 = *(const float4*)&ent_emb[(size_t)v * D + 96];
        o[0] = f2bf(f0.x); o[1] = f2bf(f0.y); o[2] = f2bf(f0.z); o[3] = f2bf(f0.w);
    }
    *(ushort8*)&ent_bf[(size_t)v * 128 + c0] = o;
}

// ---------------- Mt[key][o][j] = sum_k r_rho[(j+k)%D] * W[k][o]  (bf16, padded)
__global__ __launch_bounds__(256) void k_mtab(const float* __restrict__ rel_emb,
                                              const float* __restrict__ in_w,
                                              const float* __restrict__ out_w,
                                              unsigned short* __restrict__ Mtab) {
    __shared__ __align__(16) float Wsh[D * OUT];  // 80 KB
    __shared__ float rsh[240];
    int key = blockIdx.x;
    int rho = (key < R) ? key : key - R;
    const float* __restrict__ W = (key < R) ? in_w : out_w;
    int t = threadIdx.x;
    for (int i = t * 4; i < D * OUT; i += 1024)
        *(float4*)&Wsh[i] = *(const float4*)&W[i];
    for (int s = t; s < 240; s += 256) {
        int sm = s; if (sm >= 200) sm -= 200; if (sm >= 100) sm -= 100;
        rsh[s] = rel_emb[rho * D + sm];
    }
    __syncthreads();
    unsigned short* MtK = Mtab + (size_t)key * MT_SZ;
    int jg = t >> 3, og = t & 7;
    int j0 = jg * 4;
    for (int go = og; go < 50; go += 8) {
        int o0 = go * 4;
        float acc[4][4] = {};  // [oi][ji]
        float r0 = rsh[j0], r1 = rsh[j0 + 1], r2 = rsh[j0 + 2], r3 = rsh[j0 + 3];
#pragma unroll 4
        for (int k = 0; k < D; ++k) {
            float4 w = *(const float4*)&Wsh[k * OUT + o0];
            float wv[4] = {w.x, w.y, w.z, w.w};
#pragma unroll
            for (int oi = 0; oi < 4; ++oi) {
                acc[oi][0] += r0 * wv[oi];
                acc[oi][1] += r1 * wv[oi];
                acc[oi][2] += r2 * wv[oi];
                acc[oi][3] += r3 * wv[oi];
            }
            r0 = r1; r1 = r2; r2 = r3; r3 = rsh[j0 + k + 4];
        }
#pragma unroll
        for (int ji = 0; ji < 4; ++ji)
            if (j0 + ji >= D) { acc[0][ji] = acc[1][ji] = acc[2][ji] = acc[3][ji] = 0.f; }
#pragma unroll
        for (int oi = 0; oi < 4; ++oi) {
            ushort4 pk;
            pk.x = f2bf(acc[oi][0]); pk.y = f2bf(acc[oi][1]);
            pk.z = f2bf(acc[oi][2]); pk.w = f2bf(acc[oi][3]);
            *(ushort4*)&MtK[(o0 + oi) * MT_K + j0] = pk;
        }
    }
    for (int i = t; i < 8 * 32; i += 256) {
        int row = 200 + (i >> 5), j4 = (i & 31) * 4;
        *(ushort4*)&MtK[row * MT_K + j4] = make_ushort4(0, 0, 0, 0);
    }
}

// ---------------- per-chunk MFMA: msg[p][o] = (h_src[p] @ Mt_key) * norm
__global__ __launch_bounds__(256, 2) void k_edgemm(const int* __restrict__ perm1,
                                                   const int* __restrict__ keys_sorted,
                                                   const int* __restrict__ Edev,
                                                   const int* __restrict__ esrc,
                                                   const float* __restrict__ enorm,
                                                   const unsigned short* __restrict__ ent_bf,
                                                   const unsigned short* __restrict__ Mtab,
                                                   unsigned short* __restrict__ msg) {
    __shared__ __align__(16) unsigned short MtL[MT_SZ];      // 53,248 B
    __shared__ __align__(16) unsigned short AtL[64 * MT_K];  // 16,384 B
    __shared__ float snrm[64];
    __shared__ int ssrc[64];
    int t = threadIdx.x, lane = t & 63, wid = t >> 6;
    // XCD-aware swizzle: each XCD gets a contiguous chunk range -> Mt L2 reuse
    int cpx = gridDim.x >> 3;
    int chunk = (blockIdx.x & 7) * cpx + (blockIdx.x >> 3);
    if (chunk * 64 >= *Edev) return;
    int key = keys_sorted[chunk * 64];
    const unsigned short* MtK = Mtab + (size_t)key * MT_SZ;
    if (t < 64) {
        int p = chunk * 64 + t;
        int e = perm1[p];
        ssrc[t] = (e >= 0) ? esrc[e] : 0;
        snrm[t] = (e >= 0) ? enorm[e] : 0.f;
    }
    // Mt staging (swizzled global source, linear LDS dest)
    for (int i = 0; i < 13; ++i) {
        int G0 = (wid * 13 + i) * 64;
        int G = G0 + lane;
        int o = G >> 4, g = G & 15;
        int gs = g ^ (o & 7);
        __builtin_amdgcn_global_load_lds((guint_t*)(MtK + o * MT_K + gs * 8),
                                         (luint_t*)(MtL + (size_t)G0 * 8), 16, 0, 0);
    }
    __syncthreads();  // ssrc visible (also drains Mt loads)
    // A staging direct from bf16 ent table (pre-swizzled source, linear dest)
    for (int i = 0; i < 4; ++i) {
        int base = (wid * 4 + i) * 1024;   // LDS byte offset, wave-uniform
        int Gb = base + lane * 16;
        int row = Gb >> 8;
        int g = (Gb >> 4) & 15;
        int gs = g ^ (row & 7);
        __builtin_amdgcn_global_load_lds((guint_t*)(ent_bf + (size_t)ssrc[row] * 128 + gs * 8),
                                         (luint_t*)((char*)AtL + base), 16, 0, 0);
    }
    __syncthreads();
    int erow = wid * 16 + (lane & 15);
    int kq = lane >> 4;
    f32x4 acc[13] = {};
    for (int ks = 0; ks < 4; ++ks) {
        int g = ks * 4 + kq;
        bf16x8 bfr = *(const bf16x8*)((const char*)AtL + erow * 256 + ((g ^ (erow & 7)) * 16));
#pragma unroll
        for (int of = 0; of < 13; ++of) {
            int orow = of * 16 + (lane & 15);
            bf16x8 afr = *(const bf16x8*)((const char*)MtL + orow * 256 + ((g ^ (orow & 7)) * 16));
            acc[of] = __builtin_amdgcn_mfma_f32_16x16x32_bf16(afr, bfr, acc[of], 0, 0, 0);
        }
    }
    float nr = snrm[erow];
    size_t rowbase = (size_t)(chunk * 64 + erow) * OUT;
#pragma unroll
    for (int of = 0; of < 13; ++of) {
        int o0 = of * 16 + kq * 4;
        if (o0 < OUT) {
            ushort4 pk;
            pk.x = f2bf(acc[of][0] * nr); pk.y = f2bf(acc[of][1] * nr);
            pk.z = f2bf(acc[of][2] * nr); pk.w = f2bf(acc[of][3] * nr);
            *(ushort4*)&msg[rowbase + o0] = pk;
        }
    }
}

// ---------------- gather-sum per dst (single indirection)
__global__ __launch_bounds__(256) void k_agg(const int* __restrict__ start2,
                                             const int* __restrict__ poslist,
                                             const unsigned short* __restrict__ msg,
                                             float* __restrict__ agg) {
    int wid = threadIdx.x >> 6, lane = threadIdx.x & 63;
    int v = blockIdx.x * 4 + wid;
    if (v >= V) return;
    int s = start2[v], epos = start2[v + 1];
    float acc[8] = {};
    for (int q = s; q < epos; ++q) {
        int p = poslist[q];
        if (lane < 25) {
            ushort8 m = *(const ushort8*)&msg[(size_t)p * OUT + lane * 8];
#pragma unroll
            for (int i = 0; i < 8; ++i) acc[i] += bf2f(m[i]);
        }
    }
    if (lane < 25) {
        float4 o0 = {acc[0], acc[1], acc[2], acc[3]};
        float4 o1 = {acc[4], acc[5], acc[6], acc[7]};
        *(float4*)&agg[(size_t)v * OUT + lane * 8] = o0;
        *(float4*)&agg[(size_t)v * OUT + lane * 8 + 4] = o1;
    }
}

// ---------------- x = (agg + ent_emb@Mloop)/3 + conv_bias (in place)
__global__ __launch_bounds__(256) void k_x2(const float* __restrict__ ent_emb,
                                            const float* __restrict__ Mloop,
                                            const float* __restrict__ conv_bias,
                                            float* __restrict__ x) {
    __shared__ float sat[100][36];
    int t = threadIdx.x;
    int v0 = blockIdx.x * 32;
    for (int i = t; i < 800; i += 256) {
        int kg = i >> 5, vv = i & 31;
        int vsafe = min(v0 + vv, V - 1);
        float4 a4 = *(const float4*)&ent_emb[(size_t)vsafe * D + kg * 4];
        sat[kg * 4 + 0][vv] = a4.x;
        sat[kg * 4 + 1][vv] = a4.y;
        sat[kg * 4 + 2][vv] = a4.z;
        sat[kg * 4 + 3][vv] = a4.w;
    }
    __syncthreads();
    if (t < 200) {
        int og = t % 50, eg = t / 50;
        int o0 = og * 4, vv0 = eg * 8;
        float acc[8][4] = {};
        for (int k = 0; k < D; ++k) {
            float4 w4 = *(const float4*)&Mloop[k * OUT + o0];
            float4 ca = *(const float4*)&sat[k][vv0];
            float4 cb = *(const float4*)&sat[k][vv0 + 4];
            float cc[8] = {ca.x, ca.y, ca.z, ca.w, cb.x, cb.y, cb.z, cb.w};
            float wv[4] = {w4.x, w4.y, w4.z, w4.w};
#pragma unroll
            for (int ee = 0; ee < 8; ++ee)
#pragma unroll
                for (int j = 0; j < 4; ++j) acc[ee][j] += cc[ee] * wv[j];
        }
        float4 bi = *(const float4*)&conv_bias[o0];
        float bv[4] = {bi.x, bi.y, bi.z, bi.w};
#pragma unroll
        for (int ee = 0; ee < 8; ++ee) {
            int v = v0 + vv0 + ee;
            if (v < V) {
                size_t base = (size_t)v * OUT + o0;
                float4 ag = *(const float4*)&x[base];
                float4 ov;
                ov.x = (ag.x + acc[ee][0]) * (1.f / 3.f) + bv[0];
                ov.y = (ag.y + acc[ee][1]) * (1.f / 3.f) + bv[1];
                ov.z = (ag.z + acc[ee][2]) * (1.f / 3.f) + bv[2];
                ov.w = (ag.w + acc[ee][3]) * (1.f / 3.f) + bv[3];
                *(float4*)&x[base] = ov;
            }
        }
    }
}

// ---------------- BN stats
__global__ __launch_bounds__(256) void k_stats(const float* __restrict__ x,
                                               float* __restrict__ colsum,
                                               float* __restrict__ colsq) {
    int g = blockIdx.x * 256 + threadIdx.x;
    int col = g % OUT;
    int r0 = g / OUT;
    float s = 0.f, sq = 0.f;
    for (int r = r0; r < V; r += 512) {
        float v = x[(size_t)r * OUT + col];
        s += v;
        sq += v * v;
    }
    atomicAdd(&colsum[col], s);
    atomicAdd(&colsq[col], sq);
}

__global__ void k_finstats(const float* __restrict__ colsum, const float* __restrict__ colsq,
                           float* __restrict__ mean, float* __restrict__ rstd) {
    int o = threadIdx.x;
    if (o >= OUT) return;
    float m = colsum[o] / (float)V;
    float var = colsq[o] / (float)V - m * m;
    mean[o] = m;
    rstd[o] = rsqrtf(var + EPS);
}

// ---------------- obj_bf = bf16(tanh(BN(x[head]))*r_out[rela]) zero-padded to K2
__global__ __launch_bounds__(256) void k_obj(const int* __restrict__ head,
                                             const int* __restrict__ rela,
                                             const float* __restrict__ x,
                                             const float* __restrict__ mean,
                                             const float* __restrict__ rstd,
                                             const float* __restrict__ gamma,
                                             const float* __restrict__ beta,
                                             const float* __restrict__ r_out,
                                             unsigned short* __restrict__ obj_bf) {
    int b = blockIdx.x, t = threadIdx.x;
    if (t >= K2) return;
    float v = 0.f;
    if (t < OUT) {
        int h = head[b], r = rela[b];
        float val = (x[(size_t)h * OUT + t] - mean[t]) * rstd[t] * gamma[t] + beta[t];
        val = tanhf(val);
        v = val * r_out[r * OUT + t];
    }
    obj_bf[(size_t)b * K2 + t] = f2bf(v);
}

// ---------------- emb_bf padded (vectorized)
__global__ __launch_bounds__(256) void k_cvt_emb(const float* __restrict__ emb_ent,
                                                 unsigned short* __restrict__ emb_bf) {
    int i = blockIdx.x * 256 + threadIdx.x;  // VPAD*29
    if (i >= VPAD * 29) return;
    int v = i / 29, c8 = i % 29;
    int c0 = c8 * 8;
    ushort8 o = (ushort8)0;
    if (v < V && c0 < 200) {
        float4 f0 = *(const float4*)&emb_ent[(size_t)v * OUT + c0];
        float4 f1 = *(const float4*)&emb_ent[(size_t)v * OUT + c0 + 4];
        o[0] = f2bf(f0.x); o[1] = f2bf(f0.y); o[2] = f2bf(f0.z); o[3] = f2bf(f0.w);
        o[4] = f2bf(f1.x); o[5] = f2bf(f1.y); o[6] = f2bf(f1.z); o[7] = f2bf(f1.w);
    }
    *(ushort8*)&emb_bf[(size_t)v * K2 + c0] = o;
}

// ---------------- decoder (bf16 MFMA)
constexpr int DEC_BM = 64, DEC_BN = 256;

__global__ __launch_bounds__(512) void k_dec2(const unsigned short* __restrict__ obj_bf,
                                              const unsigned short* __restrict__ emb_bf,
                                              const float* __restrict__ ent_bias,
                                              float* __restrict__ score) {
    __shared__ __align__(16) unsigned short As[DEC_BM * K2];
    __shared__ __align__(16) unsigned short Bs[DEC_BN * K2];
    int t = threadIdx.x;
    int lane = t & 63, wid = t >> 6;
    int b0 = blockIdx.x * DEC_BM;
    int v0 = blockIdx.y * DEC_BN;
    const unsigned short* gA = obj_bf + (size_t)b0 * K2;
    const unsigned short* gB = emb_bf + (size_t)v0 * K2;
    for (int c = wid; c < 29; c += 8) {
        __builtin_amdgcn_global_load_lds((guint_t*)(gA + c * 512 + lane * 8),
                                         (luint_t*)(As + c * 512), 16, 0, 0);
    }
    for (int c = wid; c < 116; c += 8) {
        __builtin_amdgcn_global_load_lds((guint_t*)(gB + c * 512 + lane * 8),
                                         (luint_t*)(Bs + c * 512), 16, 0, 0);
    }
    __syncthreads();
    int wm = wid & 1, wn = wid >> 1;
    int rA = wm * 32 + (lane & 15);
    int rB = wn * 64 + (lane & 15);
    int kc = (lane >> 4) * 8;
    f32x4 acc[2][4] = {};
    for (int ks = 0; ks < 7; ++ks) {
        int kof = ks * 32 + kc;
        bf16x8 a0 = *(const bf16x8*)&As[(rA + 0) * K2 + kof];
        bf16x8 a1 = *(const bf16x8*)&As[(rA + 16) * K2 + kof];
        bf16x8 bb0 = *(const bf16x8*)&Bs[(rB + 0) * K2 + kof];
        bf16x8 bb1 = *(const bf16x8*)&Bs[(rB + 16) * K2 + kof];
        bf16x8 bb2 = *(const bf16x8*)&Bs[(rB + 32) * K2 + kof];
        bf16x8 bb3 = *(const bf16x8*)&Bs[(rB + 48) * K2 + kof];
        acc[0][0] = __builtin_amdgcn_mfma_f32_16x16x32_bf16(a0, bb0, acc[0][0], 0, 0, 0);
        acc[0][1] = __builtin_amdgcn_mfma_f32_16x16x32_bf16(a0, bb1, acc[0][1], 0, 0, 0);
        acc[0][2] = __builtin_amdgcn_mfma_f32_16x16x32_bf16(a0, bb2, acc[0][2], 0, 0, 0);
        acc[0][3] = __builtin_amdgcn_mfma_f32_16x16x32_bf16(a0, bb3, acc[0][3], 0, 0, 0);
        acc[1][0] = __builtin_amdgcn_mfma_f32_16x16x32_bf16(a1, bb0, acc[1][0], 0, 0, 0);
        acc[1][1] = __builtin_amdgcn_mfma_f32_16x16x32_bf16(a1, bb1, acc[1][1], 0, 0, 0);
        acc[1][2] = __builtin_amdgcn_mfma_f32_16x16x32_bf16(a1, bb2, acc[1][2], 0, 0, 0);
        acc[1][3] = __builtin_amdgcn_mfma_f32_16x16x32_bf16(a1, bb3, acc[1][3], 0, 0, 0);
    }
#pragma unroll
    for (int nf = 0; nf < 4; ++nf) {
        int v = v0 + wn * 64 + nf * 16 + (lane & 15);
        if (v >= V) continue;
        float bias = ent_bias[v];
#pragma unroll
        for (int mf = 0; mf < 2; ++mf) {
            int brow = b0 + wm * 32 + mf * 16 + (lane >> 4) * 4;
            f32x4 a = acc[mf][nf];
#pragma unroll
            for (int i = 0; i < 4; ++i) {
                float val = a[i] + bias;
                score[(size_t)(brow + i) * V + v] = 1.f / (1.f + __expf(-val));
            }
        }
    }
}

extern "C" void kernel_launch(void* const* d_in, const int* in_sizes, int n_in,
                              void* d_out, int out_size, void* d_ws, size_t ws_size,
                              hipStream_t stream) {
    const int*   edge_src  = (const int*)d_in[0];
    const int*   edge_dst  = (const int*)d_in[1];
    const int*   edge_type = (const int*)d_in[2];
    const int*   head      = (const int*)d_in[3];
    const int*   rela      = (const int*)d_in[4];
    const float* edge_norm = (const float*)d_in[5];
    const float* ent_emb   = (const float*)d_in[6];
    const float* rel_emb   = (const float*)d_in[7];
    const float* in_w      = (const float*)d_in[8];
    const float* out_w     = (const float*)d_in[9];
    const float* loop_w    = (const float*)d_in[10];
    const float* w_rel     = (const float*)d_in[11];
    const float* loop_rel  = (const float*)d_in[12];
    const float* conv_bias = (const float*)d_in[13];
    const float* bn_gamma  = (const float*)d_in[14];
    const float* bn_beta   = (const float*)d_in[15];
    const float* emb_ent   = (const float*)d_in[16];
    const float* ent_bias  = (const float*)d_in[17];
    float* score = (float*)d_out;

    // ---- workspace layout
    char* w = (char*)d_ws;
    float*          agg    = (float*)w;                      w += (size_t)V * OUT * 4;   // 40 MB
    unsigned short* Mtab   = (unsigned short*)w;             w += (size_t)NKEY * MT_SZ * 2;
    int*            perm1  = (int*)w;                        w += (size_t)E1MAX * 4;
    int*            keyss  = (int*)w;                        w += (size_t)E1MAX * 4;
    int*            poslist= (int*)w;                        w += (size_t)E * 4;
    char* zbase = w;
    int*   hist1   = (int*)w;                                w += NKEY * 4;
    int*   cursor1 = (int*)w;                                w += NKEY * 4;
    int*   hist2   = (int*)w;                                w += V * 4;
    int*   cursor2 = (int*)w;                                w += V * 4;
    float* colsum  = (float*)w;                              w += OUT * 4;
    float* colsq   = (float*)w;                              w += OUT * 4;
    size_t zbytes = (size_t)(w - zbase);
    int*   start1  = (int*)w;                                w += (NKEY + 1) * 4;
    int*   start2  = (int*)w;                                w += (V + 4) * 4;
    int*   Edev    = (int*)w;                                w += 16;
    float* meanp   = (float*)w;                              w += OUT * 4;
    float* rstdp   = (float*)w;                              w += OUT * 4;
    float* Mloop   = (float*)w;                              w += (size_t)D * OUT * 4;
    float* r_out   = (float*)w;                              w += (size_t)R * OUT * 4;
    unsigned short* obj_bf = (unsigned short*)w;             w += (size_t)B * K2 * 2;
    // overlays on agg's region (strictly ordered by stream):
    unsigned short* ent_bf = (unsigned short*)agg;   // V*128 ushorts (12.8 MB); dead after k_edgemm
    unsigned short* emb_bf = (unsigned short*)agg;   // VPAD*K2 ushorts; written after k_obj
    unsigned short* msg    = (unsigned short*)d_out; // E1MAX*200 ushorts; dead after k_agg

    hipMemsetAsync(zbase, 0, zbytes, stream);
    hipMemsetAsync(perm1, 0xFF, (size_t)E1MAX * 4, stream);

    k_hist<<<(E + 255) / 256, 256, 0, stream>>>(edge_type, edge_dst, hist1, hist2);
    k_scan<<<1, 1024, 0, stream>>>(hist1, hist2, start1, start2, Edev);
    k_scatter<<<(E + 255) / 256, 256, 0, stream>>>(edge_type, edge_dst, start1, start2,
                                                   cursor1, cursor2, perm1, keyss, poslist);
    k_mtab<<<NKEY, 256, 0, stream>>>(rel_emb, in_w, out_w, Mtab);
    k_mloop<<<(D * OUT + 255) / 256, 256, 0, stream>>>(loop_rel, loop_w, Mloop);
    k_rout<<<(R * OUT + 255) / 256, 256, 0, stream>>>(rel_emb, w_rel, r_out);
    k_cvt_ent<<<(V * 16 + 255) / 256, 256, 0, stream>>>(ent_emb, ent_bf);
    k_edgemm<<<E1MAX / 64, 256, 0, stream>>>(perm1, keyss, Edev, edge_src, edge_norm,
                                             ent_bf, Mtab, msg);
    k_agg<<<V / 4, 256, 0, stream>>>(start2, poslist, msg, agg);
    k_x2<<<(V + 31) / 32, 256, 0, stream>>>(ent_emb, Mloop, conv_bias, agg);
    k_stats<<<400, 256, 0, stream>>>(agg, colsum, colsq);
    k_finstats<<<1, 256, 0, stream>>>(colsum, colsq, meanp, rstdp);
    k_obj<<<B, 256, 0, stream>>>(head, rela, agg, meanp, rstdp, bn_gamma, bn_beta,
                                 r_out, obj_bf);
    k_cvt_emb<<<(VPAD * 29 + 255) / 256, 256, 0, stream>>>(emb_ent, emb_bf);
    dim3 dgrid(B / DEC_BM, VPAD / DEC_BN);
    k_dec2<<<dgrid, 512, 0, stream>>>(obj_bf, emb_bf, ent_bias, score);
}

// Round 5
// 587.260 us; speedup vs baseline: 7.3063x; 1.3157x over previous
//
#include <hip/hip_runtime.h>
#include <cstddef>

constexpr int V = 50000, E = 400000, R = 400, D = 100, OUT = 200, B = 1024;
constexpr int HALF = E / 2;
constexpr float EPS = 1e-5f;
constexpr int K2 = 232;        // decoder K pad (bf16)
constexpr int VPAD = 50176;    // 196*256
constexpr int NKEY = 800;      // (rel, side)
constexpr int E1MAX = 450560;  // E + NKEY*63 rounded up; /64 = 7040 (div by 8)
constexpr int MT_O = 208, MT_K = 128;
constexpr int MT_SZ = MT_O * MT_K;
constexpr int NB2 = 196;       // coarse dst buckets (dst>>8), 50000>>8 = 195 max
constexpr int BCAP = 2560;     // bucket capacity (mean 2041, std 45 -> 11 sigma)

typedef short bf16x8 __attribute__((ext_vector_type(8)));
typedef float f32x4  __attribute__((ext_vector_type(4)));
typedef unsigned short ushort8 __attribute__((ext_vector_type(8)));
typedef __attribute__((address_space(1))) const unsigned int guint_t;
typedef __attribute__((address_space(3))) unsigned int luint_t;

__device__ inline unsigned short f2bf(float x) {
    unsigned u = __float_as_uint(x);
    u = (u + 0x7fffu + ((u >> 16) & 1u)) >> 16;
    return (unsigned short)u;
}
__device__ inline float bf2f(unsigned short u) {
    return __uint_as_float(((unsigned)u) << 16);
}

// ---------------- Mloop[j][o] = sum_k loop_rel[(j+k)%D] * loop_w[k][o]
__global__ __launch_bounds__(256) void k_mloop(const float* __restrict__ loop_rel,
                                               const float* __restrict__ loop_w,
                                               float* __restrict__ Mloop) {
    int i = blockIdx.x * 256 + threadIdx.x;
    if (i >= D * OUT) return;
    int j = i / OUT, o = i % OUT;
    float s = 0.f;
    for (int k = 0; k < D; ++k) {
        int idx = j + k; if (idx >= D) idx -= D;
        s += loop_rel[idx] * loop_w[k * OUT + o];
    }
    Mloop[i] = s;
}

// ---------------- r_out = rel_emb @ w_rel  [R,OUT]
__global__ __launch_bounds__(256) void k_rout(const float* __restrict__ rel_emb,
                                              const float* __restrict__ w_rel,
                                              float* __restrict__ r_out) {
    int i = blockIdx.x * 256 + threadIdx.x;
    if (i >= R * OUT) return;
    int r = i / OUT, o = i % OUT;
    float s = 0.f;
    for (int k = 0; k < D; ++k) s += rel_emb[r * D + k] * w_rel[k * OUT + o];
    r_out[i] = s;
}

// ---------------- histograms (hist1 LDS-aggregated; hist2 per-edge)
__global__ __launch_bounds__(256) void k_hist(const int* __restrict__ etyp,
                                              const int* __restrict__ edst,
                                              int* __restrict__ hist1,
                                              int* __restrict__ hist2) {
    __shared__ int lh[NKEY];
    int t = threadIdx.x;
    for (int i = t; i < NKEY; i += 256) lh[i] = 0;
    __syncthreads();
    for (int e = blockIdx.x * 256 + t; e < E; e += gridDim.x * 256) {
        int key = etyp[e] + (e < HALF ? 0 : R);
        atomicAdd(&lh[key], 1);
        atomicAdd(&hist2[edst[e]], 1);
    }
    __syncthreads();
    for (int i = t; i < NKEY; i += 256) {
        int c = lh[i];
        if (c) atomicAdd(&hist1[i], c);
    }
}

// ---------------- scans
__global__ __launch_bounds__(1024) void k_scan(const int* __restrict__ hist1,
                                               const int* __restrict__ hist2,
                                               int* __restrict__ start1,
                                               int* __restrict__ start2,
                                               int* __restrict__ Edev) {
    __shared__ int buf[1024];
    int t = threadIdx.x;
    int c = (t < NKEY) ? ((hist1[t] + 63) & ~63) : 0;
    buf[t] = c; __syncthreads();
    for (int off = 1; off < 1024; off <<= 1) {
        int x = (t >= off) ? buf[t - off] : 0; __syncthreads();
        buf[t] += x; __syncthreads();
    }
    if (t < NKEY) start1[t] = buf[t] - c;
    if (t == NKEY - 1) { start1[NKEY] = buf[t]; *Edev = buf[t]; }
    __syncthreads();
    const int STR = 49;
    int base = t * STR;
    int s = 0;
    for (int i = 0; i < STR; ++i) { int idx = base + i; s += (idx < V) ? hist2[idx] : 0; }
    buf[t] = s; __syncthreads();
    for (int off = 1; off < 1024; off <<= 1) {
        int x = (t >= off) ? buf[t - off] : 0; __syncthreads();
        buf[t] += x; __syncthreads();
    }
    int run = buf[t] - s;
    for (int i = 0; i < STR; ++i) {
        int idx = base + i;
        if (idx < V) { int h = hist2[idx]; start2[idx] = run; run += h; }
    }
    if (t == 0) start2[V] = E;
}

// ---------------- key-binned scatter: perm1[p] = e | key<<19 ; pos_of_e[e] = p
__global__ __launch_bounds__(1024) void k_binkey(const int* __restrict__ etyp,
                                                 const int* __restrict__ start1,
                                                 int* __restrict__ cursor1,
                                                 unsigned* __restrict__ perm1,
                                                 int* __restrict__ pos_of_e) {
    __shared__ int lhist[NKEY], lbase[NKEY], lcnt[NKEY];
    int t = threadIdx.x;
    int e0 = blockIdx.x * 8192;
    for (int i = t; i < NKEY; i += 1024) { lhist[i] = 0; lcnt[i] = 0; }
    __syncthreads();
    for (int i = t; i < 8192; i += 1024) {
        int e = e0 + i;
        if (e < E) {
            int key = etyp[e] + (e < HALF ? 0 : R);
            atomicAdd(&lhist[key], 1);
        }
    }
    __syncthreads();
    for (int i = t; i < NKEY; i += 1024) {
        int c = lhist[i];
        lbase[i] = c ? (start1[i] + atomicAdd(&cursor1[i], c)) : 0;
    }
    __syncthreads();
    for (int i = t; i < 8192; i += 1024) {
        int e = e0 + i;
        if (e < E) {
            int key = etyp[e] + (e < HALF ? 0 : R);
            int r = atomicAdd(&lcnt[key], 1);
            int p = lbase[key] + r;
            perm1[p] = (unsigned)e | ((unsigned)key << 19);
            pos_of_e[e] = p;
        }
    }
}

// ---------------- coarse dst binning: pairs[bucket][slot] = (d, p)
__global__ __launch_bounds__(1024) void k_bindst1(const int* __restrict__ edst,
                                                  const int* __restrict__ pos_of_e,
                                                  int* __restrict__ cursor196,
                                                  uint2* __restrict__ pairs) {
    __shared__ int chist[NB2], cbase[NB2], ccnt[NB2];
    int t = threadIdx.x;
    int e0 = blockIdx.x * 8192;
    for (int i = t; i < NB2; i += 1024) { chist[i] = 0; ccnt[i] = 0; }
    __syncthreads();
    for (int i = t; i < 8192; i += 1024) {
        int e = e0 + i;
        if (e < E) atomicAdd(&chist[edst[e] >> 8], 1);
    }
    __syncthreads();
    for (int i = t; i < NB2; i += 1024) {
        int c = chist[i];
        cbase[i] = c ? atomicAdd(&cursor196[i], c) : 0;
    }
    __syncthreads();
    for (int i = t; i < 8192; i += 1024) {
        int e = e0 + i;
        if (e < E) {
            int d = edst[e];
            int ld = d >> 8;
            int r = atomicAdd(&ccnt[ld], 1);
            int slot = cbase[ld] + r;
            if (slot < BCAP)
                pairs[(size_t)ld * BCAP + slot] = make_uint2((unsigned)d, (unsigned)pos_of_e[e]);
        }
    }
}

// ---------------- exact dst ranking within bucket -> coalesced poslist writes
__global__ __launch_bounds__(256) void k_bindst2(const int* __restrict__ cursor196,
                                                 const uint2* __restrict__ pairs,
                                                 const int* __restrict__ start2,
                                                 int* __restrict__ poslist) {
    __shared__ int lcnt[256];
    int b = blockIdx.x, t = threadIdx.x;
    lcnt[t] = 0;
    __syncthreads();
    int n = cursor196[b];
    if (n > BCAP) n = BCAP;
    for (int i = t; i < n; i += 256) {
        uint2 pr = pairs[(size_t)b * BCAP + i];
        int d = (int)pr.x;
        int r = atomicAdd(&lcnt[d - b * 256], 1);
        poslist[start2[d] + r] = (int)pr.y;
    }
}

// ---------------- ent_bf[v][0..127] = bf16(ent_emb[v][k]), zero for k>=100
__global__ __launch_bounds__(256) void k_cvt_ent(const float* __restrict__ ent_emb,
                                                 unsigned short* __restrict__ ent_bf) {
    int i = blockIdx.x * 256 + threadIdx.x;  // V*16
    if (i >= V * 16) return;
    int v = i >> 4, c8 = i & 15;
    int c0 = c8 * 8;
    ushort8 o = (ushort8)0;
    if (c0 < 96) {
        float4 f0 = *(const float4*)&ent_emb[(size_t)v * D + c0];
        float4 f1 = *(const float4*)&ent_emb[(size_t)v * D + c0 + 4];
        o[0] = f2bf(f0.x); o[1] = f2bf(f0.y); o[2] = f2bf(f0.z); o[3] = f2bf(f0.w);
        o[4] = f2bf(f1.x); o[5] = f2bf(f1.y); o[6] = f2bf(f1.z); o[7] = f2bf(f1.w);
    } else if (c0 == 96) {
        float4 f0 = *(const float4*)&ent_emb[(size_t)v * D + 96];
        o[0] = f2bf(f0.x); o[1] = f2bf(f0.y); o[2] = f2bf(f0.z); o[3] = f2bf(f0.w);
    }
    *(ushort8*)&ent_bf[(size_t)v * 128 + c0] = o;
}

// ---------------- Mt[key][o][j] = sum_k r_rho[(j+k)%D] * W[k][o]  (bf16, padded)
__global__ __launch_bounds__(256) void k_mtab(const float* __restrict__ rel_emb,
                                              const float* __restrict__ in_w,
                                              const float* __restrict__ out_w,
                                              unsigned short* __restrict__ Mtab) {
    __shared__ __align__(16) float Wsh[D * OUT];  // 80 KB
    __shared__ float rsh[240];
    int key = blockIdx.x;
    int rho = (key < R) ? key : key - R;
    const float* __restrict__ W = (key < R) ? in_w : out_w;
    int t = threadIdx.x;
    for (int i = t * 4; i < D * OUT; i += 1024)
        *(float4*)&Wsh[i] = *(const float4*)&W[i];
    for (int s = t; s < 240; s += 256) {
        int sm = s; if (sm >= 200) sm -= 200; if (sm >= 100) sm -= 100;
        rsh[s] = rel_emb[rho * D + sm];
    }
    __syncthreads();
    unsigned short* MtK = Mtab + (size_t)key * MT_SZ;
    int jg = t >> 3, og = t & 7;
    int j0 = jg * 4;
    for (int go = og; go < 50; go += 8) {
        int o0 = go * 4;
        float acc[4][4] = {};  // [oi][ji]
        float r0 = rsh[j0], r1 = rsh[j0 + 1], r2 = rsh[j0 + 2], r3 = rsh[j0 + 3];
#pragma unroll 4
        for (int k = 0; k < D; ++k) {
            float4 w = *(const float4*)&Wsh[k * OUT + o0];
            float wv[4] = {w.x, w.y, w.z, w.w};
#pragma unroll
            for (int oi = 0; oi < 4; ++oi) {
                acc[oi][0] += r0 * wv[oi];
                acc[oi][1] += r1 * wv[oi];
                acc[oi][2] += r2 * wv[oi];
                acc[oi][3] += r3 * wv[oi];
            }
            r0 = r1; r1 = r2; r2 = r3; r3 = rsh[j0 + k + 4];
        }
#pragma unroll
        for (int ji = 0; ji < 4; ++ji)
            if (j0 + ji >= D) { acc[0][ji] = acc[1][ji] = acc[2][ji] = acc[3][ji] = 0.f; }
#pragma unroll
        for (int oi = 0; oi < 4; ++oi) {
            ushort4 pk;
            pk.x = f2bf(acc[oi][0]); pk.y = f2bf(acc[oi][1]);
            pk.z = f2bf(acc[oi][2]); pk.w = f2bf(acc[oi][3]);
            *(ushort4*)&MtK[(o0 + oi) * MT_K + j0] = pk;
        }
    }
    for (int i = t; i < 8 * 32; i += 256) {
        int row = 200 + (i >> 5), j4 = (i & 31) * 4;
        *(ushort4*)&MtK[row * MT_K + j4] = make_ushort4(0, 0, 0, 0);
    }
}

// ---------------- per-chunk MFMA: msg[p][o] = (h_src[p] @ Mt_key) * norm
__global__ __launch_bounds__(256, 2) void k_edgemm(const unsigned* __restrict__ perm1,
                                                   const int* __restrict__ Edev,
                                                   const int* __restrict__ esrc,
                                                   const float* __restrict__ enorm,
                                                   const unsigned short* __restrict__ ent_bf,
                                                   const unsigned short* __restrict__ Mtab,
                                                   unsigned short* __restrict__ msg) {
    __shared__ __align__(16) unsigned short MtL[MT_SZ];      // 53,248 B
    __shared__ __align__(16) unsigned short AtL[64 * MT_K];  // 16,384 B
    __shared__ float snrm[64];
    __shared__ int ssrc[64];
    int t = threadIdx.x, lane = t & 63, wid = t >> 6;
    // XCD-aware swizzle: each XCD gets contiguous chunks -> Mtab L2 reuse
    int cpx = gridDim.x >> 3;
    int chunk = (blockIdx.x & 7) * cpx + (blockIdx.x >> 3);
    if (chunk * 64 >= *Edev) return;
    unsigned kv = perm1[chunk * 64];   // chunk base is always a real edge
    int key = (int)(kv >> 19);
    const unsigned short* MtK = Mtab + (size_t)key * MT_SZ;
    if (t < 64) {
        unsigned val = perm1[chunk * 64 + t];
        int e = (int)(val & 0x7FFFFu);
        bool ok = (val != 0xFFFFFFFFu);
        ssrc[t] = ok ? esrc[e] : 0;
        snrm[t] = ok ? enorm[e] : 0.f;
    }
    // Mt staging (swizzled global source, linear LDS dest)
    for (int i = 0; i < 13; ++i) {
        int G0 = (wid * 13 + i) * 64;
        int G = G0 + lane;
        int o = G >> 4, g = G & 15;
        int gs = g ^ (o & 7);
        __builtin_amdgcn_global_load_lds((guint_t*)(MtK + o * MT_K + gs * 8),
                                         (luint_t*)(MtL + (size_t)G0 * 8), 16, 0, 0);
    }
    __syncthreads();  // ssrc visible (also drains Mt loads)
    // A staging direct from bf16 ent table (pre-swizzled source, linear dest)
    for (int i = 0; i < 4; ++i) {
        int base = (wid * 4 + i) * 1024;   // LDS byte offset, wave-uniform
        int Gb = base + lane * 16;
        int row = Gb >> 8;
        int g = (Gb >> 4) & 15;
        int gs = g ^ (row & 7);
        __builtin_amdgcn_global_load_lds((guint_t*)(ent_bf + (size_t)ssrc[row] * 128 + gs * 8),
                                         (luint_t*)((char*)AtL + base), 16, 0, 0);
    }
    __syncthreads();
    int erow = wid * 16 + (lane & 15);
    int kq = lane >> 4;
    f32x4 acc[13] = {};
    for (int ks = 0; ks < 4; ++ks) {
        int g = ks * 4 + kq;
        bf16x8 bfr = *(const bf16x8*)((const char*)AtL + erow * 256 + ((g ^ (erow & 7)) * 16));
#pragma unroll
        for (int of = 0; of < 13; ++of) {
            int orow = of * 16 + (lane & 15);
            bf16x8 afr = *(const bf16x8*)((const char*)MtL + orow * 256 + ((g ^ (orow & 7)) * 16));
            acc[of] = __builtin_amdgcn_mfma_f32_16x16x32_bf16(afr, bfr, acc[of], 0, 0, 0);
        }
    }
    float nr = snrm[erow];
    size_t rowbase = (size_t)(chunk * 64 + erow) * OUT;
#pragma unroll
    for (int of = 0; of < 13; ++of) {
        int o0 = of * 16 + kq * 4;
        if (o0 < OUT) {
            ushort4 pk;
            pk.x = f2bf(acc[of][0] * nr); pk.y = f2bf(acc[of][1] * nr);
            pk.z = f2bf(acc[of][2] * nr); pk.w = f2bf(acc[of][3] * nr);
            *(ushort4*)&msg[rowbase + o0] = pk;
        }
    }
}

// ---------------- gather-sum per dst (2 rows per iter, 50 active lanes)
__global__ __launch_bounds__(256) void k_agg(const int* __restrict__ start2,
                                             const int* __restrict__ poslist,
                                             const unsigned short* __restrict__ msg,
                                             float* __restrict__ agg) {
    int wid = threadIdx.x >> 6, lane = threadIdx.x & 63;
    int v = blockIdx.x * 4 + wid;
    if (v >= V) return;
    int s = start2[v], epos = start2[v + 1];
    int half = (lane >= 25 && lane < 50) ? 1 : 0;
    int c = lane - half * 25;
    bool act = lane < 50;
    float acc[8] = {};
    for (int q = s; q < epos; q += 2) {
        int qq = q + half;
        if (act && qq < epos) {
            int p = poslist[qq];
            ushort8 m = *(const ushort8*)&msg[(size_t)p * OUT + c * 8];
#pragma unroll
            for (int i = 0; i < 8; ++i) acc[i] += bf2f(m[i]);
        }
    }
    int src = lane + 25 < 64 ? lane + 25 : 63;
#pragma unroll
    for (int i = 0; i < 8; ++i) {
        float o = __shfl(acc[i], src);
        if (lane < 25) acc[i] += o;
    }
    if (lane < 25) {
        float4 o0 = {acc[0], acc[1], acc[2], acc[3]};
        float4 o1 = {acc[4], acc[5], acc[6], acc[7]};
        *(float4*)&agg[(size_t)v * OUT + lane * 8] = o0;
        *(float4*)&agg[(size_t)v * OUT + lane * 8 + 4] = o1;
    }
}

// ---------------- x = (agg + ent_emb@Mloop)/3 + conv_bias (in place)
__global__ __launch_bounds__(256) void k_x2(const float* __restrict__ ent_emb,
                                            const float* __restrict__ Mloop,
                                            const float* __restrict__ conv_bias,
                                            float* __restrict__ x) {
    __shared__ float sat[100][36];
    int t = threadIdx.x;
    int v0 = blockIdx.x * 32;
    for (int i = t; i < 800; i += 256) {
        int kg = i >> 5, vv = i & 31;
        int vsafe = min(v0 + vv, V - 1);
        float4 a4 = *(const float4*)&ent_emb[(size_t)vsafe * D + kg * 4];
        sat[kg * 4 + 0][vv] = a4.x;
        sat[kg * 4 + 1][vv] = a4.y;
        sat[kg * 4 + 2][vv] = a4.z;
        sat[kg * 4 + 3][vv] = a4.w;
    }
    __syncthreads();
    if (t < 200) {
        int og = t % 50, eg = t / 50;
        int o0 = og * 4, vv0 = eg * 8;
        float acc[8][4] = {};
        for (int k = 0; k < D; ++k) {
            float4 w4 = *(const float4*)&Mloop[k * OUT + o0];
            float4 ca = *(const float4*)&sat[k][vv0];
            float4 cb = *(const float4*)&sat[k][vv0 + 4];
            float cc[8] = {ca.x, ca.y, ca.z, ca.w, cb.x, cb.y, cb.z, cb.w};
            float wv[4] = {w4.x, w4.y, w4.z, w4.w};
#pragma unroll
            for (int ee = 0; ee < 8; ++ee)
#pragma unroll
                for (int j = 0; j < 4; ++j) acc[ee][j] += cc[ee] * wv[j];
        }
        float4 bi = *(const float4*)&conv_bias[o0];
        float bv[4] = {bi.x, bi.y, bi.z, bi.w};
#pragma unroll
        for (int ee = 0; ee < 8; ++ee) {
            int v = v0 + vv0 + ee;
            if (v < V) {
                size_t base = (size_t)v * OUT + o0;
                float4 ag = *(const float4*)&x[base];
                float4 ov;
                ov.x = (ag.x + acc[ee][0]) * (1.f / 3.f) + bv[0];
                ov.y = (ag.y + acc[ee][1]) * (1.f / 3.f) + bv[1];
                ov.z = (ag.z + acc[ee][2]) * (1.f / 3.f) + bv[2];
                ov.w = (ag.w + acc[ee][3]) * (1.f / 3.f) + bv[3];
                *(float4*)&x[base] = ov;
            }
        }
    }
}

// ---------------- BN stats
__global__ __launch_bounds__(256) void k_stats(const float* __restrict__ x,
                                               float* __restrict__ colsum,
                                               float* __restrict__ colsq) {
    int g = blockIdx.x * 256 + threadIdx.x;
    int col = g % OUT;
    int r0 = g / OUT;
    float s = 0.f, sq = 0.f;
    for (int r = r0; r < V; r += 512) {
        float v = x[(size_t)r * OUT + col];
        s += v;
        sq += v * v;
    }
    atomicAdd(&colsum[col], s);
    atomicAdd(&colsq[col], sq);
}

__global__ void k_finstats(const float* __restrict__ colsum, const float* __restrict__ colsq,
                           float* __restrict__ mean, float* __restrict__ rstd) {
    int o = threadIdx.x;
    if (o >= OUT) return;
    float m = colsum[o] / (float)V;
    float var = colsq[o] / (float)V - m * m;
    mean[o] = m;
    rstd[o] = rsqrtf(var + EPS);
}

// ---------------- obj_bf = bf16(tanh(BN(x[head]))*r_out[rela]) zero-padded to K2
__global__ __launch_bounds__(256) void k_obj(const int* __restrict__ head,
                                             const int* __restrict__ rela,
                                             const float* __restrict__ x,
                                             const float* __restrict__ mean,
                                             const float* __restrict__ rstd,
                                             const float* __restrict__ gamma,
                                             const float* __restrict__ beta,
                                             const float* __restrict__ r_out,
                                             unsigned short* __restrict__ obj_bf) {
    int b = blockIdx.x, t = threadIdx.x;
    if (t >= K2) return;
    float v = 0.f;
    if (t < OUT) {
        int h = head[b], r = rela[b];
        float val = (x[(size_t)h * OUT + t] - mean[t]) * rstd[t] * gamma[t] + beta[t];
        val = tanhf(val);
        v = val * r_out[r * OUT + t];
    }
    obj_bf[(size_t)b * K2 + t] = f2bf(v);
}

// ---------------- emb_bf padded (vectorized)
__global__ __launch_bounds__(256) void k_cvt_emb(const float* __restrict__ emb_ent,
                                                 unsigned short* __restrict__ emb_bf) {
    int i = blockIdx.x * 256 + threadIdx.x;  // VPAD*29
    if (i >= VPAD * 29) return;
    int v = i / 29, c8 = i % 29;
    int c0 = c8 * 8;
    ushort8 o = (ushort8)0;
    if (v < V && c0 < 200) {
        float4 f0 = *(const float4*)&emb_ent[(size_t)v * OUT + c0];
        float4 f1 = *(const float4*)&emb_ent[(size_t)v * OUT + c0 + 4];
        o[0] = f2bf(f0.x); o[1] = f2bf(f0.y); o[2] = f2bf(f0.z); o[3] = f2bf(f0.w);
        o[4] = f2bf(f1.x); o[5] = f2bf(f1.y); o[6] = f2bf(f1.z); o[7] = f2bf(f1.w);
    }
    *(ushort8*)&emb_bf[(size_t)v * K2 + c0] = o;
}

// ---------------- decoder (bf16 MFMA), XCD-swizzled 1D grid
constexpr int DEC_BM = 64, DEC_BN = 256;
constexpr int DEC_GX = B / DEC_BM;          // 16
constexpr int DEC_GY = VPAD / DEC_BN;       // 196
constexpr int DEC_NWG = DEC_GX * DEC_GY;    // 3136 (div by 8)

__global__ __launch_bounds__(512) void k_dec2(const unsigned short* __restrict__ obj_bf,
                                              const unsigned short* __restrict__ emb_bf,
                                              const float* __restrict__ ent_bias,
                                              float* __restrict__ score) {
    __shared__ __align__(16) unsigned short As[DEC_BM * K2];
    __shared__ __align__(16) unsigned short Bs[DEC_BN * K2];
    int t = threadIdx.x;
    int lane = t & 63, wid = t >> 6;
    // bijective XCD swizzle: each XCD owns ~24.5 consecutive v-tiles (x-major)
    int wg = (blockIdx.x & 7) * (DEC_NWG >> 3) + (blockIdx.x >> 3);
    int b0 = (wg & (DEC_GX - 1)) * DEC_BM;
    int v0 = (wg / DEC_GX) * DEC_BN;
    const unsigned short* gA = obj_bf + (size_t)b0 * K2;
    const unsigned short* gB = emb_bf + (size_t)v0 * K2;
    for (int c = wid; c < 29; c += 8) {
        __builtin_amdgcn_global_load_lds((guint_t*)(gA + c * 512 + lane * 8),
                                         (luint_t*)(As + c * 512), 16, 0, 0);
    }
    for (int c = wid; c < 116; c += 8) {
        __builtin_amdgcn_global_load_lds((guint_t*)(gB + c * 512 + lane * 8),
                                         (luint_t*)(Bs + c * 512), 16, 0, 0);
    }
    __syncthreads();
    int wm = wid & 1, wn = wid >> 1;
    int rA = wm * 32 + (lane & 15);
    int rB = wn * 64 + (lane & 15);
    int kc = (lane >> 4) * 8;
    f32x4 acc[2][4] = {};
    for (int ks = 0; ks < 7; ++ks) {
        int kof = ks * 32 + kc;
        bf16x8 a0 = *(const bf16x8*)&As[(rA + 0) * K2 + kof];
        bf16x8 a1 = *(const bf16x8*)&As[(rA + 16) * K2 + kof];
        bf16x8 bb0 = *(const bf16x8*)&Bs[(rB + 0) * K2 + kof];
        bf16x8 bb1 = *(const bf16x8*)&Bs[(rB + 16) * K2 + kof];
        bf16x8 bb2 = *(const bf16x8*)&Bs[(rB + 32) * K2 + kof];
        bf16x8 bb3 = *(const bf16x8*)&Bs[(rB + 48) * K2 + kof];
        acc[0][0] = __builtin_amdgcn_mfma_f32_16x16x32_bf16(a0, bb0, acc[0][0], 0, 0, 0);
        acc[0][1] = __builtin_amdgcn_mfma_f32_16x16x32_bf16(a0, bb1, acc[0][1], 0, 0, 0);
        acc[0][2] = __builtin_amdgcn_mfma_f32_16x16x32_bf16(a0, bb2, acc[0][2], 0, 0, 0);
        acc[0][3] = __builtin_amdgcn_mfma_f32_16x16x32_bf16(a0, bb3, acc[0][3], 0, 0, 0);
        acc[1][0] = __builtin_amdgcn_mfma_f32_16x16x32_bf16(a1, bb0, acc[1][0], 0, 0, 0);
        acc[1][1] = __builtin_amdgcn_mfma_f32_16x16x32_bf16(a1, bb1, acc[1][1], 0, 0, 0);
        acc[1][2] = __builtin_amdgcn_mfma_f32_16x16x32_bf16(a1, bb2, acc[1][2], 0, 0, 0);
        acc[1][3] = __builtin_amdgcn_mfma_f32_16x16x32_bf16(a1, bb3, acc[1][3], 0, 0, 0);
    }
#pragma unroll
    for (int nf = 0; nf < 4; ++nf) {
        int v = v0 + wn * 64 + nf * 16 + (lane & 15);
        if (v >= V) continue;
        float bias = ent_bias[v];
#pragma unroll
        for (int mf = 0; mf < 2; ++mf) {
            int brow = b0 + wm * 32 + mf * 16 + (lane >> 4) * 4;
            f32x4 a = acc[mf][nf];
#pragma unroll
            for (int i = 0; i < 4; ++i) {
                float val = a[i] + bias;
                score[(size_t)(brow + i) * V + v] = 1.f / (1.f + __expf(-val));
            }
        }
    }
}

extern "C" void kernel_launch(void* const* d_in, const int* in_sizes, int n_in,
                              void* d_out, int out_size, void* d_ws, size_t ws_size,
                              hipStream_t stream) {
    const int*   edge_src  = (const int*)d_in[0];
    const int*   edge_dst  = (const int*)d_in[1];
    const int*   edge_type = (const int*)d_in[2];
    const int*   head      = (const int*)d_in[3];
    const int*   rela      = (const int*)d_in[4];
    const float* edge_norm = (const float*)d_in[5];
    const float* ent_emb   = (const float*)d_in[6];
    const float* rel_emb   = (const float*)d_in[7];
    const float* in_w      = (const float*)d_in[8];
    const float* out_w     = (const float*)d_in[9];
    const float* loop_w    = (const float*)d_in[10];
    const float* w_rel     = (const float*)d_in[11];
    const float* loop_rel  = (const float*)d_in[12];
    const float* conv_bias = (const float*)d_in[13];
    const float* bn_gamma  = (const float*)d_in[14];
    const float* bn_beta   = (const float*)d_in[15];
    const float* emb_ent   = (const float*)d_in[16];
    const float* ent_bias  = (const float*)d_in[17];
    float* score = (float*)d_out;

    // ---- workspace layout
    char* w = (char*)d_ws;
    float*          agg    = (float*)w;                      w += (size_t)V * OUT * 4;   // 40 MB
    unsigned short* Mtab   = (unsigned short*)w;             w += (size_t)NKEY * MT_SZ * 2;
    unsigned*       perm1  = (unsigned*)w;                   w += (size_t)E1MAX * 4;
    int*            pos_of_e = (int*)w;                      w += (size_t)E * 4;
    int*            poslist  = (int*)w;                      w += (size_t)E * 4;
    uint2*          pairs    = (uint2*)w;                    w += (size_t)NB2 * BCAP * 8;
    char* zbase = w;
    int*   hist1     = (int*)w;                              w += NKEY * 4;
    int*   cursor1   = (int*)w;                              w += NKEY * 4;
    int*   hist2     = (int*)w;                              w += V * 4;
    int*   cursor196 = (int*)w;                              w += NB2 * 4;
    float* colsum    = (float*)w;                            w += OUT * 4;
    float* colsq     = (float*)w;                            w += OUT * 4;
    size_t zbytes = (size_t)(w - zbase);
    int*   start1  = (int*)w;                                w += (NKEY + 1) * 4;
    int*   start2  = (int*)w;                                w += (V + 4) * 4;
    int*   Edev    = (int*)w;                                w += 16;
    float* meanp   = (float*)w;                              w += OUT * 4;
    float* rstdp   = (float*)w;                              w += OUT * 4;
    float* Mloop   = (float*)w;                              w += (size_t)D * OUT * 4;
    float* r_out   = (float*)w;                              w += (size_t)R * OUT * 4;
    unsigned short* obj_bf = (unsigned short*)w;             w += (size_t)B * K2 * 2;
    // overlays on agg's region (strictly stream-ordered):
    unsigned short* ent_bf = (unsigned short*)agg;   // V*128 ushorts; dead after k_edgemm
    unsigned short* emb_bf = (unsigned short*)agg;   // VPAD*K2 ushorts; written after k_obj
    unsigned short* msg    = (unsigned short*)d_out; // E1MAX*200 ushorts; dead after k_agg

    hipMemsetAsync(zbase, 0, zbytes, stream);
    hipMemsetAsync(perm1, 0xFF, (size_t)E1MAX * 4, stream);

    k_hist<<<512, 256, 0, stream>>>(edge_type, edge_dst, hist1, hist2);
    k_scan<<<1, 1024, 0, stream>>>(hist1, hist2, start1, start2, Edev);
    k_binkey<<<(E + 8191) / 8192, 1024, 0, stream>>>(edge_type, start1, cursor1,
                                                     perm1, pos_of_e);
    k_bindst1<<<(E + 8191) / 8192, 1024, 0, stream>>>(edge_dst, pos_of_e, cursor196, pairs);
    k_bindst2<<<NB2, 256, 0, stream>>>(cursor196, pairs, start2, poslist);
    k_mtab<<<NKEY, 256, 0, stream>>>(rel_emb, in_w, out_w, Mtab);
    k_mloop<<<(D * OUT + 255) / 256, 256, 0, stream>>>(loop_rel, loop_w, Mloop);
    k_rout<<<(R * OUT + 255) / 256, 256, 0, stream>>>(rel_emb, w_rel, r_out);
    k_cvt_ent<<<(V * 16 + 255) / 256, 256, 0, stream>>>(ent_emb, ent_bf);
    k_edgemm<<<E1MAX / 64, 256, 0, stream>>>(perm1, Edev, edge_src, edge_norm,
                                             ent_bf, Mtab, msg);
    k_agg<<<V / 4, 256, 0, stream>>>(start2, poslist, msg, agg);
    k_x2<<<(V + 31) / 32, 256, 0, stream>>>(ent_emb, Mloop, conv_bias, agg);
    k_stats<<<400, 256, 0, stream>>>(agg, colsum, colsq);
    k_finstats<<<1, 256, 0, stream>>>(colsum, colsq, meanp, rstdp);
    k_obj<<<B, 256, 0, stream>>>(head, rela, agg, meanp, rstdp, bn_gamma, bn_beta,
                                 r_out, obj_bf);
    k_cvt_emb<<<(VPAD * 29 + 255) / 256, 256, 0, stream>>>(emb_ent, emb_bf);
    k_dec2<<<DEC_NWG, 512, 0, stream>>>(obj_bf, emb_bf, ent_bias, score);
}

// Round 6
// 495.137 us; speedup vs baseline: 8.6657x; 1.1861x over previous
//
#include <hip/hip_runtime.h>
#include <cstddef>

constexpr int V = 50000, E = 400000, R = 400, D = 100, OUT = 200, B = 1024;
constexpr int HALF = E / 2;
constexpr float EPS = 1e-5f;
constexpr int K2 = 232;        // decoder K pad (bf16)
constexpr int VPAD = 50176;    // 196*256
constexpr int NKEY = 800;      // (rel, side)
constexpr int E1MAX = 450560;  // E + NKEY*63 rounded up; /64 = 7040 (div by 8)
constexpr int MT_O = 208, MT_K = 128;
constexpr int MT_SZ = MT_O * MT_K;
constexpr int NB2 = 196;       // coarse dst buckets (dst>>8)
constexpr int BCAP = 2560;     // bucket capacity (mean 2041, std ~45)

typedef short bf16x8 __attribute__((ext_vector_type(8)));
typedef float f32x4  __attribute__((ext_vector_type(4)));
typedef unsigned short ushort8 __attribute__((ext_vector_type(8)));
typedef __attribute__((address_space(1))) const unsigned int guint_t;
typedef __attribute__((address_space(3))) unsigned int luint_t;

__device__ inline unsigned short f2bf(float x) {
    unsigned u = __float_as_uint(x);
    u = (u + 0x7fffu + ((u >> 16) & 1u)) >> 16;
    return (unsigned short)u;
}
__device__ inline float bf2f(unsigned short u) {
    return __uint_as_float(((unsigned)u) << 16);
}

// ---------------- Mloop[j][o] = sum_k loop_rel[(j+k)%D] * loop_w[k][o]
__global__ __launch_bounds__(256) void k_mloop(const float* __restrict__ loop_rel,
                                               const float* __restrict__ loop_w,
                                               float* __restrict__ Mloop) {
    int i = blockIdx.x * 256 + threadIdx.x;
    if (i >= D * OUT) return;
    int j = i / OUT, o = i % OUT;
    float s = 0.f;
    for (int k = 0; k < D; ++k) {
        int idx = j + k; if (idx >= D) idx -= D;
        s += loop_rel[idx] * loop_w[k * OUT + o];
    }
    Mloop[i] = s;
}

// ---------------- r_out = rel_emb @ w_rel  [R,OUT]
__global__ __launch_bounds__(256) void k_rout(const float* __restrict__ rel_emb,
                                              const float* __restrict__ w_rel,
                                              float* __restrict__ r_out) {
    int i = blockIdx.x * 256 + threadIdx.x;
    if (i >= R * OUT) return;
    int r = i / OUT, o = i % OUT;
    float s = 0.f;
    for (int k = 0; k < D; ++k) s += rel_emb[r * D + k] * w_rel[k * OUT + o];
    r_out[i] = s;
}

// ---------------- key histogram (LDS-aggregated)
__global__ __launch_bounds__(256) void k_hist(const int* __restrict__ etyp,
                                              int* __restrict__ hist1) {
    __shared__ int lh[NKEY];
    int t = threadIdx.x;
    for (int i = t; i < NKEY; i += 256) lh[i] = 0;
    __syncthreads();
    for (int e = blockIdx.x * 256 + t; e < E; e += gridDim.x * 256) {
        int key = etyp[e] + (e < HALF ? 0 : R);
        atomicAdd(&lh[key], 1);
    }
    __syncthreads();
    for (int i = t; i < NKEY; i += 256) {
        int c = lh[i];
        if (c) atomicAdd(&hist1[i], c);
    }
}

// ---------------- key scan (64-aligned buckets)
__global__ __launch_bounds__(1024) void k_scan(const int* __restrict__ hist1,
                                               int* __restrict__ start1,
                                               int* __restrict__ Edev) {
    __shared__ int buf[1024];
    int t = threadIdx.x;
    int c = (t < NKEY) ? ((hist1[t] + 63) & ~63) : 0;
    buf[t] = c; __syncthreads();
    for (int off = 1; off < 1024; off <<= 1) {
        int x = (t >= off) ? buf[t - off] : 0; __syncthreads();
        buf[t] += x; __syncthreads();
    }
    if (t < NKEY) start1[t] = buf[t] - c;
    if (t == NKEY - 1) { start1[NKEY] = buf[t]; *Edev = buf[t]; }
}

// ---------------- key-binned scatter: perm1[p] = e | key<<19 ; pos_of_e[e] = p
__global__ __launch_bounds__(1024) void k_binkey(const int* __restrict__ etyp,
                                                 const int* __restrict__ start1,
                                                 int* __restrict__ cursor1,
                                                 unsigned* __restrict__ perm1,
                                                 int* __restrict__ pos_of_e) {
    __shared__ int lhist[NKEY], lbase[NKEY], lcnt[NKEY];
    int t = threadIdx.x;
    int e0 = blockIdx.x * 8192;
    for (int i = t; i < NKEY; i += 1024) { lhist[i] = 0; lcnt[i] = 0; }
    __syncthreads();
    for (int i = t; i < 8192; i += 1024) {
        int e = e0 + i;
        if (e < E) {
            int key = etyp[e] + (e < HALF ? 0 : R);
            atomicAdd(&lhist[key], 1);
        }
    }
    __syncthreads();
    for (int i = t; i < NKEY; i += 1024) {
        int c = lhist[i];
        lbase[i] = c ? (start1[i] + atomicAdd(&cursor1[i], c)) : 0;
    }
    __syncthreads();
    for (int i = t; i < 8192; i += 1024) {
        int e = e0 + i;
        if (e < E) {
            int key = etyp[e] + (e < HALF ? 0 : R);
            int r = atomicAdd(&lcnt[key], 1);
            int p = lbase[key] + r;
            perm1[p] = (unsigned)e | ((unsigned)key << 19);
            pos_of_e[e] = p;
        }
    }
}

// ---------------- coarse dst binning: pairs[bucket][slot] = (d, p)
__global__ __launch_bounds__(1024) void k_bindst1(const int* __restrict__ edst,
                                                  const int* __restrict__ pos_of_e,
                                                  int* __restrict__ cursor196,
                                                  uint2* __restrict__ pairs) {
    __shared__ int chist[NB2], cbase[NB2], ccnt[NB2];
    int t = threadIdx.x;
    int e0 = blockIdx.x * 8192;
    for (int i = t; i < NB2; i += 1024) { chist[i] = 0; ccnt[i] = 0; }
    __syncthreads();
    for (int i = t; i < 8192; i += 1024) {
        int e = e0 + i;
        if (e < E) atomicAdd(&chist[edst[e] >> 8], 1);
    }
    __syncthreads();
    for (int i = t; i < NB2; i += 1024) {
        int c = chist[i];
        cbase[i] = c ? atomicAdd(&cursor196[i], c) : 0;
    }
    __syncthreads();
    for (int i = t; i < 8192; i += 1024) {
        int e = e0 + i;
        if (e < E) {
            int d = edst[e];
            int ld = d >> 8;
            int r = atomicAdd(&ccnt[ld], 1);
            int slot = cbase[ld] + r;
            if (slot < BCAP)
                pairs[(size_t)ld * BCAP + slot] = make_uint2((unsigned)d, (unsigned)pos_of_e[e]);
        }
    }
}

// ---------------- bucket base scan (196 entries)
__global__ void k_scan2(const int* __restrict__ cursor196,
                        int* __restrict__ bbase, int* __restrict__ start2) {
    __shared__ int buf[256];
    int t = threadIdx.x;
    int c = (t < NB2) ? min(cursor196[t], BCAP) : 0;
    buf[t] = c; __syncthreads();
    for (int off = 1; off < 256; off <<= 1) {
        int x = (t >= off) ? buf[t - off] : 0; __syncthreads();
        buf[t] += x; __syncthreads();
    }
    if (t < NB2) bbase[t] = buf[t] - c;
    if (t == NB2 - 1) { bbase[NB2] = buf[t]; start2[V] = buf[t]; }
}

// ---------------- per-bucket exact ranking: writes start2 + poslist
__global__ __launch_bounds__(256) void k_bindst2(const int* __restrict__ cursor196,
                                                 const int* __restrict__ bbase,
                                                 const uint2* __restrict__ pairs,
                                                 int* __restrict__ start2,
                                                 int* __restrict__ poslist) {
    __shared__ int lcnt[256], loff[256], lrk[256];
    int b = blockIdx.x, t = threadIdx.x;
    lcnt[t] = 0; lrk[t] = 0;
    __syncthreads();
    int n = min(cursor196[b], BCAP);
    int base = bbase[b];
    for (int i = t; i < n; i += 256) {
        int d = (int)pairs[(size_t)b * BCAP + i].x;
        atomicAdd(&lcnt[d - (b << 8)], 1);
    }
    __syncthreads();
    int c = lcnt[t];
    loff[t] = c; __syncthreads();
    for (int off = 1; off < 256; off <<= 1) {
        int x = (t >= off) ? loff[t - off] : 0; __syncthreads();
        loff[t] += x; __syncthreads();
    }
    int excl = loff[t] - c;     // exclusive scan value for this dst
    loff[t] = excl;             // own slot write, no cross-read before barrier
    int d = (b << 8) + t;
    if (d < V) start2[d] = base + excl;
    __syncthreads();
    for (int i = t; i < n; i += 256) {
        uint2 pr = pairs[(size_t)b * BCAP + i];
        int ld = (int)pr.x - (b << 8);
        int r = atomicAdd(&lrk[ld], 1);
        poslist[base + loff[ld] + r] = (int)pr.y;
    }
}

// ---------------- ent_bf[v][0..127] = bf16(ent_emb[v][k]), zero for k>=100
__global__ __launch_bounds__(256) void k_cvt_ent(const float* __restrict__ ent_emb,
                                                 unsigned short* __restrict__ ent_bf) {
    int i = blockIdx.x * 256 + threadIdx.x;  // V*16
    if (i >= V * 16) return;
    int v = i >> 4, c8 = i & 15;
    int c0 = c8 * 8;
    ushort8 o = (ushort8)0;
    if (c0 < 96) {
        float4 f0 = *(const float4*)&ent_emb[(size_t)v * D + c0];
        float4 f1 = *(const float4*)&ent_emb[(size_t)v * D + c0 + 4];
        o[0] = f2bf(f0.x); o[1] = f2bf(f0.y); o[2] = f2bf(f0.z); o[3] = f2bf(f0.w);
        o[4] = f2bf(f1.x); o[5] = f2bf(f1.y); o[6] = f2bf(f1.z); o[7] = f2bf(f1.w);
    } else if (c0 == 96) {
        float4 f0 = *(const float4*)&ent_emb[(size_t)v * D + 96];
        o[0] = f2bf(f0.x); o[1] = f2bf(f0.y); o[2] = f2bf(f0.z); o[3] = f2bf(f0.w);
    }
    *(ushort8*)&ent_bf[(size_t)v * 128 + c0] = o;
}

// ---------------- Mt[key][o][j] = sum_k r_rho[(j+k)%D] * W[k][o]  (bf16, padded)
__global__ __launch_bounds__(256) void k_mtab(const float* __restrict__ rel_emb,
                                              const float* __restrict__ in_w,
                                              const float* __restrict__ out_w,
                                              unsigned short* __restrict__ Mtab) {
    __shared__ __align__(16) float Wsh[D * OUT];  // 80 KB
    __shared__ float rsh[240];
    int key = blockIdx.x;
    int rho = (key < R) ? key : key - R;
    const float* __restrict__ W = (key < R) ? in_w : out_w;
    int t = threadIdx.x;
    for (int i = t * 4; i < D * OUT; i += 1024)
        *(float4*)&Wsh[i] = *(const float4*)&W[i];
    for (int s = t; s < 240; s += 256) {
        int sm = s; if (sm >= 200) sm -= 200; if (sm >= 100) sm -= 100;
        rsh[s] = rel_emb[rho * D + sm];
    }
    __syncthreads();
    unsigned short* MtK = Mtab + (size_t)key * MT_SZ;
    int jg = t >> 3, og = t & 7;
    int j0 = jg * 4;
    for (int go = og; go < 50; go += 8) {
        int o0 = go * 4;
        float acc[4][4] = {};  // [oi][ji]
        float r0 = rsh[j0], r1 = rsh[j0 + 1], r2 = rsh[j0 + 2], r3 = rsh[j0 + 3];
#pragma unroll 4
        for (int k = 0; k < D; ++k) {
            float4 w = *(const float4*)&Wsh[k * OUT + o0];
            float wv[4] = {w.x, w.y, w.z, w.w};
#pragma unroll
            for (int oi = 0; oi < 4; ++oi) {
                acc[oi][0] += r0 * wv[oi];
                acc[oi][1] += r1 * wv[oi];
                acc[oi][2] += r2 * wv[oi];
                acc[oi][3] += r3 * wv[oi];
            }
            r0 = r1; r1 = r2; r2 = r3; r3 = rsh[j0 + k + 4];
        }
#pragma unroll
        for (int ji = 0; ji < 4; ++ji)
            if (j0 + ji >= D) { acc[0][ji] = acc[1][ji] = acc[2][ji] = acc[3][ji] = 0.f; }
#pragma unroll
        for (int oi = 0; oi < 4; ++oi) {
            ushort4 pk;
            pk.x = f2bf(acc[oi][0]); pk.y = f2bf(acc[oi][1]);
            pk.z = f2bf(acc[oi][2]); pk.w = f2bf(acc[oi][3]);
            *(ushort4*)&MtK[(o0 + oi) * MT_K + j0] = pk;
        }
    }
    for (int i = t; i < 8 * 32; i += 256) {
        int row = 200 + (i >> 5), j4 = (i & 31) * 4;
        *(ushort4*)&MtK[row * MT_K + j4] = make_ushort4(0, 0, 0, 0);
    }
}

// ---------------- per-chunk MFMA: msg[p][o] = (h_src[p] @ Mt_key) * norm
__global__ __launch_bounds__(256, 2) void k_edgemm(const unsigned* __restrict__ perm1,
                                                   const int* __restrict__ Edev,
                                                   const int* __restrict__ esrc,
                                                   const float* __restrict__ enorm,
                                                   const unsigned short* __restrict__ ent_bf,
                                                   const unsigned short* __restrict__ Mtab,
                                                   unsigned short* __restrict__ msg) {
    __shared__ __align__(16) unsigned short MtL[MT_SZ];      // 53,248 B
    __shared__ __align__(16) unsigned short AtL[64 * MT_K];  // 16,384 B
    __shared__ float snrm[64];
    __shared__ int ssrc[64];
    int t = threadIdx.x, lane = t & 63, wid = t >> 6;
    int cpx = gridDim.x >> 3;
    int chunk = (blockIdx.x & 7) * cpx + (blockIdx.x >> 3);
    if (chunk * 64 >= *Edev) return;
    unsigned kv = perm1[chunk * 64];   // chunk base is always a real edge
    int key = (int)(kv >> 19);
    const unsigned short* MtK = Mtab + (size_t)key * MT_SZ;
    if (t < 64) {
        unsigned val = perm1[chunk * 64 + t];
        int e = (int)(val & 0x7FFFFu);
        bool ok = (val != 0xFFFFFFFFu);
        ssrc[t] = ok ? esrc[e] : 0;
        snrm[t] = ok ? enorm[e] : 0.f;
    }
    for (int i = 0; i < 13; ++i) {
        int G0 = (wid * 13 + i) * 64;
        int G = G0 + lane;
        int o = G >> 4, g = G & 15;
        int gs = g ^ (o & 7);
        __builtin_amdgcn_global_load_lds((guint_t*)(MtK + o * MT_K + gs * 8),
                                         (luint_t*)(MtL + (size_t)G0 * 8), 16, 0, 0);
    }
    __syncthreads();
    for (int i = 0; i < 4; ++i) {
        int base = (wid * 4 + i) * 1024;
        int Gb = base + lane * 16;
        int row = Gb >> 8;
        int g = (Gb >> 4) & 15;
        int gs = g ^ (row & 7);
        __builtin_amdgcn_global_load_lds((guint_t*)(ent_bf + (size_t)ssrc[row] * 128 + gs * 8),
                                         (luint_t*)((char*)AtL + base), 16, 0, 0);
    }
    __syncthreads();
    int erow = wid * 16 + (lane & 15);
    int kq = lane >> 4;
    f32x4 acc[13] = {};
    for (int ks = 0; ks < 4; ++ks) {
        int g = ks * 4 + kq;
        bf16x8 bfr = *(const bf16x8*)((const char*)AtL + erow * 256 + ((g ^ (erow & 7)) * 16));
#pragma unroll
        for (int of = 0; of < 13; ++of) {
            int orow = of * 16 + (lane & 15);
            bf16x8 afr = *(const bf16x8*)((const char*)MtL + orow * 256 + ((g ^ (orow & 7)) * 16));
            acc[of] = __builtin_amdgcn_mfma_f32_16x16x32_bf16(afr, bfr, acc[of], 0, 0, 0);
        }
    }
    float nr = snrm[erow];
    size_t rowbase = (size_t)(chunk * 64 + erow) * OUT;
#pragma unroll
    for (int of = 0; of < 13; ++of) {
        int o0 = of * 16 + kq * 4;
        if (o0 < OUT) {
            ushort4 pk;
            pk.x = f2bf(acc[of][0] * nr); pk.y = f2bf(acc[of][1] * nr);
            pk.z = f2bf(acc[of][2] * nr); pk.w = f2bf(acc[of][3] * nr);
            *(ushort4*)&msg[rowbase + o0] = pk;
        }
    }
}

// ---------------- gather-sum per dst (2 rows per iter, 50 active lanes)
__global__ __launch_bounds__(256) void k_agg(const int* __restrict__ start2,
                                             const int* __restrict__ poslist,
                                             const unsigned short* __restrict__ msg,
                                             float* __restrict__ agg) {
    int wid = threadIdx.x >> 6, lane = threadIdx.x & 63;
    int v = blockIdx.x * 4 + wid;
    if (v >= V) return;
    int s = start2[v], epos = start2[v + 1];
    int half = (lane >= 25 && lane < 50) ? 1 : 0;
    int c = lane - half * 25;
    bool act = lane < 50;
    float acc[8] = {};
    for (int q = s; q < epos; q += 2) {
        int qq = q + half;
        if (act && qq < epos) {
            int p = poslist[qq];
            ushort8 m = *(const ushort8*)&msg[(size_t)p * OUT + c * 8];
#pragma unroll
            for (int i = 0; i < 8; ++i) acc[i] += bf2f(m[i]);
        }
    }
    int src = lane + 25 < 64 ? lane + 25 : 63;
#pragma unroll
    for (int i = 0; i < 8; ++i) {
        float o = __shfl(acc[i], src);
        if (lane < 25) acc[i] += o;
    }
    if (lane < 25) {
        float4 o0 = {acc[0], acc[1], acc[2], acc[3]};
        float4 o1 = {acc[4], acc[5], acc[6], acc[7]};
        *(float4*)&agg[(size_t)v * OUT + lane * 8] = o0;
        *(float4*)&agg[(size_t)v * OUT + lane * 8 + 4] = o1;
    }
}

// ---------------- x = (agg + ent_emb@Mloop)/3 + conv_bias (in place)
__global__ __launch_bounds__(256) void k_x2(const float* __restrict__ ent_emb,
                                            const float* __restrict__ Mloop,
                                            const float* __restrict__ conv_bias,
                                            float* __restrict__ x) {
    __shared__ float sat[100][36];
    int t = threadIdx.x;
    int v0 = blockIdx.x * 32;
    for (int i = t; i < 800; i += 256) {
        int kg = i >> 5, vv = i & 31;
        int vsafe = min(v0 + vv, V - 1);
        float4 a4 = *(const float4*)&ent_emb[(size_t)vsafe * D + kg * 4];
        sat[kg * 4 + 0][vv] = a4.x;
        sat[kg * 4 + 1][vv] = a4.y;
        sat[kg * 4 + 2][vv] = a4.z;
        sat[kg * 4 + 3][vv] = a4.w;
    }
    __syncthreads();
    if (t < 200) {
        int og = t % 50, eg = t / 50;
        int o0 = og * 4, vv0 = eg * 8;
        float acc[8][4] = {};
        for (int k = 0; k < D; ++k) {
            float4 w4 = *(const float4*)&Mloop[k * OUT + o0];
            float4 ca = *(const float4*)&sat[k][vv0];
            float4 cb = *(const float4*)&sat[k][vv0 + 4];
            float cc[8] = {ca.x, ca.y, ca.z, ca.w, cb.x, cb.y, cb.z, cb.w};
            float wv[4] = {w4.x, w4.y, w4.z, w4.w};
#pragma unroll
            for (int ee = 0; ee < 8; ++ee)
#pragma unroll
                for (int j = 0; j < 4; ++j) acc[ee][j] += cc[ee] * wv[j];
        }
        float4 bi = *(const float4*)&conv_bias[o0];
        float bv[4] = {bi.x, bi.y, bi.z, bi.w};
#pragma unroll
        for (int ee = 0; ee < 8; ++ee) {
            int v = v0 + vv0 + ee;
            if (v < V) {
                size_t base = (size_t)v * OUT + o0;
                float4 ag = *(const float4*)&x[base];
                float4 ov;
                ov.x = (ag.x + acc[ee][0]) * (1.f / 3.f) + bv[0];
                ov.y = (ag.y + acc[ee][1]) * (1.f / 3.f) + bv[1];
                ov.z = (ag.z + acc[ee][2]) * (1.f / 3.f) + bv[2];
                ov.w = (ag.w + acc[ee][3]) * (1.f / 3.f) + bv[3];
                *(float4*)&x[base] = ov;
            }
        }
    }
}

// ---------------- BN stats
__global__ __launch_bounds__(256) void k_stats(const float* __restrict__ x,
                                               float* __restrict__ colsum,
                                               float* __restrict__ colsq) {
    int g = blockIdx.x * 256 + threadIdx.x;
    int col = g % OUT;
    int r0 = g / OUT;
    float s = 0.f, sq = 0.f;
    for (int r = r0; r < V; r += 512) {
        float v = x[(size_t)r * OUT + col];
        s += v;
        sq += v * v;
    }
    atomicAdd(&colsum[col], s);
    atomicAdd(&colsq[col], sq);
}

__global__ void k_finstats(const float* __restrict__ colsum, const float* __restrict__ colsq,
                           float* __restrict__ mean, float* __restrict__ rstd) {
    int o = threadIdx.x;
    if (o >= OUT) return;
    float m = colsum[o] / (float)V;
    float var = colsq[o] / (float)V - m * m;
    mean[o] = m;
    rstd[o] = rsqrtf(var + EPS);
}

// ---------------- obj_bf = bf16(tanh(BN(x[head]))*r_out[rela]) zero-padded to K2
__global__ __launch_bounds__(256) void k_obj(const int* __restrict__ head,
                                             const int* __restrict__ rela,
                                             const float* __restrict__ x,
                                             const float* __restrict__ mean,
                                             const float* __restrict__ rstd,
                                             const float* __restrict__ gamma,
                                             const float* __restrict__ beta,
                                             const float* __restrict__ r_out,
                                             unsigned short* __restrict__ obj_bf) {
    int b = blockIdx.x, t = threadIdx.x;
    if (t >= K2) return;
    float v = 0.f;
    if (t < OUT) {
        int h = head[b], r = rela[b];
        float val = (x[(size_t)h * OUT + t] - mean[t]) * rstd[t] * gamma[t] + beta[t];
        val = tanhf(val);
        v = val * r_out[r * OUT + t];
    }
    obj_bf[(size_t)b * K2 + t] = f2bf(v);
}

// ---------------- emb_bf padded (vectorized)
__global__ __launch_bounds__(256) void k_cvt_emb(const float* __restrict__ emb_ent,
                                                 unsigned short* __restrict__ emb_bf) {
    int i = blockIdx.x * 256 + threadIdx.x;  // VPAD*29
    if (i >= VPAD * 29) return;
    int v = i / 29, c8 = i % 29;
    int c0 = c8 * 8;
    ushort8 o = (ushort8)0;
    if (v < V && c0 < 200) {
        float4 f0 = *(const float4*)&emb_ent[(size_t)v * OUT + c0];
        float4 f1 = *(const float4*)&emb_ent[(size_t)v * OUT + c0 + 4];
        o[0] = f2bf(f0.x); o[1] = f2bf(f0.y); o[2] = f2bf(f0.z); o[3] = f2bf(f0.w);
        o[4] = f2bf(f1.x); o[5] = f2bf(f1.y); o[6] = f2bf(f1.z); o[7] = f2bf(f1.w);
    }
    *(ushort8*)&emb_bf[(size_t)v * K2 + c0] = o;
}

// ---------------- decoder: LDS-free register MFMA GEMM (A,B from L1/L2)
constexpr int DEC_BM = 64, DEC_BN = 256;
constexpr int DEC_GX = B / DEC_BM;          // 16
constexpr int DEC_GY = VPAD / DEC_BN;       // 196
constexpr int DEC_NWG = DEC_GX * DEC_GY;    // 3136 (div by 8)

__global__ __launch_bounds__(256) void k_dec2(const unsigned short* __restrict__ obj_bf,
                                              const unsigned short* __restrict__ emb_bf,
                                              const float* __restrict__ ent_bias,
                                              float* __restrict__ score) {
    int t = threadIdx.x;
    int lane = t & 63, wid = t >> 6;
    // bijective XCD swizzle: 16 consecutive wg share one v-tile on one XCD
    int wg = (blockIdx.x & 7) * (DEC_NWG >> 3) + (blockIdx.x >> 3);
    int b0 = (wg & (DEC_GX - 1)) * DEC_BM;
    int v0 = (wg >> 4) * DEC_BN;
    int r16 = lane & 15;
    int kc = (lane >> 4) * 8;
    int vbase = v0 + wid * 64;   // this wave's 64 v-rows
    const unsigned short* gA = obj_bf + (size_t)(b0 + r16) * K2 + kc;
    const unsigned short* gB = emb_bf + (size_t)(vbase + r16) * K2 + kc;
    f32x4 acc[4][4] = {};
    for (int ks = 0; ks < 7; ++ks) {
        int kof = ks * 32;
        bf16x8 a[4], bb[4];
#pragma unroll
        for (int mf = 0; mf < 4; ++mf)
            a[mf] = *(const bf16x8*)(gA + (size_t)(mf * 16) * K2 + kof);
#pragma unroll
        for (int nf = 0; nf < 4; ++nf)
            bb[nf] = *(const bf16x8*)(gB + (size_t)(nf * 16) * K2 + kof);
#pragma unroll
        for (int mf = 0; mf < 4; ++mf)
#pragma unroll
            for (int nf = 0; nf < 4; ++nf)
                acc[mf][nf] = __builtin_amdgcn_mfma_f32_16x16x32_bf16(a[mf], bb[nf],
                                                                      acc[mf][nf], 0, 0, 0);
    }
#pragma unroll
    for (int nf = 0; nf < 4; ++nf) {
        int v = vbase + nf * 16 + r16;
        if (v >= V) continue;
        float bias = ent_bias[v];
#pragma unroll
        for (int mf = 0; mf < 4; ++mf) {
            int brow = b0 + mf * 16 + (lane >> 4) * 4;
            f32x4 av = acc[mf][nf];
#pragma unroll
            for (int i = 0; i < 4; ++i) {
                float val = av[i] + bias;
                score[(size_t)(brow + i) * V + v] = 1.f / (1.f + __expf(-val));
            }
        }
    }
}

extern "C" void kernel_launch(void* const* d_in, const int* in_sizes, int n_in,
                              void* d_out, int out_size, void* d_ws, size_t ws_size,
                              hipStream_t stream) {
    const int*   edge_src  = (const int*)d_in[0];
    const int*   edge_dst  = (const int*)d_in[1];
    const int*   edge_type = (const int*)d_in[2];
    const int*   head      = (const int*)d_in[3];
    const int*   rela      = (const int*)d_in[4];
    const float* edge_norm = (const float*)d_in[5];
    const float* ent_emb   = (const float*)d_in[6];
    const float* rel_emb   = (const float*)d_in[7];
    const float* in_w      = (const float*)d_in[8];
    const float* out_w     = (const float*)d_in[9];
    const float* loop_w    = (const float*)d_in[10];
    const float* w_rel     = (const float*)d_in[11];
    const float* loop_rel  = (const float*)d_in[12];
    const float* conv_bias = (const float*)d_in[13];
    const float* bn_gamma  = (const float*)d_in[14];
    const float* bn_beta   = (const float*)d_in[15];
    const float* emb_ent   = (const float*)d_in[16];
    const float* ent_bias  = (const float*)d_in[17];
    float* score = (float*)d_out;

    // ---- workspace layout
    char* w = (char*)d_ws;
    float*          agg    = (float*)w;                      w += (size_t)V * OUT * 4;   // 40 MB
    unsigned short* Mtab   = (unsigned short*)w;             w += (size_t)NKEY * MT_SZ * 2;
    unsigned*       perm1  = (unsigned*)w;                   w += (size_t)E1MAX * 4;
    int*            pos_of_e = (int*)w;                      w += (size_t)E * 4;
    int*            poslist  = (int*)w;                      w += (size_t)E * 4;
    uint2*          pairs    = (uint2*)w;                    w += (size_t)NB2 * BCAP * 8;
    char* zbase = w;
    int*   hist1     = (int*)w;                              w += NKEY * 4;
    int*   cursor1   = (int*)w;                              w += NKEY * 4;
    int*   cursor196 = (int*)w;                              w += NB2 * 4;
    float* colsum    = (float*)w;                            w += OUT * 4;
    float* colsq     = (float*)w;                            w += OUT * 4;
    size_t zbytes = (size_t)(w - zbase);
    int*   start1  = (int*)w;                                w += (NKEY + 1) * 4;
    int*   start2  = (int*)w;                                w += (V + 4) * 4;
    int*   bbase   = (int*)w;                                w += (NB2 + 4) * 4;
    int*   Edev    = (int*)w;                                w += 16;
    float* meanp   = (float*)w;                              w += OUT * 4;
    float* rstdp   = (float*)w;                              w += OUT * 4;
    float* Mloop   = (float*)w;                              w += (size_t)D * OUT * 4;
    float* r_out   = (float*)w;                              w += (size_t)R * OUT * 4;
    unsigned short* obj_bf = (unsigned short*)w;             w += (size_t)B * K2 * 2;
    // overlays on agg's region (strictly stream-ordered):
    unsigned short* ent_bf = (unsigned short*)agg;   // V*128 ushorts; dead after k_edgemm
    unsigned short* emb_bf = (unsigned short*)agg;   // VPAD*K2 ushorts; written after k_obj
    unsigned short* msg    = (unsigned short*)d_out; // E1MAX*200 ushorts; dead after k_agg

    hipMemsetAsync(zbase, 0, zbytes, stream);
    hipMemsetAsync(perm1, 0xFF, (size_t)E1MAX * 4, stream);

    k_hist<<<512, 256, 0, stream>>>(edge_type, hist1);
    k_scan<<<1, 1024, 0, stream>>>(hist1, start1, Edev);
    k_binkey<<<(E + 8191) / 8192, 1024, 0, stream>>>(edge_type, start1, cursor1,
                                                     perm1, pos_of_e);
    k_bindst1<<<(E + 8191) / 8192, 1024, 0, stream>>>(edge_dst, pos_of_e, cursor196, pairs);
    k_scan2<<<1, 256, 0, stream>>>(cursor196, bbase, start2);
    k_bindst2<<<NB2, 256, 0, stream>>>(cursor196, bbase, pairs, start2, poslist);
    k_mtab<<<NKEY, 256, 0, stream>>>(rel_emb, in_w, out_w, Mtab);
    k_mloop<<<(D * OUT + 255) / 256, 256, 0, stream>>>(loop_rel, loop_w, Mloop);
    k_rout<<<(R * OUT + 255) / 256, 256, 0, stream>>>(rel_emb, w_rel, r_out);
    k_cvt_ent<<<(V * 16 + 255) / 256, 256, 0, stream>>>(ent_emb, ent_bf);
    k_edgemm<<<E1MAX / 64, 256, 0, stream>>>(perm1, Edev, edge_src, edge_norm,
                                             ent_bf, Mtab, msg);
    k_agg<<<V / 4, 256, 0, stream>>>(start2, poslist, msg, agg);
    k_x2<<<(V + 31) / 32, 256, 0, stream>>>(ent_emb, Mloop, conv_bias, agg);
    k_stats<<<400, 256, 0, stream>>>(agg, colsum, colsq);
    k_finstats<<<1, 256, 0, stream>>>(colsum, colsq, meanp, rstdp);
    k_obj<<<B, 256, 0, stream>>>(head, rela, agg, meanp, rstdp, bn_gamma, bn_beta,
                                 r_out, obj_bf);
    k_cvt_emb<<<(VPAD * 29 + 255) / 256, 256, 0, stream>>>(emb_ent, emb_bf);
    k_dec2<<<DEC_NWG, 256, 0, stream>>>(obj_bf, emb_bf, ent_bias, score);
}

// Round 7
// 441.826 us; speedup vs baseline: 9.7113x; 1.1207x over previous
//
#include <hip/hip_runtime.h>
#include <cstddef>

constexpr int V = 50000, E = 400000, R = 400, D = 100, OUT = 200, B = 1024;
constexpr int HALF = E / 2;
constexpr float EPS = 1e-5f;
constexpr int K2 = 232;        // decoder K pad (bf16)
constexpr int VPAD = 50176;    // 196*256
constexpr int NKEY = 800;      // (rel, side)
constexpr int E1MAX = 450560;  // E + NKEY*63 rounded up; /64 = 7040 chunks
constexpr int MT_O = 208, MT_K = 128;
constexpr int MT_SZ = MT_O * MT_K;
constexpr int NB2 = 196;       // coarse dst buckets (dst>>8)
constexpr int BCAP = 2560;     // bucket capacity
constexpr int ECHK = 4;        // chunks per edgemm block (Mt reuse)

typedef short bf16x8 __attribute__((ext_vector_type(8)));
typedef float f32x4  __attribute__((ext_vector_type(4)));
typedef unsigned short ushort8 __attribute__((ext_vector_type(8)));
typedef __attribute__((address_space(1))) const unsigned int guint_t;
typedef __attribute__((address_space(3))) unsigned int luint_t;

__device__ inline unsigned short f2bf(float x) {
    unsigned u = __float_as_uint(x);
    u = (u + 0x7fffu + ((u >> 16) & 1u)) >> 16;
    return (unsigned short)u;
}
__device__ inline float bf2f(unsigned short u) {
    return __uint_as_float(((unsigned)u) << 16);
}

// ---------------- Mloop[j][o] = sum_k loop_rel[(j+k)%D] * loop_w[k][o]
__global__ __launch_bounds__(256) void k_mloop(const float* __restrict__ loop_rel,
                                               const float* __restrict__ loop_w,
                                               float* __restrict__ Mloop) {
    int i = blockIdx.x * 256 + threadIdx.x;
    if (i >= D * OUT) return;
    int j = i / OUT, o = i % OUT;
    float s = 0.f;
    for (int k = 0; k < D; ++k) {
        int idx = j + k; if (idx >= D) idx -= D;
        s += loop_rel[idx] * loop_w[k * OUT + o];
    }
    Mloop[i] = s;
}

// ---------------- r_out = rel_emb @ w_rel  [R,OUT]
__global__ __launch_bounds__(256) void k_rout(const float* __restrict__ rel_emb,
                                              const float* __restrict__ w_rel,
                                              float* __restrict__ r_out) {
    int i = blockIdx.x * 256 + threadIdx.x;
    if (i >= R * OUT) return;
    int r = i / OUT, o = i % OUT;
    float s = 0.f;
    for (int k = 0; k < D; ++k) s += rel_emb[r * D + k] * w_rel[k * OUT + o];
    r_out[i] = s;
}

// ---------------- key histogram (LDS-aggregated)
__global__ __launch_bounds__(256) void k_hist(const int* __restrict__ etyp,
                                              int* __restrict__ hist1) {
    __shared__ int lh[NKEY];
    int t = threadIdx.x;
    for (int i = t; i < NKEY; i += 256) lh[i] = 0;
    __syncthreads();
    for (int e = blockIdx.x * 256 + t; e < E; e += gridDim.x * 256) {
        int key = etyp[e] + (e < HALF ? 0 : R);
        atomicAdd(&lh[key], 1);
    }
    __syncthreads();
    for (int i = t; i < NKEY; i += 256) {
        int c = lh[i];
        if (c) atomicAdd(&hist1[i], c);
    }
}

// ---------------- key scan (64-aligned buckets)
__global__ __launch_bounds__(1024) void k_scan(const int* __restrict__ hist1,
                                               int* __restrict__ start1,
                                               int* __restrict__ Edev) {
    __shared__ int buf[1024];
    int t = threadIdx.x;
    int c = (t < NKEY) ? ((hist1[t] + 63) & ~63) : 0;
    buf[t] = c; __syncthreads();
    for (int off = 1; off < 1024; off <<= 1) {
        int x = (t >= off) ? buf[t - off] : 0; __syncthreads();
        buf[t] += x; __syncthreads();
    }
    if (t < NKEY) start1[t] = buf[t] - c;
    if (t == NKEY - 1) { start1[NKEY] = buf[t]; *Edev = buf[t]; }
}

// ---------------- key-binned scatter: perm1[p] = e | key<<19 ; pos_of_e[e] = p
__global__ __launch_bounds__(1024) void k_binkey(const int* __restrict__ etyp,
                                                 const int* __restrict__ start1,
                                                 int* __restrict__ cursor1,
                                                 unsigned* __restrict__ perm1,
                                                 int* __restrict__ pos_of_e) {
    __shared__ int lhist[NKEY], lbase[NKEY], lcnt[NKEY];
    int t = threadIdx.x;
    int e0 = blockIdx.x * 8192;
    for (int i = t; i < NKEY; i += 1024) { lhist[i] = 0; lcnt[i] = 0; }
    __syncthreads();
    for (int i = t; i < 8192; i += 1024) {
        int e = e0 + i;
        if (e < E) {
            int key = etyp[e] + (e < HALF ? 0 : R);
            atomicAdd(&lhist[key], 1);
        }
    }
    __syncthreads();
    for (int i = t; i < NKEY; i += 1024) {
        int c = lhist[i];
        lbase[i] = c ? (start1[i] + atomicAdd(&cursor1[i], c)) : 0;
    }
    __syncthreads();
    for (int i = t; i < 8192; i += 1024) {
        int e = e0 + i;
        if (e < E) {
            int key = etyp[e] + (e < HALF ? 0 : R);
            int r = atomicAdd(&lcnt[key], 1);
            int p = lbase[key] + r;
            perm1[p] = (unsigned)e | ((unsigned)key << 19);
            pos_of_e[e] = p;
        }
    }
}

// ---------------- coarse dst binning: pairs[bucket][slot] = (d, p)
__global__ __launch_bounds__(1024) void k_bindst1(const int* __restrict__ edst,
                                                  const int* __restrict__ pos_of_e,
                                                  int* __restrict__ cursor196,
                                                  uint2* __restrict__ pairs) {
    __shared__ int chist[NB2], cbase[NB2], ccnt[NB2];
    int t = threadIdx.x;
    int e0 = blockIdx.x * 8192;
    for (int i = t; i < NB2; i += 1024) { chist[i] = 0; ccnt[i] = 0; }
    __syncthreads();
    for (int i = t; i < 8192; i += 1024) {
        int e = e0 + i;
        if (e < E) atomicAdd(&chist[edst[e] >> 8], 1);
    }
    __syncthreads();
    for (int i = t; i < NB2; i += 1024) {
        int c = chist[i];
        cbase[i] = c ? atomicAdd(&cursor196[i], c) : 0;
    }
    __syncthreads();
    for (int i = t; i < 8192; i += 1024) {
        int e = e0 + i;
        if (e < E) {
            int d = edst[e];
            int ld = d >> 8;
            int r = atomicAdd(&ccnt[ld], 1);
            int slot = cbase[ld] + r;
            if (slot < BCAP)
                pairs[(size_t)ld * BCAP + slot] = make_uint2((unsigned)d, (unsigned)pos_of_e[e]);
        }
    }
}

// ---------------- bucket base scan (196 entries)
__global__ void k_scan2(const int* __restrict__ cursor196,
                        int* __restrict__ bbase, int* __restrict__ start2) {
    __shared__ int buf[256];
    int t = threadIdx.x;
    int c = (t < NB2) ? min(cursor196[t], BCAP) : 0;
    buf[t] = c; __syncthreads();
    for (int off = 1; off < 256; off <<= 1) {
        int x = (t >= off) ? buf[t - off] : 0; __syncthreads();
        buf[t] += x; __syncthreads();
    }
    if (t < NB2) bbase[t] = buf[t] - c;
    if (t == NB2 - 1) { bbase[NB2] = buf[t]; start2[V] = buf[t]; }
}

// ---------------- per-bucket exact ranking: writes start2 + poslist
__global__ __launch_bounds__(256) void k_bindst2(const int* __restrict__ cursor196,
                                                 const int* __restrict__ bbase,
                                                 const uint2* __restrict__ pairs,
                                                 int* __restrict__ start2,
                                                 int* __restrict__ poslist) {
    __shared__ int lcnt[256], loff[256], lrk[256];
    int b = blockIdx.x, t = threadIdx.x;
    lcnt[t] = 0; lrk[t] = 0;
    __syncthreads();
    int n = min(cursor196[b], BCAP);
    int base = bbase[b];
    for (int i = t; i < n; i += 256) {
        int d = (int)pairs[(size_t)b * BCAP + i].x;
        atomicAdd(&lcnt[d - (b << 8)], 1);
    }
    __syncthreads();
    int c = lcnt[t];
    loff[t] = c; __syncthreads();
    for (int off = 1; off < 256; off <<= 1) {
        int x = (t >= off) ? loff[t - off] : 0; __syncthreads();
        loff[t] += x; __syncthreads();
    }
    int excl = loff[t] - c;
    loff[t] = excl;
    int d = (b << 8) + t;
    if (d < V) start2[d] = base + excl;
    __syncthreads();
    for (int i = t; i < n; i += 256) {
        uint2 pr = pairs[(size_t)b * BCAP + i];
        int ld = (int)pr.x - (b << 8);
        int r = atomicAdd(&lrk[ld], 1);
        poslist[base + loff[ld] + r] = (int)pr.y;
    }
}

// ---------------- ent_bf[v][0..127] = bf16(ent_emb[v][k]), zero for k>=100
__global__ __launch_bounds__(256) void k_cvt_ent(const float* __restrict__ ent_emb,
                                                 unsigned short* __restrict__ ent_bf) {
    int i = blockIdx.x * 256 + threadIdx.x;  // V*16
    if (i >= V * 16) return;
    int v = i >> 4, c8 = i & 15;
    int c0 = c8 * 8;
    ushort8 o = (ushort8)0;
    if (c0 < 96) {
        float4 f0 = *(const float4*)&ent_emb[(size_t)v * D + c0];
        float4 f1 = *(const float4*)&ent_emb[(size_t)v * D + c0 + 4];
        o[0] = f2bf(f0.x); o[1] = f2bf(f0.y); o[2] = f2bf(f0.z); o[3] = f2bf(f0.w);
        o[4] = f2bf(f1.x); o[5] = f2bf(f1.y); o[6] = f2bf(f1.z); o[7] = f2bf(f1.w);
    } else if (c0 == 96) {
        float4 f0 = *(const float4*)&ent_emb[(size_t)v * D + 96];
        o[0] = f2bf(f0.x); o[1] = f2bf(f0.y); o[2] = f2bf(f0.z); o[3] = f2bf(f0.w);
    }
    *(ushort8*)&ent_bf[(size_t)v * 128 + c0] = o;
}

// ---------------- WT_bf[side][o][k] = bf16(W_side[k][o]), zero-padded (o>=200, k>=100)
__global__ __launch_bounds__(256) void k_cvt_wt(const float* __restrict__ in_w,
                                                const float* __restrict__ out_w,
                                                unsigned short* __restrict__ WT_bf) {
    int i = blockIdx.x * 256 + threadIdx.x;  // 2*208*16
    if (i >= 2 * 208 * 16) return;
    int side = i / (208 * 16);
    int rem = i - side * 208 * 16;
    int o = rem >> 4, c8 = rem & 15;
    int k0 = c8 * 8;
    const float* __restrict__ W = side ? out_w : in_w;
    ushort8 v = (ushort8)0;
    if (o < 200) {
#pragma unroll
        for (int q = 0; q < 8; ++q) {
            int k = k0 + q;
            if (k < 100) v[q] = f2bf(W[k * OUT + o]);
        }
    }
    *(ushort8*)&WT_bf[((size_t)side * 208 + o) * 128 + k0] = v;
}

// ---------------- Mt[key] = WT_bf[side] @ Hankel(r)  via MFMA
// Mt[o][j] = sum_k W[k][o] * r[(j+k)%100]; B[k][j] = rsh[k+j], rsh[s]=r[s%100].
// Rows o>=200 are zero (A zero-padded); cols j>=100 are garbage but multiply
// zero-padded k-slots of ent_bf downstream -> harmless.
__global__ __launch_bounds__(256) void k_mtab(const float* __restrict__ rel_emb,
                                              const unsigned short* __restrict__ WT_bf,
                                              unsigned short* __restrict__ Mtab) {
    __shared__ unsigned short rsh[256];
    int key = blockIdx.x;
    int rho = (key < R) ? key : key - R;
    int side = (key < R) ? 0 : 1;
    int t = threadIdx.x, lane = t & 63, wid = t >> 6;
    {
        int sm = t;
        if (sm >= 200) sm -= 200; else if (sm >= 100) sm -= 100;
        rsh[t] = f2bf(rel_emb[rho * D + sm]);
    }
    __syncthreads();
    const unsigned short* WT = WT_bf + (size_t)side * 208 * 128;
    unsigned short* MtK = Mtab + (size_t)key * MT_SZ;
    int m16 = lane & 15, kq = lane >> 4;
    for (int jt = 0; jt < 2; ++jt) {
        int j0 = (wid * 2 + jt) * 16;
        f32x4 acc[13] = {};
        for (int ks = 0; ks < 4; ++ks) {
            int rbase = ks * 32 + kq * 8 + j0 + m16;   // max 254
            ushort8 tmp;
#pragma unroll
            for (int q = 0; q < 8; ++q) tmp[q] = rsh[rbase + q];
            bf16x8 bfr = *(bf16x8*)&tmp;
#pragma unroll
            for (int of = 0; of < 13; ++of) {
                bf16x8 afr = *(const bf16x8*)&WT[(size_t)(of * 16 + m16) * 128 + ks * 32 + kq * 8];
                acc[of] = __builtin_amdgcn_mfma_f32_16x16x32_bf16(afr, bfr, acc[of], 0, 0, 0);
            }
        }
#pragma unroll
        for (int of = 0; of < 13; ++of) {
            int orow = of * 16 + kq * 4;
#pragma unroll
            for (int q = 0; q < 4; ++q)
                MtK[(size_t)(orow + q) * MT_K + j0 + m16] = f2bf(acc[of][q]);
        }
    }
}

// ---------------- per-chunk MFMA with Mt reuse across 4 chunks per block
__global__ __launch_bounds__(256, 2) void k_edgemm(const unsigned* __restrict__ perm1,
                                                   const int* __restrict__ Edev,
                                                   const int* __restrict__ esrc,
                                                   const float* __restrict__ enorm,
                                                   const unsigned short* __restrict__ ent_bf,
                                                   const unsigned short* __restrict__ Mtab,
                                                   unsigned short* __restrict__ msg) {
    __shared__ __align__(16) unsigned short MtL[MT_SZ];      // 53,248 B
    __shared__ __align__(16) unsigned short AtL[64 * MT_K];  // 16,384 B
    __shared__ float snrm[2][64];
    __shared__ int ssrc[2][64];
    int t = threadIdx.x, lane = t & 63, wid = t >> 6;
    // XCD-aware swizzle over 1760 blocks (div by 8): contiguous key ranges per XCD
    int cpx = gridDim.x >> 3;
    int blk = (blockIdx.x & 7) * cpx + (blockIdx.x >> 3);
    int nE = *Edev;
    int curkey = -1;
    for (int c = 0; c < ECHK; ++c) {
        int chunk = blk * ECHK + c;
        if (chunk * 64 >= nE) break;
        int buf = c & 1;
        if (t < 64) {
            unsigned val = perm1[chunk * 64 + t];
            int e = (int)(val & 0x7FFFFu);
            bool ok = (val != 0xFFFFFFFFu);
            ssrc[buf][t] = ok ? esrc[e] : 0;
            snrm[buf][t] = ok ? enorm[e] : 0.f;
        }
        int key = (int)(perm1[chunk * 64] >> 19);   // chunk base is always real
        __syncthreads();   // ssrc visible; previous compute done (WAR on MtL/AtL)
        if (key != curkey) {
            for (int i = 0; i < 13; ++i) {
                int G0 = (wid * 13 + i) * 64;
                int G = G0 + lane;
                int o = G >> 4, g = G & 15;
                int gs = g ^ (o & 7);
                __builtin_amdgcn_global_load_lds(
                    (guint_t*)(Mtab + (size_t)key * MT_SZ + o * MT_K + gs * 8),
                    (luint_t*)(MtL + (size_t)G0 * 8), 16, 0, 0);
            }
            curkey = key;
        }
        for (int i = 0; i < 4; ++i) {
            int base = (wid * 4 + i) * 1024;
            int Gb = base + lane * 16;
            int row = Gb >> 8;
            int g = (Gb >> 4) & 15;
            int gs = g ^ (row & 7);
            __builtin_amdgcn_global_load_lds(
                (guint_t*)(ent_bf + (size_t)ssrc[buf][row] * 128 + gs * 8),
                (luint_t*)((char*)AtL + base), 16, 0, 0);
        }
        __syncthreads();   // drains gload_lds (vmcnt 0 before barrier)
        int erow = wid * 16 + (lane & 15);
        int kq = lane >> 4;
        f32x4 acc[13] = {};
        for (int ks = 0; ks < 4; ++ks) {
            int g = ks * 4 + kq;
            bf16x8 bfr = *(const bf16x8*)((const char*)AtL + erow * 256 + ((g ^ (erow & 7)) * 16));
#pragma unroll
            for (int of = 0; of < 13; ++of) {
                int orow = of * 16 + (lane & 15);
                bf16x8 afr = *(const bf16x8*)((const char*)MtL + orow * 256 + ((g ^ (orow & 7)) * 16));
                acc[of] = __builtin_amdgcn_mfma_f32_16x16x32_bf16(afr, bfr, acc[of], 0, 0, 0);
            }
        }
        float nr = snrm[buf][erow];
        size_t rowbase = (size_t)(chunk * 64 + erow) * OUT;
#pragma unroll
        for (int of = 0; of < 13; ++of) {
            int o0 = of * 16 + kq * 4;
            if (o0 < OUT) {
                ushort4 pk;
                pk.x = f2bf(acc[of][0] * nr); pk.y = f2bf(acc[of][1] * nr);
                pk.z = f2bf(acc[of][2] * nr); pk.w = f2bf(acc[of][3] * nr);
                *(ushort4*)&msg[rowbase + o0] = pk;
            }
        }
    }
}

// ---------------- gather-sum per dst (2 rows per iter, 50 active lanes)
__global__ __launch_bounds__(256) void k_agg(const int* __restrict__ start2,
                                             const int* __restrict__ poslist,
                                             const unsigned short* __restrict__ msg,
                                             float* __restrict__ agg) {
    int wid = threadIdx.x >> 6, lane = threadIdx.x & 63;
    int v = blockIdx.x * 4 + wid;
    if (v >= V) return;
    int s = start2[v], epos = start2[v + 1];
    int half = (lane >= 25 && lane < 50) ? 1 : 0;
    int c = lane - half * 25;
    bool act = lane < 50;
    float acc[8] = {};
    for (int q = s; q < epos; q += 2) {
        int qq = q + half;
        if (act && qq < epos) {
            int p = poslist[qq];
            ushort8 m = *(const ushort8*)&msg[(size_t)p * OUT + c * 8];
#pragma unroll
            for (int i = 0; i < 8; ++i) acc[i] += bf2f(m[i]);
        }
    }
    int src = lane + 25 < 64 ? lane + 25 : 63;
#pragma unroll
    for (int i = 0; i < 8; ++i) {
        float o = __shfl(acc[i], src);
        if (lane < 25) acc[i] += o;
    }
    if (lane < 25) {
        float4 o0 = {acc[0], acc[1], acc[2], acc[3]};
        float4 o1 = {acc[4], acc[5], acc[6], acc[7]};
        *(float4*)&agg[(size_t)v * OUT + lane * 8] = o0;
        *(float4*)&agg[(size_t)v * OUT + lane * 8 + 4] = o1;
    }
}

// ---------------- x = (agg + ent_emb@Mloop)/3 + conv_bias (in place)
__global__ __launch_bounds__(256) void k_x2(const float* __restrict__ ent_emb,
                                            const float* __restrict__ Mloop,
                                            const float* __restrict__ conv_bias,
                                            float* __restrict__ x) {
    __shared__ float sat[100][36];
    int t = threadIdx.x;
    int v0 = blockIdx.x * 32;
    for (int i = t; i < 800; i += 256) {
        int kg = i >> 5, vv = i & 31;
        int vsafe = min(v0 + vv, V - 1);
        float4 a4 = *(const float4*)&ent_emb[(size_t)vsafe * D + kg * 4];
        sat[kg * 4 + 0][vv] = a4.x;
        sat[kg * 4 + 1][vv] = a4.y;
        sat[kg * 4 + 2][vv] = a4.z;
        sat[kg * 4 + 3][vv] = a4.w;
    }
    __syncthreads();
    if (t < 200) {
        int og = t % 50, eg = t / 50;
        int o0 = og * 4, vv0 = eg * 8;
        float acc[8][4] = {};
        for (int k = 0; k < D; ++k) {
            float4 w4 = *(const float4*)&Mloop[k * OUT + o0];
            float4 ca = *(const float4*)&sat[k][vv0];
            float4 cb = *(const float4*)&sat[k][vv0 + 4];
            float cc[8] = {ca.x, ca.y, ca.z, ca.w, cb.x, cb.y, cb.z, cb.w};
            float wv[4] = {w4.x, w4.y, w4.z, w4.w};
#pragma unroll
            for (int ee = 0; ee < 8; ++ee)
#pragma unroll
                for (int j = 0; j < 4; ++j) acc[ee][j] += cc[ee] * wv[j];
        }
        float4 bi = *(const float4*)&conv_bias[o0];
        float bv[4] = {bi.x, bi.y, bi.z, bi.w};
#pragma unroll
        for (int ee = 0; ee < 8; ++ee) {
            int v = v0 + vv0 + ee;
            if (v < V) {
                size_t base = (size_t)v * OUT + o0;
                float4 ag = *(const float4*)&x[base];
                float4 ov;
                ov.x = (ag.x + acc[ee][0]) * (1.f / 3.f) + bv[0];
                ov.y = (ag.y + acc[ee][1]) * (1.f / 3.f) + bv[1];
                ov.z = (ag.z + acc[ee][2]) * (1.f / 3.f) + bv[2];
                ov.w = (ag.w + acc[ee][3]) * (1.f / 3.f) + bv[3];
                *(float4*)&x[base] = ov;
            }
        }
    }
}

// ---------------- BN stats
__global__ __launch_bounds__(256) void k_stats(const float* __restrict__ x,
                                               float* __restrict__ colsum,
                                               float* __restrict__ colsq) {
    int g = blockIdx.x * 256 + threadIdx.x;
    int col = g % OUT;
    int r0 = g / OUT;
    float s = 0.f, sq = 0.f;
    for (int r = r0; r < V; r += 512) {
        float v = x[(size_t)r * OUT + col];
        s += v;
        sq += v * v;
    }
    atomicAdd(&colsum[col], s);
    atomicAdd(&colsq[col], sq);
}

__global__ void k_finstats(const float* __restrict__ colsum, const float* __restrict__ colsq,
                           float* __restrict__ mean, float* __restrict__ rstd) {
    int o = threadIdx.x;
    if (o >= OUT) return;
    float m = colsum[o] / (float)V;
    float var = colsq[o] / (float)V - m * m;
    mean[o] = m;
    rstd[o] = rsqrtf(var + EPS);
}

// ---------------- obj_bf = bf16(tanh(BN(x[head]))*r_out[rela]) zero-padded to K2
__global__ __launch_bounds__(256) void k_obj(const int* __restrict__ head,
                                             const int* __restrict__ rela,
                                             const float* __restrict__ x,
                                             const float* __restrict__ mean,
                                             const float* __restrict__ rstd,
                                             const float* __restrict__ gamma,
                                             const float* __restrict__ beta,
                                             const float* __restrict__ r_out,
                                             unsigned short* __restrict__ obj_bf) {
    int b = blockIdx.x, t = threadIdx.x;
    if (t >= K2) return;
    float v = 0.f;
    if (t < OUT) {
        int h = head[b], r = rela[b];
        float val = (x[(size_t)h * OUT + t] - mean[t]) * rstd[t] * gamma[t] + beta[t];
        val = tanhf(val);
        v = val * r_out[r * OUT + t];
    }
    obj_bf[(size_t)b * K2 + t] = f2bf(v);
}

// ---------------- emb_bf padded (vectorized)
__global__ __launch_bounds__(256) void k_cvt_emb(const float* __restrict__ emb_ent,
                                                 unsigned short* __restrict__ emb_bf) {
    int i = blockIdx.x * 256 + threadIdx.x;  // VPAD*29
    if (i >= VPAD * 29) return;
    int v = i / 29, c8 = i % 29;
    int c0 = c8 * 8;
    ushort8 o = (ushort8)0;
    if (v < V && c0 < 200) {
        float4 f0 = *(const float4*)&emb_ent[(size_t)v * OUT + c0];
        float4 f1 = *(const float4*)&emb_ent[(size_t)v * OUT + c0 + 4];
        o[0] = f2bf(f0.x); o[1] = f2bf(f0.y); o[2] = f2bf(f0.z); o[3] = f2bf(f0.w);
        o[4] = f2bf(f1.x); o[5] = f2bf(f1.y); o[6] = f2bf(f1.z); o[7] = f2bf(f1.w);
    }
    *(ushort8*)&emb_bf[(size_t)v * K2 + c0] = o;
}

// ---------------- decoder: LDS-free register MFMA GEMM (A,B from L1/L2)
constexpr int DEC_BM = 64, DEC_BN = 256;
constexpr int DEC_GX = B / DEC_BM;          // 16
constexpr int DEC_GY = VPAD / DEC_BN;       // 196
constexpr int DEC_NWG = DEC_GX * DEC_GY;    // 3136 (div by 8)

__global__ __launch_bounds__(256) void k_dec2(const unsigned short* __restrict__ obj_bf,
                                              const unsigned short* __restrict__ emb_bf,
                                              const float* __restrict__ ent_bias,
                                              float* __restrict__ score) {
    int t = threadIdx.x;
    int lane = t & 63, wid = t >> 6;
    int wg = (blockIdx.x & 7) * (DEC_NWG >> 3) + (blockIdx.x >> 3);
    int b0 = (wg & (DEC_GX - 1)) * DEC_BM;
    int v0 = (wg >> 4) * DEC_BN;
    int r16 = lane & 15;
    int kc = (lane >> 4) * 8;
    int vbase = v0 + wid * 64;
    const unsigned short* gA = obj_bf + (size_t)(b0 + r16) * K2 + kc;
    const unsigned short* gB = emb_bf + (size_t)(vbase + r16) * K2 + kc;
    f32x4 acc[4][4] = {};
    for (int ks = 0; ks < 7; ++ks) {
        int kof = ks * 32;
        bf16x8 a[4], bb[4];
#pragma unroll
        for (int mf = 0; mf < 4; ++mf)
            a[mf] = *(const bf16x8*)(gA + (size_t)(mf * 16) * K2 + kof);
#pragma unroll
        for (int nf = 0; nf < 4; ++nf)
            bb[nf] = *(const bf16x8*)(gB + (size_t)(nf * 16) * K2 + kof);
#pragma unroll
        for (int mf = 0; mf < 4; ++mf)
#pragma unroll
            for (int nf = 0; nf < 4; ++nf)
                acc[mf][nf] = __builtin_amdgcn_mfma_f32_16x16x32_bf16(a[mf], bb[nf],
                                                                      acc[mf][nf], 0, 0, 0);
    }
#pragma unroll
    for (int nf = 0; nf < 4; ++nf) {
        int v = vbase + nf * 16 + r16;
        if (v >= V) continue;
        float bias = ent_bias[v];
#pragma unroll
        for (int mf = 0; mf < 4; ++mf) {
            int brow = b0 + mf * 16 + (lane >> 4) * 4;
            f32x4 av = acc[mf][nf];
#pragma unroll
            for (int i = 0; i < 4; ++i) {
                float val = av[i] + bias;
                score[(size_t)(brow + i) * V + v] = 1.f / (1.f + __expf(-val));
            }
        }
    }
}

extern "C" void kernel_launch(void* const* d_in, const int* in_sizes, int n_in,
                              void* d_out, int out_size, void* d_ws, size_t ws_size,
                              hipStream_t stream) {
    const int*   edge_src  = (const int*)d_in[0];
    const int*   edge_dst  = (const int*)d_in[1];
    const int*   edge_type = (const int*)d_in[2];
    const int*   head      = (const int*)d_in[3];
    const int*   rela      = (const int*)d_in[4];
    const float* edge_norm = (const float*)d_in[5];
    const float* ent_emb   = (const float*)d_in[6];
    const float* rel_emb   = (const float*)d_in[7];
    const float* in_w      = (const float*)d_in[8];
    const float* out_w     = (const float*)d_in[9];
    const float* loop_w    = (const float*)d_in[10];
    const float* w_rel     = (const float*)d_in[11];
    const float* loop_rel  = (const float*)d_in[12];
    const float* conv_bias = (const float*)d_in[13];
    const float* bn_gamma  = (const float*)d_in[14];
    const float* bn_beta   = (const float*)d_in[15];
    const float* emb_ent   = (const float*)d_in[16];
    const float* ent_bias  = (const float*)d_in[17];
    float* score = (float*)d_out;

    // ---- workspace layout
    char* w = (char*)d_ws;
    float*          agg    = (float*)w;                      w += (size_t)V * OUT * 4;   // 40 MB
    unsigned short* Mtab   = (unsigned short*)w;             w += (size_t)NKEY * MT_SZ * 2;
    unsigned*       perm1  = (unsigned*)w;                   w += (size_t)E1MAX * 4;
    int*            pos_of_e = (int*)w;                      w += (size_t)E * 4;
    int*            poslist  = (int*)w;                      w += (size_t)E * 4;
    uint2*          pairs    = (uint2*)w;                    w += (size_t)NB2 * BCAP * 8;
    char* zbase = w;
    int*   hist1     = (int*)w;                              w += NKEY * 4;
    int*   cursor1   = (int*)w;                              w += NKEY * 4;
    int*   cursor196 = (int*)w;                              w += NB2 * 4;
    float* colsum    = (float*)w;                            w += OUT * 4;
    float* colsq     = (float*)w;                            w += OUT * 4;
    size_t zbytes = (size_t)(w - zbase);
    int*   start1  = (int*)w;                                w += (NKEY + 1) * 4;
    int*   start2  = (int*)w;                                w += (V + 4) * 4;
    int*   bbase   = (int*)w;                                w += (NB2 + 4) * 4;
    int*   Edev    = (int*)w;                                w += 16;
    float* meanp   = (float*)w;                              w += OUT * 4;
    float* rstdp   = (float*)w;                              w += OUT * 4;
    float* Mloop   = (float*)w;                              w += (size_t)D * OUT * 4;
    float* r_out   = (float*)w;                              w += (size_t)R * OUT * 4;
    unsigned short* obj_bf = (unsigned short*)w;             w += (size_t)B * K2 * 2;
    unsigned short* WT_bf  = (unsigned short*)w;             w += (size_t)2 * 208 * 128 * 2;
    // overlays on agg's region (strictly stream-ordered):
    unsigned short* ent_bf = (unsigned short*)agg;   // V*128 ushorts; dead after k_edgemm
    unsigned short* emb_bf = (unsigned short*)agg;   // VPAD*K2 ushorts; written after k_obj
    unsigned short* msg    = (unsigned short*)d_out; // E1MAX*200 ushorts; dead after k_agg

    hipMemsetAsync(zbase, 0, zbytes, stream);
    hipMemsetAsync(perm1, 0xFF, (size_t)E1MAX * 4, stream);

    k_hist<<<512, 256, 0, stream>>>(edge_type, hist1);
    k_scan<<<1, 1024, 0, stream>>>(hist1, start1, Edev);
    k_binkey<<<(E + 8191) / 8192, 1024, 0, stream>>>(edge_type, start1, cursor1,
                                                     perm1, pos_of_e);
    k_bindst1<<<(E + 8191) / 8192, 1024, 0, stream>>>(edge_dst, pos_of_e, cursor196, pairs);
    k_scan2<<<1, 256, 0, stream>>>(cursor196, bbase, start2);
    k_bindst2<<<NB2, 256, 0, stream>>>(cursor196, bbase, pairs, start2, poslist);
    k_cvt_wt<<<(2 * 208 * 16 + 255) / 256, 256, 0, stream>>>(in_w, out_w, WT_bf);
    k_mtab<<<NKEY, 256, 0, stream>>>(rel_emb, WT_bf, Mtab);
    k_mloop<<<(D * OUT + 255) / 256, 256, 0, stream>>>(loop_rel, loop_w, Mloop);
    k_rout<<<(R * OUT + 255) / 256, 256, 0, stream>>>(rel_emb, w_rel, r_out);
    k_cvt_ent<<<(V * 16 + 255) / 256, 256, 0, stream>>>(ent_emb, ent_bf);
    k_edgemm<<<E1MAX / 64 / ECHK, 256, 0, stream>>>(perm1, Edev, edge_src, edge_norm,
                                                    ent_bf, Mtab, msg);
    k_agg<<<V / 4, 256, 0, stream>>>(start2, poslist, msg, agg);
    k_x2<<<(V + 31) / 32, 256, 0, stream>>>(ent_emb, Mloop, conv_bias, agg);
    k_stats<<<400, 256, 0, stream>>>(agg, colsum, colsq);
    k_finstats<<<1, 256, 0, stream>>>(colsum, colsq, meanp, rstdp);
    k_obj<<<B, 256, 0, stream>>>(head, rela, agg, meanp, rstdp, bn_gamma, bn_beta,
                                 r_out, obj_bf);
    k_cvt_emb<<<(VPAD * 29 + 255) / 256, 256, 0, stream>>>(emb_ent, emb_bf);
    k_dec2<<<DEC_NWG, 256, 0, stream>>>(obj_bf, emb_bf, ent_bias, score);
}

// Round 8
// 413.656 us; speedup vs baseline: 10.3726x; 1.0681x over previous
//
#include <hip/hip_runtime.h>
#include <cstddef>

constexpr int V = 50000, E = 400000, R = 400, D = 100, OUT = 200, B = 1024;
constexpr int HALF = E / 2;
constexpr float EPS = 1e-5f;
constexpr int K2 = 232;        // decoder K pad (bf16)
constexpr int VPAD = 50176;    // 196*256
constexpr int NKEY = 800;      // (rel, side)
constexpr int E1MAX = 450560;  // E + NKEY*63 rounded up; /64 = 7040 chunks
constexpr int MT_O = 208, MT_K = 128;
constexpr int MT_SZ = MT_O * MT_K;
constexpr int NB2 = 196;       // coarse dst buckets (dst>>8)
constexpr int BCAP = 2560;     // bucket capacity
constexpr int ECHK = 8;        // chunks per edgemm block (Mt reuse); 7040/8=880 (div 8)

typedef short bf16x8 __attribute__((ext_vector_type(8)));
typedef float f32x4  __attribute__((ext_vector_type(4)));
typedef unsigned short ushort8 __attribute__((ext_vector_type(8)));
typedef __attribute__((address_space(1))) const unsigned int guint_t;
typedef __attribute__((address_space(3))) unsigned int luint_t;

__device__ inline unsigned short f2bf(float x) {
    unsigned u = __float_as_uint(x);
    u = (u + 0x7fffu + ((u >> 16) & 1u)) >> 16;
    return (unsigned short)u;
}
__device__ inline float bf2f(unsigned short u) {
    return __uint_as_float(((unsigned)u) << 16);
}

// ---------------- fused precompute: Mloop | r_out | WT_bf | ent_bf
constexpr int G_MLOOP = (D * OUT + 255) / 256;       // 79
constexpr int G_ROUT  = (R * OUT + 255) / 256;       // 313
constexpr int G_CVTWT = (2 * 208 * 16) / 256;        // 26
constexpr int G_CVTENT = (V * 16) / 256;             // 3125
constexpr int PRE_B1 = G_MLOOP;                      // 79
constexpr int PRE_B2 = PRE_B1 + G_ROUT;              // 392
constexpr int PRE_B3 = PRE_B2 + G_CVTWT;             // 418
constexpr int PRE_NWG = PRE_B3 + G_CVTENT;           // 3543

__global__ __launch_bounds__(256) void k_pre(const float* __restrict__ loop_rel,
                                             const float* __restrict__ loop_w,
                                             const float* __restrict__ rel_emb,
                                             const float* __restrict__ w_rel,
                                             const float* __restrict__ in_w,
                                             const float* __restrict__ out_w,
                                             const float* __restrict__ ent_emb,
                                             float* __restrict__ Mloop,
                                             float* __restrict__ r_out,
                                             unsigned short* __restrict__ WT_bf,
                                             unsigned short* __restrict__ ent_bf) {
    int blk = blockIdx.x, t = threadIdx.x;
    if (blk < PRE_B1) {                       // Mloop[j][o]
        int i = blk * 256 + t;
        if (i >= D * OUT) return;
        int j = i / OUT, o = i % OUT;
        float s = 0.f;
        for (int k = 0; k < D; ++k) {
            int idx = j + k; if (idx >= D) idx -= D;
            s += loop_rel[idx] * loop_w[k * OUT + o];
        }
        Mloop[i] = s;
    } else if (blk < PRE_B2) {                // r_out = rel_emb @ w_rel
        int i = (blk - PRE_B1) * 256 + t;
        if (i >= R * OUT) return;
        int r = i / OUT, o = i % OUT;
        float s = 0.f;
        for (int k = 0; k < D; ++k) s += rel_emb[r * D + k] * w_rel[k * OUT + o];
        r_out[i] = s;
    } else if (blk < PRE_B3) {                // WT_bf[side][o][k]
        int i = (blk - PRE_B2) * 256 + t;
        int side = i / (208 * 16);
        int rem = i - side * 208 * 16;
        int o = rem >> 4, c8 = rem & 15;
        int k0 = c8 * 8;
        const float* __restrict__ W = side ? out_w : in_w;
        ushort8 v = (ushort8)0;
        if (o < 200) {
#pragma unroll
            for (int q = 0; q < 8; ++q) {
                int k = k0 + q;
                if (k < 100) v[q] = f2bf(W[k * OUT + o]);
            }
        }
        *(ushort8*)&WT_bf[((size_t)side * 208 + o) * 128 + k0] = v;
    } else {                                  // ent_bf[v][0..127]
        int i = (blk - PRE_B3) * 256 + t;
        if (i >= V * 16) return;
        int v = i >> 4, c8 = i & 15;
        int c0 = c8 * 8;
        ushort8 o = (ushort8)0;
        if (c0 < 96) {
            float4 f0 = *(const float4*)&ent_emb[(size_t)v * D + c0];
            float4 f1 = *(const float4*)&ent_emb[(size_t)v * D + c0 + 4];
            o[0] = f2bf(f0.x); o[1] = f2bf(f0.y); o[2] = f2bf(f0.z); o[3] = f2bf(f0.w);
            o[4] = f2bf(f1.x); o[5] = f2bf(f1.y); o[6] = f2bf(f1.z); o[7] = f2bf(f1.w);
        } else if (c0 == 96) {
            float4 f0 = *(const float4*)&ent_emb[(size_t)v * D + 96];
            o[0] = f2bf(f0.x); o[1] = f2bf(f0.y); o[2] = f2bf(f0.z); o[3] = f2bf(f0.w);
        }
        *(ushort8*)&ent_bf[(size_t)v * 128 + c0] = o;
    }
}

// ---------------- key histogram (LDS-aggregated)
__global__ __launch_bounds__(256) void k_hist(const int* __restrict__ etyp,
                                              int* __restrict__ hist1) {
    __shared__ int lh[NKEY];
    int t = threadIdx.x;
    for (int i = t; i < NKEY; i += 256) lh[i] = 0;
    __syncthreads();
    for (int e = blockIdx.x * 256 + t; e < E; e += gridDim.x * 256) {
        int key = etyp[e] + (e < HALF ? 0 : R);
        atomicAdd(&lh[key], 1);
    }
    __syncthreads();
    for (int i = t; i < NKEY; i += 256) {
        int c = lh[i];
        if (c) atomicAdd(&hist1[i], c);
    }
}

// ---------------- key scan (64-aligned buckets)
__global__ __launch_bounds__(1024) void k_scan(const int* __restrict__ hist1,
                                               int* __restrict__ start1,
                                               int* __restrict__ Edev) {
    __shared__ int buf[1024];
    int t = threadIdx.x;
    int c = (t < NKEY) ? ((hist1[t] + 63) & ~63) : 0;
    buf[t] = c; __syncthreads();
    for (int off = 1; off < 1024; off <<= 1) {
        int x = (t >= off) ? buf[t - off] : 0; __syncthreads();
        buf[t] += x; __syncthreads();
    }
    if (t < NKEY) start1[t] = buf[t] - c;
    if (t == NKEY - 1) { start1[NKEY] = buf[t]; *Edev = buf[t]; }
}

// ---------------- key-binned scatter: perm1[p] = e | key<<19 ; pos_of_e[e] = p
__global__ __launch_bounds__(1024) void k_binkey(const int* __restrict__ etyp,
                                                 const int* __restrict__ start1,
                                                 int* __restrict__ cursor1,
                                                 unsigned* __restrict__ perm1,
                                                 int* __restrict__ pos_of_e) {
    __shared__ int lhist[NKEY], lbase[NKEY], lcnt[NKEY];
    int t = threadIdx.x;
    int e0 = blockIdx.x * 8192;
    for (int i = t; i < NKEY; i += 1024) { lhist[i] = 0; lcnt[i] = 0; }
    __syncthreads();
    for (int i = t; i < 8192; i += 1024) {
        int e = e0 + i;
        if (e < E) {
            int key = etyp[e] + (e < HALF ? 0 : R);
            atomicAdd(&lhist[key], 1);
        }
    }
    __syncthreads();
    for (int i = t; i < NKEY; i += 1024) {
        int c = lhist[i];
        lbase[i] = c ? (start1[i] + atomicAdd(&cursor1[i], c)) : 0;
    }
    __syncthreads();
    for (int i = t; i < 8192; i += 1024) {
        int e = e0 + i;
        if (e < E) {
            int key = etyp[e] + (e < HALF ? 0 : R);
            int r = atomicAdd(&lcnt[key], 1);
            int p = lbase[key] + r;
            perm1[p] = (unsigned)e | ((unsigned)key << 19);
            pos_of_e[e] = p;
        }
    }
}

// ---------------- coarse dst binning: pairs[bucket][slot] = (d, p)
__global__ __launch_bounds__(1024) void k_bindst1(const int* __restrict__ edst,
                                                  const int* __restrict__ pos_of_e,
                                                  int* __restrict__ cursor196,
                                                  uint2* __restrict__ pairs) {
    __shared__ int chist[NB2], cbase[NB2], ccnt[NB2];
    int t = threadIdx.x;
    int e0 = blockIdx.x * 8192;
    for (int i = t; i < NB2; i += 1024) { chist[i] = 0; ccnt[i] = 0; }
    __syncthreads();
    for (int i = t; i < 8192; i += 1024) {
        int e = e0 + i;
        if (e < E) atomicAdd(&chist[edst[e] >> 8], 1);
    }
    __syncthreads();
    for (int i = t; i < NB2; i += 1024) {
        int c = chist[i];
        cbase[i] = c ? atomicAdd(&cursor196[i], c) : 0;
    }
    __syncthreads();
    for (int i = t; i < 8192; i += 1024) {
        int e = e0 + i;
        if (e < E) {
            int d = edst[e];
            int ld = d >> 8;
            int r = atomicAdd(&ccnt[ld], 1);
            int slot = cbase[ld] + r;
            if (slot < BCAP)
                pairs[(size_t)ld * BCAP + slot] = make_uint2((unsigned)d, (unsigned)pos_of_e[e]);
        }
    }
}

// ---------------- per-bucket exact ranking (self-computed base scan)
__global__ __launch_bounds__(256) void k_bindst2(const int* __restrict__ cursor196,
                                                 const uint2* __restrict__ pairs,
                                                 int* __restrict__ start2,
                                                 int* __restrict__ poslist) {
    __shared__ int lcnt[256], loff[256], lrk[256], bscan[256];
    int b = blockIdx.x, t = threadIdx.x;
    lcnt[t] = 0; lrk[t] = 0;
    bscan[t] = (t < NB2) ? min(cursor196[t], BCAP) : 0;
    __syncthreads();
    for (int off = 1; off < 256; off <<= 1) {
        int xx = (t >= off) ? bscan[t - off] : 0; __syncthreads();
        bscan[t] += xx; __syncthreads();
    }
    int base = (b > 0) ? bscan[b - 1] : 0;
    if (b == 0 && t == 0) start2[V] = bscan[NB2 - 1];
    int n = min(cursor196[b], BCAP);
    for (int i = t; i < n; i += 256) {
        int d = (int)pairs[(size_t)b * BCAP + i].x;
        atomicAdd(&lcnt[d - (b << 8)], 1);
    }
    __syncthreads();
    int cc = lcnt[t];
    loff[t] = cc; __syncthreads();
    for (int off = 1; off < 256; off <<= 1) {
        int xx = (t >= off) ? loff[t - off] : 0; __syncthreads();
        loff[t] += xx; __syncthreads();
    }
    int excl = loff[t] - cc;
    loff[t] = excl;                 // own-slot overwrite; cross-reads only after barrier
    int d = (b << 8) + t;
    if (d < V) start2[d] = base + excl;
    __syncthreads();
    for (int i = t; i < n; i += 256) {
        uint2 pr = pairs[(size_t)b * BCAP + i];
        int ld = (int)pr.x - (b << 8);
        int r = atomicAdd(&lrk[ld], 1);
        poslist[base + loff[ld] + r] = (int)pr.y;
    }
}

// ---------------- Mt[key] = WT_bf[side] @ Hankel(r) via MFMA (bf16, padded)
__global__ __launch_bounds__(256) void k_mtab(const float* __restrict__ rel_emb,
                                              const unsigned short* __restrict__ WT_bf,
                                              unsigned short* __restrict__ Mtab) {
    __shared__ unsigned short rsh[256];
    int key = blockIdx.x;
    int rho = (key < R) ? key : key - R;
    int side = (key < R) ? 0 : 1;
    int t = threadIdx.x, lane = t & 63, wid = t >> 6;
    {
        int sm = t;
        if (sm >= 200) sm -= 200; else if (sm >= 100) sm -= 100;
        rsh[t] = f2bf(rel_emb[rho * D + sm]);
    }
    __syncthreads();
    const unsigned short* WT = WT_bf + (size_t)side * 208 * 128;
    unsigned short* MtK = Mtab + (size_t)key * MT_SZ;
    int m16 = lane & 15, kq = lane >> 4;
    for (int jt = 0; jt < 2; ++jt) {
        int j0 = (wid * 2 + jt) * 16;
        f32x4 acc[13] = {};
        for (int ks = 0; ks < 4; ++ks) {
            int rbase = ks * 32 + kq * 8 + j0 + m16;   // max 254
            ushort8 tmp;
#pragma unroll
            for (int q = 0; q < 8; ++q) tmp[q] = rsh[rbase + q];
            bf16x8 bfr = *(bf16x8*)&tmp;
#pragma unroll
            for (int of = 0; of < 13; ++of) {
                bf16x8 afr = *(const bf16x8*)&WT[(size_t)(of * 16 + m16) * 128 + ks * 32 + kq * 8];
                acc[of] = __builtin_amdgcn_mfma_f32_16x16x32_bf16(afr, bfr, acc[of], 0, 0, 0);
            }
        }
#pragma unroll
        for (int of = 0; of < 13; ++of) {
            int orow = of * 16 + kq * 4;
#pragma unroll
            for (int q = 0; q < 4; ++q)
                MtK[(size_t)(orow + q) * MT_K + j0 + m16] = f2bf(acc[of][q]);
        }
    }
}

// ---------------- per-chunk MFMA with Mt reuse across 8 chunks per block
__global__ __launch_bounds__(256, 2) void k_edgemm(const unsigned* __restrict__ perm1,
                                                   const int* __restrict__ Edev,
                                                   const int* __restrict__ esrc,
                                                   const float* __restrict__ enorm,
                                                   const unsigned short* __restrict__ ent_bf,
                                                   const unsigned short* __restrict__ Mtab,
                                                   unsigned short* __restrict__ msg) {
    __shared__ __align__(16) unsigned short MtL[MT_SZ];      // 53,248 B
    __shared__ __align__(16) unsigned short AtL[64 * MT_K];  // 16,384 B
    __shared__ float snrm[2][64];
    __shared__ int ssrc[2][64];
    int t = threadIdx.x, lane = t & 63, wid = t >> 6;
    int cpx = gridDim.x >> 3;
    int blk = (blockIdx.x & 7) * cpx + (blockIdx.x >> 3);
    int nE = *Edev;
    int curkey = -1;
    for (int c = 0; c < ECHK; ++c) {
        int chunk = blk * ECHK + c;
        if (chunk * 64 >= nE) break;
        int buf = c & 1;
        if (t < 64) {
            unsigned val = perm1[chunk * 64 + t];
            int e = (int)(val & 0x7FFFFu);
            bool ok = (val != 0xFFFFFFFFu);
            ssrc[buf][t] = ok ? esrc[e] : 0;
            snrm[buf][t] = ok ? enorm[e] : 0.f;
        }
        int key = (int)(perm1[chunk * 64] >> 19);   // chunk base is always real
        __syncthreads();   // ssrc visible; previous compute done (WAR on MtL/AtL)
        if (key != curkey) {
            for (int i = 0; i < 13; ++i) {
                int G0 = (wid * 13 + i) * 64;
                int G = G0 + lane;
                int o = G >> 4, g = G & 15;
                int gs = g ^ (o & 7);
                __builtin_amdgcn_global_load_lds(
                    (guint_t*)(Mtab + (size_t)key * MT_SZ + o * MT_K + gs * 8),
                    (luint_t*)(MtL + (size_t)G0 * 8), 16, 0, 0);
            }
            curkey = key;
        }
        for (int i = 0; i < 4; ++i) {
            int base = (wid * 4 + i) * 1024;
            int Gb = base + lane * 16;
            int row = Gb >> 8;
            int g = (Gb >> 4) & 15;
            int gs = g ^ (row & 7);
            __builtin_amdgcn_global_load_lds(
                (guint_t*)(ent_bf + (size_t)ssrc[buf][row] * 128 + gs * 8),
                (luint_t*)((char*)AtL + base), 16, 0, 0);
        }
        __syncthreads();   // drains gload_lds
        int erow = wid * 16 + (lane & 15);
        int kq = lane >> 4;
        f32x4 acc[13] = {};
        for (int ks = 0; ks < 4; ++ks) {
            int g = ks * 4 + kq;
            bf16x8 bfr = *(const bf16x8*)((const char*)AtL + erow * 256 + ((g ^ (erow & 7)) * 16));
#pragma unroll
            for (int of = 0; of < 13; ++of) {
                int orow = of * 16 + (lane & 15);
                bf16x8 afr = *(const bf16x8*)((const char*)MtL + orow * 256 + ((g ^ (orow & 7)) * 16));
                acc[of] = __builtin_amdgcn_mfma_f32_16x16x32_bf16(afr, bfr, acc[of], 0, 0, 0);
            }
        }
        float nr = snrm[buf][erow];
        size_t rowbase = (size_t)(chunk * 64 + erow) * OUT;
#pragma unroll
        for (int of = 0; of < 13; ++of) {
            int o0 = of * 16 + kq * 4;
            if (o0 < OUT) {
                ushort4 pk;
                pk.x = f2bf(acc[of][0] * nr); pk.y = f2bf(acc[of][1] * nr);
                pk.z = f2bf(acc[of][2] * nr); pk.w = f2bf(acc[of][3] * nr);
                *(ushort4*)&msg[rowbase + o0] = pk;
            }
        }
    }
}

// ---------------- fused gather-sum + loop-term + bias: x = (agg + ent@Mloop)/3 + cb
__global__ __launch_bounds__(256) void k_aggx(const int* __restrict__ start2,
                                              const int* __restrict__ poslist,
                                              const unsigned short* __restrict__ msg,
                                              const float* __restrict__ ent_emb,
                                              const float* __restrict__ Mloop,
                                              const float* __restrict__ conv_bias,
                                              float* __restrict__ x) {
    __shared__ float xt[16][200];     // 12.8 KB
    __shared__ float sat[100][20];    // 8 KB
    int t = threadIdx.x, lane = t & 63, wid = t >> 6;
    int v0 = blockIdx.x * 16;
    int half = (lane >= 25 && lane < 50) ? 1 : 0;
    int c = lane - half * 25;
    bool act = lane < 50;
    int src = lane + 25 < 64 ? lane + 25 : 63;
    for (int i = 0; i < 4; ++i) {     // each wave: 4 v's
        int v = v0 + wid * 4 + i;
        int s = start2[v], epos = start2[v + 1];
        float acc[8] = {};
        for (int q = s; q < epos; q += 2) {
            int qq = q + half;
            if (act && qq < epos) {
                int p = poslist[qq];
                ushort8 m = *(const ushort8*)&msg[(size_t)p * OUT + c * 8];
#pragma unroll
                for (int j = 0; j < 8; ++j) acc[j] += bf2f(m[j]);
            }
        }
#pragma unroll
        for (int j = 0; j < 8; ++j) {
            float o = __shfl(acc[j], src);
            if (lane < 25) acc[j] += o;
        }
        if (lane < 25) {
#pragma unroll
            for (int j = 0; j < 8; ++j) xt[wid * 4 + i][lane * 8 + j] = acc[j];
        }
    }
    for (int i = t; i < 400; i += 256) {   // stage ent rows transposed
        int kg = i >> 4, vv = i & 15;
        float4 a4 = *(const float4*)&ent_emb[(size_t)(v0 + vv) * D + kg * 4];
        sat[kg * 4 + 0][vv] = a4.x;
        sat[kg * 4 + 1][vv] = a4.y;
        sat[kg * 4 + 2][vv] = a4.z;
        sat[kg * 4 + 3][vv] = a4.w;
    }
    __syncthreads();
    if (t < 200) {
        int og = t % 50, eg = t / 50;
        int o0 = og * 4, vv0 = eg * 4;
        float acc[4][4] = {};
        for (int k = 0; k < D; ++k) {
            float4 w4 = *(const float4*)&Mloop[k * OUT + o0];
            float4 ca = *(const float4*)&sat[k][vv0];
            float cc[4] = {ca.x, ca.y, ca.z, ca.w};
            float wv[4] = {w4.x, w4.y, w4.z, w4.w};
#pragma unroll
            for (int r = 0; r < 4; ++r)
#pragma unroll
                for (int j = 0; j < 4; ++j) acc[r][j] += cc[r] * wv[j];
        }
        float4 bi = *(const float4*)&conv_bias[o0];
        float bv[4] = {bi.x, bi.y, bi.z, bi.w};
#pragma unroll
        for (int r = 0; r < 4; ++r) {
            int vv = vv0 + r;
            float4 ov;
            ov.x = (xt[vv][o0 + 0] + acc[r][0]) * (1.f / 3.f) + bv[0];
            ov.y = (xt[vv][o0 + 1] + acc[r][1]) * (1.f / 3.f) + bv[1];
            ov.z = (xt[vv][o0 + 2] + acc[r][2]) * (1.f / 3.f) + bv[2];
            ov.w = (xt[vv][o0 + 3] + acc[r][3]) * (1.f / 3.f) + bv[3];
            *(float4*)&x[(size_t)(v0 + vv) * OUT + o0] = ov;
        }
    }
}

// ---------------- BN stats
__global__ __launch_bounds__(256) void k_stats(const float* __restrict__ x,
                                               float* __restrict__ colsum,
                                               float* __restrict__ colsq) {
    int g = blockIdx.x * 256 + threadIdx.x;
    int col = g % OUT;
    int r0 = g / OUT;
    float s = 0.f, sq = 0.f;
    for (int r = r0; r < V; r += 512) {
        float v = x[(size_t)r * OUT + col];
        s += v;
        sq += v * v;
    }
    atomicAdd(&colsum[col], s);
    atomicAdd(&colsq[col], sq);
}

// ---------------- obj_bf (inline mean/rstd from colsum/colsq)
__global__ __launch_bounds__(256) void k_obj(const int* __restrict__ head,
                                             const int* __restrict__ rela,
                                             const float* __restrict__ x,
                                             const float* __restrict__ colsum,
                                             const float* __restrict__ colsq,
                                             const float* __restrict__ gamma,
                                             const float* __restrict__ beta,
                                             const float* __restrict__ r_out,
                                             unsigned short* __restrict__ obj_bf) {
    int b = blockIdx.x, t = threadIdx.x;
    if (t >= K2) return;
    float v = 0.f;
    if (t < OUT) {
        float m = colsum[t] / (float)V;
        float var = colsq[t] / (float)V - m * m;
        float rs = rsqrtf(var + EPS);
        int h = head[b], r = rela[b];
        float val = (x[(size_t)h * OUT + t] - m) * rs * gamma[t] + beta[t];
        val = tanhf(val);
        v = val * r_out[r * OUT + t];
    }
    obj_bf[(size_t)b * K2 + t] = f2bf(v);
}

// ---------------- emb_bf padded (vectorized)
__global__ __launch_bounds__(256) void k_cvt_emb(const float* __restrict__ emb_ent,
                                                 unsigned short* __restrict__ emb_bf) {
    int i = blockIdx.x * 256 + threadIdx.x;  // VPAD*29
    if (i >= VPAD * 29) return;
    int v = i / 29, c8 = i % 29;
    int c0 = c8 * 8;
    ushort8 o = (ushort8)0;
    if (v < V && c0 < 200) {
        float4 f0 = *(const float4*)&emb_ent[(size_t)v * OUT + c0];
        float4 f1 = *(const float4*)&emb_ent[(size_t)v * OUT + c0 + 4];
        o[0] = f2bf(f0.x); o[1] = f2bf(f0.y); o[2] = f2bf(f0.z); o[3] = f2bf(f0.w);
        o[4] = f2bf(f1.x); o[5] = f2bf(f1.y); o[6] = f2bf(f1.z); o[7] = f2bf(f1.w);
    }
    *(ushort8*)&emb_bf[(size_t)v * K2 + c0] = o;
}

// ---------------- decoder: LDS-free register MFMA GEMM (A,B from L1/L2)
constexpr int DEC_BM = 64, DEC_BN = 256;
constexpr int DEC_GX = B / DEC_BM;          // 16
constexpr int DEC_GY = VPAD / DEC_BN;       // 196
constexpr int DEC_NWG = DEC_GX * DEC_GY;    // 3136 (div by 8)

__global__ __launch_bounds__(256) void k_dec2(const unsigned short* __restrict__ obj_bf,
                                              const unsigned short* __restrict__ emb_bf,
                                              const float* __restrict__ ent_bias,
                                              float* __restrict__ score) {
    int t = threadIdx.x;
    int lane = t & 63, wid = t >> 6;
    int wg = (blockIdx.x & 7) * (DEC_NWG >> 3) + (blockIdx.x >> 3);
    int b0 = (wg & (DEC_GX - 1)) * DEC_BM;
    int v0 = (wg >> 4) * DEC_BN;
    int r16 = lane & 15;
    int kc = (lane >> 4) * 8;
    int vbase = v0 + wid * 64;
    const unsigned short* gA = obj_bf + (size_t)(b0 + r16) * K2 + kc;
    const unsigned short* gB = emb_bf + (size_t)(vbase + r16) * K2 + kc;
    f32x4 acc[4][4] = {};
    for (int ks = 0; ks < 7; ++ks) {
        int kof = ks * 32;
        bf16x8 a[4], bb[4];
#pragma unroll
        for (int mf = 0; mf < 4; ++mf)
            a[mf] = *(const bf16x8*)(gA + (size_t)(mf * 16) * K2 + kof);
#pragma unroll
        for (int nf = 0; nf < 4; ++nf)
            bb[nf] = *(const bf16x8*)(gB + (size_t)(nf * 16) * K2 + kof);
#pragma unroll
        for (int mf = 0; mf < 4; ++mf)
#pragma unroll
            for (int nf = 0; nf < 4; ++nf)
                acc[mf][nf] = __builtin_amdgcn_mfma_f32_16x16x32_bf16(a[mf], bb[nf],
                                                                      acc[mf][nf], 0, 0, 0);
    }
#pragma unroll
    for (int nf = 0; nf < 4; ++nf) {
        int v = vbase + nf * 16 + r16;
        if (v >= V) continue;
        float bias = ent_bias[v];
#pragma unroll
        for (int mf = 0; mf < 4; ++mf) {
            int brow = b0 + mf * 16 + (lane >> 4) * 4;
            f32x4 av = acc[mf][nf];
#pragma unroll
            for (int i = 0; i < 4; ++i) {
                float val = av[i] + bias;
                score[(size_t)(brow + i) * V + v] = 1.f / (1.f + __expf(-val));
            }
        }
    }
}

extern "C" void kernel_launch(void* const* d_in, const int* in_sizes, int n_in,
                              void* d_out, int out_size, void* d_ws, size_t ws_size,
                              hipStream_t stream) {
    const int*   edge_src  = (const int*)d_in[0];
    const int*   edge_dst  = (const int*)d_in[1];
    const int*   edge_type = (const int*)d_in[2];
    const int*   head      = (const int*)d_in[3];
    const int*   rela      = (const int*)d_in[4];
    const float* edge_norm = (const float*)d_in[5];
    const float* ent_emb   = (const float*)d_in[6];
    const float* rel_emb   = (const float*)d_in[7];
    const float* in_w      = (const float*)d_in[8];
    const float* out_w     = (const float*)d_in[9];
    const float* loop_w    = (const float*)d_in[10];
    const float* w_rel     = (const float*)d_in[11];
    const float* loop_rel  = (const float*)d_in[12];
    const float* conv_bias = (const float*)d_in[13];
    const float* bn_gamma  = (const float*)d_in[14];
    const float* bn_beta   = (const float*)d_in[15];
    const float* emb_ent   = (const float*)d_in[16];
    const float* ent_bias  = (const float*)d_in[17];
    float* score = (float*)d_out;

    // ---- workspace layout
    char* w = (char*)d_ws;
    float*          agg    = (float*)w;                      w += (size_t)V * OUT * 4;   // 40 MB
    unsigned short* Mtab   = (unsigned short*)w;             w += (size_t)NKEY * MT_SZ * 2;
    unsigned*       perm1  = (unsigned*)w;                   w += (size_t)E1MAX * 4;
    int*            pos_of_e = (int*)w;                      w += (size_t)E * 4;
    int*            poslist  = (int*)w;                      w += (size_t)E * 4;
    uint2*          pairs    = (uint2*)w;                    w += (size_t)NB2 * BCAP * 8;
    char* zbase = w;
    int*   hist1     = (int*)w;                              w += NKEY * 4;
    int*   cursor1   = (int*)w;                              w += NKEY * 4;
    int*   cursor196 = (int*)w;                              w += NB2 * 4;
    float* colsum    = (float*)w;                            w += OUT * 4;
    float* colsq     = (float*)w;                            w += OUT * 4;
    size_t zbytes = (size_t)(w - zbase);
    int*   start1  = (int*)w;                                w += (NKEY + 1) * 4;
    int*   start2  = (int*)w;                                w += (V + 4) * 4;
    int*   Edev    = (int*)w;                                w += 16;
    float* Mloop   = (float*)w;                              w += (size_t)D * OUT * 4;
    float* r_out   = (float*)w;                              w += (size_t)R * OUT * 4;
    unsigned short* obj_bf = (unsigned short*)w;             w += (size_t)B * K2 * 2;
    unsigned short* WT_bf  = (unsigned short*)w;             w += (size_t)2 * 208 * 128 * 2;
    // overlays on agg's region (strictly stream-ordered):
    unsigned short* ent_bf = (unsigned short*)agg;   // V*128 ushorts; dead after k_edgemm
    unsigned short* emb_bf = (unsigned short*)agg;   // VPAD*K2 ushorts; written after k_obj
    unsigned short* msg    = (unsigned short*)d_out; // E1MAX*200 ushorts; dead after k_aggx

    hipMemsetAsync(zbase, 0, zbytes, stream);
    hipMemsetAsync(perm1, 0xFF, (size_t)E1MAX * 4, stream);

    k_hist<<<512, 256, 0, stream>>>(edge_type, hist1);
    k_scan<<<1, 1024, 0, stream>>>(hist1, start1, Edev);
    k_binkey<<<(E + 8191) / 8192, 1024, 0, stream>>>(edge_type, start1, cursor1,
                                                     perm1, pos_of_e);
    k_bindst1<<<(E + 8191) / 8192, 1024, 0, stream>>>(edge_dst, pos_of_e, cursor196, pairs);
    k_bindst2<<<NB2, 256, 0, stream>>>(cursor196, pairs, start2, poslist);
    k_pre<<<PRE_NWG, 256, 0, stream>>>(loop_rel, loop_w, rel_emb, w_rel, in_w, out_w,
                                       ent_emb, Mloop, r_out, WT_bf, ent_bf);
    k_mtab<<<NKEY, 256, 0, stream>>>(rel_emb, WT_bf, Mtab);
    k_edgemm<<<E1MAX / 64 / ECHK, 256, 0, stream>>>(perm1, Edev, edge_src, edge_norm,
                                                    ent_bf, Mtab, msg);
    k_aggx<<<V / 16, 256, 0, stream>>>(start2, poslist, msg, ent_emb, Mloop,
                                       conv_bias, agg);
    k_stats<<<400, 256, 0, stream>>>(agg, colsum, colsq);
    k_obj<<<B, 256, 0, stream>>>(head, rela, agg, colsum, colsq, bn_gamma, bn_beta,
                                 r_out, obj_bf);
    k_cvt_emb<<<(VPAD * 29 + 255) / 256, 256, 0, stream>>>(emb_ent, emb_bf);
    k_dec2<<<DEC_NWG, 256, 0, stream>>>(obj_bf, emb_bf, ent_bias, score);
}